// Round 5
// baseline (501.139 us; speedup 1.0000x reference)
//
#include <hip/hip_runtime.h>

#define BDIM 256
#define LDP 68          // padded LDS row stride (floats) for fp32 kernels

#define NB 8
#define NC 192
#define NN 3136         // 56*56 = 49*64
#define NCH 384
#define NK 9
#define MSEG 49         // one 64x64 m-tile per block
#define NROW (NB * NN)  // 25088

typedef __attribute__((ext_vector_type(8))) short short8;
typedef __attribute__((ext_vector_type(4))) float f32x4;

__device__ __forceinline__ unsigned short f2bf(float f) {
  union { float f; unsigned u; } x{f};
  unsigned r = x.u + 0x7fff + ((x.u >> 16) & 1);  // RNE
  return (unsigned short)(r >> 16);
}

__device__ __forceinline__ float bf2f(unsigned short u) {
  union { unsigned u; float f; } x{(unsigned)u << 16};
  return x.f;
}

// sortable-u32 transform of float bits: order-preserving for all finite values
__device__ __forceinline__ unsigned fsort(float f) {
  union { float f; unsigned u; } x{f};
  return x.u ^ ((unsigned)(((int)x.u) >> 31) | 0x80000000u);
}

__device__ __forceinline__ void fma16(float acc[4][4], float4 av, float4 bv) {
  float an[4] = {av.x, av.y, av.z, av.w};
  float bm[4] = {bv.x, bv.y, bv.z, bv.w};
#pragma unroll
  for (int q = 0; q < 4; ++q)
#pragma unroll
    for (int r = 0; r < 4; ++r) acc[q][r] = fmaf(an[q], bm[r], acc[q][r]);
}

// ---------- K0: gcwb[768][192] bf16 <- gc_w split (rows 0-383: W1, 384-767: W2) ----------
__global__ __launch_bounds__(BDIM) void k0_convw(const float* __restrict__ gw,
                                                 unsigned short* __restrict__ gcwb) {
  int i = (blockIdx.x * BDIM + threadIdx.x) * 4;  // 147456 total elems
  int o = i / NC;
  int k = i - o * NC;
  const float* src = gw + (size_t)(o < NCH ? o : o - NCH) * (2 * NC) + (o < NCH ? 0 : NC) + k;
  float4 v = *(const float4*)src;
  uint2 u;
  u.x = (unsigned)f2bf(v.x) | ((unsigned)f2bf(v.y) << 16);
  u.y = (unsigned)f2bf(v.z) | ((unsigned)f2bf(v.w) << 16);
  *(uint2*)&gcwb[i] = u;
}

// ---------- K1: fp32 GEMM fc1 + BN1; emits hnb = bf16(normalize(h)) and norm ----------
__global__ __launch_bounds__(BDIM) void k1_fc1bn(
    const float* __restrict__ x, const float* __restrict__ w,
    const float* __restrict__ bias, const float* __restrict__ g1,
    const float* __restrict__ b1, const float* __restrict__ m1,
    const float* __restrict__ v1, unsigned short* __restrict__ hnb,
    float* __restrict__ normo) {
  __shared__ __align__(16) float a[64 * LDP];   // [k][n]
  __shared__ __align__(16) float wl[64 * LDP];  // [k][col]
  __shared__ float ns[64];
  int t = threadIdx.x;
  int b = blockIdx.x / 49, n0 = (blockIdx.x % 49) * 64;
  const float* xb = x + (size_t)b * NC * NN;
  int tx = t & 15, ty = t >> 4;
  if (t < 64) ns[t] = 0.f;
  float acc[3][4][4];
#pragma unroll
  for (int cp = 0; cp < 3; ++cp)
#pragma unroll
    for (int q = 0; q < 4; ++q)
#pragma unroll
      for (int r = 0; r < 4; ++r) acc[cp][q][r] = 0.f;

  for (int kc = 0; kc < 3; ++kc) {
    __syncthreads();
    for (int i = t; i < 1024; i += BDIM) {
      int k_ = i >> 4, n4 = (i & 15) << 2;
      float4 ld = *(const float4*)&xb[(size_t)(kc * 64 + k_) * NN + n0 + n4];
      *(float4*)&a[k_ * LDP + n4] = ld;
    }
    for (int cp = 0; cp < 3; ++cp) {
      __syncthreads();
      for (int i = t; i < 1024; i += BDIM) {
        int col_ = i >> 4, k4 = (i & 15) << 2;
        float4 ld = *(const float4*)&w[(size_t)(cp * 64 + col_) * NC + kc * 64 + k4];
        wl[(k4 + 0) * LDP + col_] = ld.x;
        wl[(k4 + 1) * LDP + col_] = ld.y;
        wl[(k4 + 2) * LDP + col_] = ld.z;
        wl[(k4 + 3) * LDP + col_] = ld.w;
      }
      __syncthreads();
#pragma unroll 4
      for (int c = 0; c < 64; ++c) {
        float4 av = *(const float4*)&a[c * LDP + ty * 4];
        float4 bv = *(const float4*)&wl[c * LDP + tx * 4];
        fma16(acc[cp], av, bv);
      }
    }
  }
  size_t rowb = (size_t)(b * NN + n0);
#pragma unroll
  for (int q = 0; q < 4; ++q) {
    float p = 0.f;
#pragma unroll
    for (int cp = 0; cp < 3; ++cp)
#pragma unroll
      for (int r = 0; r < 4; ++r) {
        int c = cp * 64 + tx * 4 + r;
        float s = g1[c] * rsqrtf(v1[c] + 1e-5f);
        float val = (acc[cp][q][r] + bias[c] - m1[c]) * s + b1[c];
        acc[cp][q][r] = val;
        p += val * val;
      }
    atomicAdd(&ns[ty * 4 + q], p);
  }
  __syncthreads();
  if (t < 64) {
    float s = fmaxf(sqrtf(ns[t]), 1e-12f);
    normo[rowb + t] = s;
    ns[t] = 1.f / s;
  }
  __syncthreads();
#pragma unroll
  for (int q = 0; q < 4; ++q) {
    float iv = ns[ty * 4 + q];
#pragma unroll
    for (int cp = 0; cp < 3; ++cp) {
      uint2 u;
      u.x = (unsigned)f2bf(acc[cp][q][0] * iv) | ((unsigned)f2bf(acc[cp][q][1] * iv) << 16);
      u.y = (unsigned)f2bf(acc[cp][q][2] * iv) | ((unsigned)f2bf(acc[cp][q][3] * iv) << 16);
      *(uint2*)&hnb[(rowb + ty * 4 + q) * (size_t)NC + cp * 64 + tx * 4] = u;
    }
  }
}

// ---------- K2a: one 64x64 sim tile per block; branchless packed-key top-9 ----------
// key = sortable_f32_top20 | (4095 - m). Massive TLP (19208 blocks) hides all latency.
__global__ __launch_bounds__(BDIM) void k2a_mfma_topk(
    const unsigned short* __restrict__ hnb, unsigned* __restrict__ candK) {
  __shared__ unsigned mkeys[64 * 36];
  int t = threadIdx.x;
  int bid = blockIdx.x;
  int b = bid / (49 * MSEG);
  int rem = bid % (49 * MSEG);
  int n0 = (rem / MSEG) * 64;
  int mseg = rem % MSEG;
  int m0 = mseg * 64;
  const unsigned short* hb = hnb + (size_t)b * NN * NC;
  int lane = t & 63, w = t >> 6;
  int l15 = lane & 15, l4 = lane >> 4;

  // B frag (n-side): n = n0 + w*16 + l15, k = ks*32 + l4*8 + j
  short8 bfr[6];
  {
    const short8* brow = (const short8*)(hb + (size_t)(n0 + w * 16 + l15) * NC + l4 * 8);
#pragma unroll
    for (int ks = 0; ks < 6; ++ks) bfr[ks] = brow[ks * 4];
  }
  unsigned tk[NK];
#pragma unroll
  for (int r = 0; r < NK; ++r) tk[r] = 0u;

  // A frag (m-side): row = m0 + sub*16 + l15, col chunk l4*16
  const char* pb = (const char*)hb + (size_t)m0 * 384 + l15 * 384 + l4 * 16;
#pragma unroll
  for (int sub = 0; sub < 4; ++sub) {
    const char* ps = pb + sub * 6144;
    short8 af[6];
#pragma unroll
    for (int ks = 0; ks < 6; ++ks) af[ks] = *(const short8*)(ps + ks * 64);
    f32x4 acc = {0.f, 0.f, 0.f, 0.f};
#pragma unroll
    for (int ks = 0; ks < 6; ++ks)
      acc = __builtin_amdgcn_mfma_f32_16x16x32_bf16(af[ks], bfr[ks], acc, 0, 0, 0);
    int mknd = 4095 - (m0 + sub * 16 + l4 * 4);
#pragma unroll
    for (int r = 0; r < 4; ++r) {
      unsigned cur = (fsort(acc[r]) & 0xFFFFF000u) | (unsigned)(mknd - r);
#pragma unroll
      for (int j = 0; j < NK; ++j) {
        unsigned hi = tk[j] > cur ? tk[j] : cur;
        unsigned lo = tk[j] > cur ? cur : tk[j];
        tk[j] = hi;
        cur = lo;
      }
    }
  }
  // merge 4 per-lane lists per n-row via LDS
  int nl = w * 16 + l15;
#pragma unroll
  for (int r = 0; r < NK; ++r) mkeys[(nl * 4 + l4) * NK + r] = tk[r];
  __syncthreads();
  if (t < 64) {
    const unsigned* k36 = &mkeys[t * 36];
    unsigned best[NK];
#pragma unroll
    for (int r = 0; r < NK; ++r) best[r] = 0u;
    for (int s = 0; s < 36; ++s) {
      unsigned cur = k36[s];
#pragma unroll
      for (int j = 0; j < NK; ++j) {
        unsigned hi = best[j] > cur ? best[j] : cur;
        unsigned lo = best[j] > cur ? cur : best[j];
        best[j] = hi;
        cur = lo;
      }
    }
    size_t row = (size_t)b * NN + n0 + t;
#pragma unroll
    for (int r = 0; r < NK; ++r) candK[(size_t)(mseg * NK + r) * NROW + row] = best[r];
  }
}

// ---------- K2b: merge 441 keys/row -> final top-9 indices (4 threads/row) ----------
__global__ __launch_bounds__(BDIM) void k2b_merge(const unsigned* __restrict__ candK,
                                                  int* __restrict__ idxo) {
  __shared__ unsigned mk[64 * 36];
  int t = threadIdx.x;
  int rl = t & 63, j = t >> 6;
  int row = blockIdx.x * 64 + rl;
  unsigned tk[NK];
#pragma unroll
  for (int r = 0; r < NK; ++r) tk[r] = 0u;
  for (int s = j; s < MSEG * NK; s += 4) {
    unsigned cur = candK[(size_t)s * NROW + row];
#pragma unroll
    for (int q = 0; q < NK; ++q) {
      unsigned hi = tk[q] > cur ? tk[q] : cur;
      unsigned lo = tk[q] > cur ? cur : tk[q];
      tk[q] = hi;
      cur = lo;
    }
  }
#pragma unroll
  for (int r = 0; r < NK; ++r) mk[(rl * 4 + j) * NK + r] = tk[r];
  __syncthreads();
  if (t < 64) {
    const unsigned* k36 = &mk[t * 36];
    unsigned best[NK];
#pragma unroll
    for (int r = 0; r < NK; ++r) best[r] = 0u;
    for (int s = 0; s < 36; ++s) {
      unsigned cur = k36[s];
#pragma unroll
      for (int q = 0; q < NK; ++q) {
        unsigned hi = best[q] > cur ? best[q] : cur;
        unsigned lo = best[q] > cur ? cur : best[q];
        best[q] = hi;
        cur = lo;
      }
    }
    size_t row = (size_t)blockIdx.x * 64 + t;
#pragma unroll
    for (int r = 0; r < NK; ++r)
      idxo[row * NK + r] = 4095 - (int)(best[r] & 4095u);
  }
}

// shared staging macro (k3)
#define K2_DSW(BI)                                                          \
  {                                                                         \
    _Pragma("unroll") for (int i = 0; i < 6; ++i) {                         \
      int L = (i * 256 + t) * 16;                                           \
      int m_ = L / 384;                                                     \
      int kb_ = L - m_ * 384;                                               \
      *(short8*)&abuf[BI][m_ * 384 + (kb_ ^ ((m_ & 7) << 4))] = gr[i];      \
    }                                                                       \
  }

// ---------- K3: P,Q = bf16((hn @ gcwb^T) * norm)  via MFMA ----------
__global__ __launch_bounds__(BDIM) void k3_pq_mfma(
    const unsigned short* __restrict__ hnb, const unsigned short* __restrict__ gcwb,
    const float* __restrict__ norm, unsigned short* __restrict__ P,
    unsigned short* __restrict__ Q) {
  __shared__ __align__(16) unsigned char abuf[2][24576];
  int t = threadIdx.x;
  int b = blockIdx.x / 49, n0 = (blockIdx.x % 49) * 64;
  const unsigned short* hb = hnb + (size_t)b * NN * NC;
  int lane = t & 63, w = t >> 6;
  int l15 = lane & 15, l4 = lane >> 4;
  int n = n0 + w * 16 + l15;
  short8 bfr[6];
  {
    const short8* brow = (const short8*)(hb + (size_t)n * NC + l4 * 8);
#pragma unroll
    for (int ks = 0; ks < 6; ++ks) bfr[ks] = brow[ks * 4];
  }
  float nrm = norm[(size_t)b * NN + n];
  size_t orow = (size_t)b * NN + n;
  short8 gr[6];
  const unsigned char* wB = (const unsigned char*)gcwb;
#define K3_LOADG(CH)                                                        \
  {                                                                         \
    const unsigned char* src = wB + (size_t)(CH) * 24576;                   \
    _Pragma("unroll") for (int i = 0; i < 6; ++i)                           \
        gr[i] = *(const short8*)(src + (i * 256 + t) * 16);                 \
  }
  K3_LOADG(0);
  K2_DSW(0);
  for (int ch = 0; ch < 12; ++ch) {
    int cur = ch & 1;
    if (ch < 11) K3_LOADG(ch + 1);
    __syncthreads();
#pragma unroll
    for (int sub = 0; sub < 4; ++sub) {
      int mrow = sub * 16 + l15;
      int rbase = mrow * 384, sw = (mrow & 7) << 4;
      f32x4 acc = {0.f, 0.f, 0.f, 0.f};
#pragma unroll
      for (int ks = 0; ks < 6; ++ks) {
        int kb = ks * 64 + l4 * 16;
        short8 af = *(const short8*)&abuf[cur][rbase + (kb ^ sw)];
        acc = __builtin_amdgcn_mfma_f32_16x16x32_bf16(af, bfr[ks], acc, 0, 0, 0);
      }
      int o = ch * 64 + sub * 16 + l4 * 4;
      f32x4 st = acc * nrm;
      unsigned short* dst = (o < NCH) ? P : Q;
      int oo = (o < NCH) ? o : o - NCH;
      uint2 u;
      u.x = (unsigned)f2bf(st[0]) | ((unsigned)f2bf(st[1]) << 16);
      u.y = (unsigned)f2bf(st[2]) | ((unsigned)f2bf(st[3]) << 16);
      *(uint2*)&dst[orow * NCH + oo] = u;
    }
    if (ch < 11) {
      __syncthreads();
      K2_DSW((ch + 1) & 1);
    }
  }
}

// ---------- K4: m = gelu(BN2(P - Q + gc_b + max_k Q[idx_k])), P/Q bf16 ----------
__global__ __launch_bounds__(BDIM) void k4_gathermax(
    const unsigned short* __restrict__ P, const unsigned short* __restrict__ Q,
    const int* __restrict__ idx, const float* __restrict__ gcb,
    const float* __restrict__ g2, const float* __restrict__ b2,
    const float* __restrict__ m2, const float* __restrict__ v2,
    float* __restrict__ mb) {
  int t = threadIdx.x;
  int lane = t & 63, wv = t >> 6;
  int row = blockIdx.x * 4 + wv;
  int b = row / NN, n = row % NN;
  const int* ip = idx + (size_t)row * NK;
  int id[NK];
#pragma unroll
  for (int k = 0; k < NK; ++k) id[k] = ip[k];
  const unsigned short* Qb = Q + (size_t)b * NN * NCH;
  const unsigned short* Pr = P + (size_t)row * NCH;
  const unsigned short* Qr = Qb + (size_t)n * NCH;
#pragma unroll
  for (int j = 0; j < 6; ++j) {
    int o = j * 64 + lane;
    float mx = -1e30f;
#pragma unroll
    for (int k = 0; k < NK; ++k) mx = fmaxf(mx, bf2f(Qb[(size_t)id[k] * NCH + o]));
    float e = bf2f(Pr[o]) - bf2f(Qr[o]) + gcb[o] + mx;
    float s = g2[o] * rsqrtf(v2[o] + 1e-5f);
    float y = (e - m2[o]) * s + b2[o];
    float ge = 0.5f * y * (1.f + erff(y * 0.70710678118654752f));
    mb[(size_t)row * NCH + o] = ge;
  }
}

// ---------- K5: out = BN3(m @ fc2_w^T + b) + shortcut, transposed to (B,C,N) ----------
__global__ __launch_bounds__(BDIM) void k5_fc2out(
    const float* __restrict__ mbuf, const float* __restrict__ w,
    const float* __restrict__ bias, const float* __restrict__ g3,
    const float* __restrict__ b3, const float* __restrict__ m3,
    const float* __restrict__ v3, const float* __restrict__ x,
    float* __restrict__ out) {
  __shared__ __align__(16) float a[64 * LDP];
  __shared__ __align__(16) float wl[64 * LDP];
  int t = threadIdx.x;
  int b = blockIdx.x / 49, n0 = (blockIdx.x % 49) * 64;
  const float* mbb = mbuf + (size_t)b * NN * NCH;
  int tx = t & 15, ty = t >> 4;
  float acc[3][4][4];
#pragma unroll
  for (int cp = 0; cp < 3; ++cp)
#pragma unroll
    for (int q = 0; q < 4; ++q)
#pragma unroll
      for (int r = 0; r < 4; ++r) acc[cp][q][r] = 0.f;

  for (int kc = 0; kc < 6; ++kc) {
    __syncthreads();
    for (int i = t; i < 1024; i += BDIM) {
      int n_ = i >> 4, c4 = (i & 15) << 2;
      float4 ld = *(const float4*)&mbb[(size_t)(n0 + n_) * NCH + kc * 64 + c4];
      a[(c4 + 0) * LDP + n_] = ld.x;
      a[(c4 + 1) * LDP + n_] = ld.y;
      a[(c4 + 2) * LDP + n_] = ld.z;
      a[(c4 + 3) * LDP + n_] = ld.w;
    }
    for (int cp = 0; cp < 3; ++cp) {
      __syncthreads();
      for (int i = t; i < 1024; i += BDIM) {
        int col_ = i >> 4, k4 = (i & 15) << 2;
        float4 ld = *(const float4*)&w[(size_t)(cp * 64 + col_) * NCH + kc * 64 + k4];
        wl[(k4 + 0) * LDP + col_] = ld.x;
        wl[(k4 + 1) * LDP + col_] = ld.y;
        wl[(k4 + 2) * LDP + col_] = ld.z;
        wl[(k4 + 3) * LDP + col_] = ld.w;
      }
      __syncthreads();
#pragma unroll 4
      for (int c = 0; c < 64; ++c) {
        float4 av = *(const float4*)&a[c * LDP + ty * 4];
        float4 bv = *(const float4*)&wl[c * LDP + tx * 4];
        fma16(acc[cp], av, bv);
      }
    }
  }
  const float* xb = x + (size_t)b * NC * NN;
  float* ob = out + (size_t)b * NC * NN;
  for (int cp = 0; cp < 3; ++cp) {
    __syncthreads();
#pragma unroll
    for (int q = 0; q < 4; ++q)
#pragma unroll
      for (int r = 0; r < 4; ++r) {
        int c = cp * 64 + tx * 4 + r;
        float s = g3[c] * rsqrtf(v3[c] + 1e-5f);
        float val = (acc[cp][q][r] + bias[c] - m3[c]) * s + b3[c];
        wl[(tx * 4 + r) * LDP + ty * 4 + q] = val;
      }
    __syncthreads();
    for (int i = t; i < 4096; i += BDIM) {
      int c_ = i >> 6, n_ = i & 63;
      size_t off = (size_t)(cp * 64 + c_) * NN + n0 + n_;
      ob[off] = wl[c_ * LDP + n_] + xb[off];
    }
  }
}

extern "C" void kernel_launch(void* const* d_in, const int* in_sizes, int n_in,
                              void* d_out, int out_size, void* d_ws, size_t ws_size,
                              hipStream_t stream) {
  const float* x = (const float*)d_in[0];
  const float* fc1_w = (const float*)d_in[1];
  const float* fc1_b = (const float*)d_in[2];
  const float* bn1_g = (const float*)d_in[3];
  const float* bn1_b = (const float*)d_in[4];
  const float* bn1_m = (const float*)d_in[5];
  const float* bn1_v = (const float*)d_in[6];
  const float* gc_w = (const float*)d_in[7];
  const float* gc_b = (const float*)d_in[8];
  const float* bn2_g = (const float*)d_in[9];
  const float* bn2_b = (const float*)d_in[10];
  const float* bn2_m = (const float*)d_in[11];
  const float* bn2_v = (const float*)d_in[12];
  const float* fc2_w = (const float*)d_in[13];
  const float* fc2_b = (const float*)d_in[14];
  const float* bn3_g = (const float*)d_in[15];
  const float* bn3_b = (const float*)d_in[16];
  const float* bn3_m = (const float*)d_in[17];
  const float* bn3_v = (const float*)d_in[18];

  // workspace (~88 MB): Pb | Qb (bf16) | mb (f32) | norm | idx | hnb | gcwb
  // candK (44.3MB) aliases Pb/Qb/mb-front: k2a->k2b consume it before k3/k4 write.
  float* ws = (float*)d_ws;
  size_t nrow = (size_t)NROW;
  size_t npq = (size_t)NB * NN * NCH;
  size_t nhb = (size_t)NB * NN * NC;
  unsigned short* Pb = (unsigned short*)ws;
  unsigned short* Qb = Pb + npq;
  float* mb = (float*)(Qb + npq);
  float* norm = mb + npq;
  int* idx = (int*)(norm + nrow);
  unsigned short* hnb = (unsigned short*)(idx + nrow * NK);
  unsigned short* gcwb = hnb + nhb;
  unsigned* candK = (unsigned*)ws;

  k0_convw<<<144, BDIM, 0, stream>>>(gc_w, gcwb);
  k1_fc1bn<<<NB * 49, BDIM, 0, stream>>>(x, fc1_w, fc1_b, bn1_g, bn1_b, bn1_m,
                                         bn1_v, hnb, norm);
  k2a_mfma_topk<<<NB * 49 * MSEG, BDIM, 0, stream>>>(hnb, candK);
  k2b_merge<<<NROW / 64, BDIM, 0, stream>>>(candK, idx);
  k3_pq_mfma<<<NB * 49, BDIM, 0, stream>>>(hnb, gcwb, norm, Pb, Qb);
  k4_gathermax<<<(NB * NN) / 4, BDIM, 0, stream>>>(Pb, Qb, idx, gc_b, bn2_g,
                                                   bn2_b, bn2_m, bn2_v, mb);
  k5_fc2out<<<NB * 49, BDIM, 0, stream>>>(mb, fc2_w, fc2_b, bn3_g, bn3_b,
                                          bn3_m, bn3_v, x, (float*)d_out);
}

// Round 6
// 436.248 us; speedup vs baseline: 1.1487x; 1.1487x over previous
//
#include <hip/hip_runtime.h>

#define BDIM 256
#define LDP 68          // padded LDS row stride (floats) for fp32 kernels

#define NB 8
#define NC 192
#define NN 3136         // 56*56 = 49*64
#define NCH 384
#define NK 9
#define NROW (NB * NN)  // 25088

typedef __attribute__((ext_vector_type(8))) short short8;
typedef __attribute__((ext_vector_type(4))) float f32x4;

__device__ __forceinline__ unsigned short f2bf(float f) {
  union { float f; unsigned u; } x{f};
  unsigned r = x.u + 0x7fff + ((x.u >> 16) & 1);  // RNE
  return (unsigned short)(r >> 16);
}

__device__ __forceinline__ float bf2f(unsigned u16) {
  union { unsigned u; float f; } x{u16 << 16};
  return x.f;
}

// sortable-u32 transform of float bits: order-preserving for all finite values
__device__ __forceinline__ unsigned fsort(float f) {
  union { float f; unsigned u; } x{f};
  return x.u ^ ((unsigned)(((int)x.u) >> 31) | 0x80000000u);
}

__device__ __forceinline__ void fma16(float acc[4][4], float4 av, float4 bv) {
  float an[4] = {av.x, av.y, av.z, av.w};
  float bm[4] = {bv.x, bv.y, bv.z, bv.w};
#pragma unroll
  for (int q = 0; q < 4; ++q)
#pragma unroll
    for (int r = 0; r < 4; ++r) acc[q][r] = fmaf(an[q], bm[r], acc[q][r]);
}

// ---------- K0: gcwb[768][192] bf16 <- gc_w split (rows 0-383: W1, 384-767: W2) ----------
__global__ __launch_bounds__(BDIM) void k0_convw(const float* __restrict__ gw,
                                                 unsigned short* __restrict__ gcwb) {
  int i = (blockIdx.x * BDIM + threadIdx.x) * 4;  // 147456 total elems
  int o = i / NC;
  int k = i - o * NC;
  const float* src = gw + (size_t)(o < NCH ? o : o - NCH) * (2 * NC) + (o < NCH ? 0 : NC) + k;
  float4 v = *(const float4*)src;
  uint2 u;
  u.x = (unsigned)f2bf(v.x) | ((unsigned)f2bf(v.y) << 16);
  u.y = (unsigned)f2bf(v.z) | ((unsigned)f2bf(v.w) << 16);
  *(uint2*)&gcwb[i] = u;
}

// ---------- K1: fp32 GEMM fc1 + BN1; emits hnb = bf16(normalize(h)) and norm ----------
__global__ __launch_bounds__(BDIM) void k1_fc1bn(
    const float* __restrict__ x, const float* __restrict__ w,
    const float* __restrict__ bias, const float* __restrict__ g1,
    const float* __restrict__ b1, const float* __restrict__ m1,
    const float* __restrict__ v1, unsigned short* __restrict__ hnb,
    float* __restrict__ normo) {
  __shared__ __align__(16) float a[64 * LDP];   // [k][n]
  __shared__ __align__(16) float wl[64 * LDP];  // [k][col]
  __shared__ float ns[64];
  int t = threadIdx.x;
  int b = blockIdx.x / 49, n0 = (blockIdx.x % 49) * 64;
  const float* xb = x + (size_t)b * NC * NN;
  int tx = t & 15, ty = t >> 4;
  if (t < 64) ns[t] = 0.f;
  float acc[3][4][4];
#pragma unroll
  for (int cp = 0; cp < 3; ++cp)
#pragma unroll
    for (int q = 0; q < 4; ++q)
#pragma unroll
      for (int r = 0; r < 4; ++r) acc[cp][q][r] = 0.f;

  for (int kc = 0; kc < 3; ++kc) {
    __syncthreads();
    for (int i = t; i < 1024; i += BDIM) {
      int k_ = i >> 4, n4 = (i & 15) << 2;
      float4 ld = *(const float4*)&xb[(size_t)(kc * 64 + k_) * NN + n0 + n4];
      *(float4*)&a[k_ * LDP + n4] = ld;
    }
    for (int cp = 0; cp < 3; ++cp) {
      __syncthreads();
      for (int i = t; i < 1024; i += BDIM) {
        int col_ = i >> 4, k4 = (i & 15) << 2;
        float4 ld = *(const float4*)&w[(size_t)(cp * 64 + col_) * NC + kc * 64 + k4];
        wl[(k4 + 0) * LDP + col_] = ld.x;
        wl[(k4 + 1) * LDP + col_] = ld.y;
        wl[(k4 + 2) * LDP + col_] = ld.z;
        wl[(k4 + 3) * LDP + col_] = ld.w;
      }
      __syncthreads();
#pragma unroll 4
      for (int c = 0; c < 64; ++c) {
        float4 av = *(const float4*)&a[c * LDP + ty * 4];
        float4 bv = *(const float4*)&wl[c * LDP + tx * 4];
        fma16(acc[cp], av, bv);
      }
    }
  }
  size_t rowb = (size_t)(b * NN + n0);
#pragma unroll
  for (int q = 0; q < 4; ++q) {
    float p = 0.f;
#pragma unroll
    for (int cp = 0; cp < 3; ++cp)
#pragma unroll
      for (int r = 0; r < 4; ++r) {
        int c = cp * 64 + tx * 4 + r;
        float s = g1[c] * rsqrtf(v1[c] + 1e-5f);
        float val = (acc[cp][q][r] + bias[c] - m1[c]) * s + b1[c];
        acc[cp][q][r] = val;
        p += val * val;
      }
    atomicAdd(&ns[ty * 4 + q], p);
  }
  __syncthreads();
  if (t < 64) {
    float s = fmaxf(sqrtf(ns[t]), 1e-12f);
    normo[rowb + t] = s;
    ns[t] = 1.f / s;
  }
  __syncthreads();
#pragma unroll
  for (int q = 0; q < 4; ++q) {
    float iv = ns[ty * 4 + q];
#pragma unroll
    for (int cp = 0; cp < 3; ++cp) {
      uint2 u;
      u.x = (unsigned)f2bf(acc[cp][q][0] * iv) | ((unsigned)f2bf(acc[cp][q][1] * iv) << 16);
      u.y = (unsigned)f2bf(acc[cp][q][2] * iv) | ((unsigned)f2bf(acc[cp][q][3] * iv) << 16);
      *(uint2*)&hnb[(rowb + ty * 4 + q) * (size_t)NC + cp * 64 + tx * 4] = u;
    }
  }
}

// ---------- K2: sim top-9, one pass. Block = 16 n-rows; wave w sweeps m-tiles
// w, w+4, ... (full coverage). No LDS/barriers in main loop; branchless packed
// keys; 2-stage LDS merge writes final idx. b = blockIdx&7 pins batch to XCD L2.
__global__ __launch_bounds__(BDIM) void k2_topk(
    const unsigned short* __restrict__ hnb, int* __restrict__ idxo) {
  __shared__ unsigned mkeys[16 * 16 * NK];  // [n16][w*4+l4][9]
  __shared__ unsigned mk2[16 * 4 * NK];
  int t = threadIdx.x;
  int b = blockIdx.x & 7;
  int n0 = (int)(blockIdx.x >> 3) * 16;
  const unsigned short* hb = hnb + (size_t)b * NN * NC;
  int lane = t & 63, w = t >> 6;
  int l15 = lane & 15, l4 = lane >> 4;

  // B frag (resident): n = n0 + l15, k = l4*8 + ks*32 + j
  short8 bfr[6];
  {
    const short8* brow = (const short8*)(hb + (size_t)(n0 + l15) * NC + l4 * 8);
#pragma unroll
    for (int ks = 0; ks < 6; ++ks) bfr[ks] = brow[ks * 4];
  }
  unsigned tk[NK];
#pragma unroll
  for (int r = 0; r < NK; ++r) tk[r] = 0u;

  const char* pbase = (const char*)hb + l15 * 384 + l4 * 16;
  for (int mt = w; mt < 49; mt += 4) {
    const char* pt = pbase + (size_t)mt * 24576;
#pragma unroll
    for (int sub = 0; sub < 4; ++sub) {
      const char* ps = pt + sub * 6144;
      short8 af[6];
#pragma unroll
      for (int ks = 0; ks < 6; ++ks) af[ks] = *(const short8*)(ps + ks * 64);
      f32x4 acc = {0.f, 0.f, 0.f, 0.f};
#pragma unroll
      for (int ks = 0; ks < 6; ++ks)
        acc = __builtin_amdgcn_mfma_f32_16x16x32_bf16(af[ks], bfr[ks], acc, 0, 0, 0);
      int mknd = 4095 - (mt * 64 + sub * 16 + l4 * 4);
#pragma unroll
      for (int r = 0; r < 4; ++r) {
        unsigned cur = (fsort(acc[r]) & 0xFFFFF000u) | (unsigned)(mknd - r);
#pragma unroll
        for (int j = 0; j < NK; ++j) {
          unsigned hi = tk[j] > cur ? tk[j] : cur;
          unsigned lo = tk[j] > cur ? cur : tk[j];
          tk[j] = hi;
          cur = lo;
        }
      }
    }
  }
#pragma unroll
  for (int r = 0; r < NK; ++r) mkeys[(l15 * 16 + w * 4 + l4) * NK + r] = tk[r];
  __syncthreads();
  if (t < 64) {  // stage 2: 4 threads/row, each merges 4 lists (36 keys)
    int row = t >> 2, j = t & 3;
    const unsigned* src = &mkeys[(row * 16 + j * 4) * NK];
    unsigned best[NK];
#pragma unroll
    for (int r = 0; r < NK; ++r) best[r] = 0u;
    for (int s = 0; s < 36; ++s) {
      unsigned cur = src[s];
#pragma unroll
      for (int q = 0; q < NK; ++q) {
        unsigned hi = best[q] > cur ? best[q] : cur;
        unsigned lo = best[q] > cur ? cur : best[q];
        best[q] = hi;
        cur = lo;
      }
    }
#pragma unroll
    for (int r = 0; r < NK; ++r) mk2[(row * 4 + j) * NK + r] = best[r];
  }
  __syncthreads();
  if (t < 16) {  // stage 3: final 4-list merge, write indices
    const unsigned* src = &mk2[t * 4 * NK];
    unsigned best[NK];
#pragma unroll
    for (int r = 0; r < NK; ++r) best[r] = 0u;
    for (int s = 0; s < 36; ++s) {
      unsigned cur = src[s];
#pragma unroll
      for (int q = 0; q < NK; ++q) {
        unsigned hi = best[q] > cur ? best[q] : cur;
        unsigned lo = best[q] > cur ? cur : best[q];
        best[q] = hi;
        cur = lo;
      }
    }
    size_t row = (size_t)b * NN + n0 + t;
#pragma unroll
    for (int r = 0; r < NK; ++r)
      idxo[row * NK + r] = 4095 - (int)(best[r] & 4095u);
  }
}

// shared staging macro (k3)
#define K2_DSW(BI)                                                          \
  {                                                                         \
    _Pragma("unroll") for (int i = 0; i < 6; ++i) {                         \
      int L = (i * 256 + t) * 16;                                           \
      int m_ = L / 384;                                                     \
      int kb_ = L - m_ * 384;                                               \
      *(short8*)&abuf[BI][m_ * 384 + (kb_ ^ ((m_ & 7) << 4))] = gr[i];      \
    }                                                                       \
  }

// ---------- K3: P,Q = bf16((hn @ gcwb^T) * norm) via MFMA; 2-way o-split ----------
__global__ __launch_bounds__(BDIM) void k3_pq_mfma(
    const unsigned short* __restrict__ hnb, const unsigned short* __restrict__ gcwb,
    const float* __restrict__ norm, unsigned short* __restrict__ P,
    unsigned short* __restrict__ Q) {
  __shared__ __align__(16) unsigned char abuf[2][24576];
  int t = threadIdx.x;
  int b = blockIdx.x / 98;
  int rem = blockIdx.x % 98;
  int n0 = (rem >> 1) * 64;
  int ch0 = (rem & 1) * 6;
  const unsigned short* hb = hnb + (size_t)b * NN * NC;
  int lane = t & 63, w = t >> 6;
  int l15 = lane & 15, l4 = lane >> 4;
  int n = n0 + w * 16 + l15;
  short8 bfr[6];
  {
    const short8* brow = (const short8*)(hb + (size_t)n * NC + l4 * 8);
#pragma unroll
    for (int ks = 0; ks < 6; ++ks) bfr[ks] = brow[ks * 4];
  }
  float nrm = norm[(size_t)b * NN + n];
  size_t orow = (size_t)b * NN + n;
  short8 gr[6];
  const unsigned char* wB = (const unsigned char*)gcwb;
#define K3_LOADG(CH)                                                        \
  {                                                                         \
    const unsigned char* src = wB + (size_t)(CH) * 24576;                   \
    _Pragma("unroll") for (int i = 0; i < 6; ++i)                           \
        gr[i] = *(const short8*)(src + (i * 256 + t) * 16);                 \
  }
  K3_LOADG(ch0);
  K2_DSW(0);
  for (int ci = 0; ci < 6; ++ci) {
    int ch = ch0 + ci;
    int cur = ci & 1;
    if (ci < 5) K3_LOADG(ch + 1);
    __syncthreads();
#pragma unroll
    for (int sub = 0; sub < 4; ++sub) {
      int mrow = sub * 16 + l15;
      int rbase = mrow * 384, sw = (mrow & 7) << 4;
      f32x4 acc = {0.f, 0.f, 0.f, 0.f};
#pragma unroll
      for (int ks = 0; ks < 6; ++ks) {
        int kb = ks * 64 + l4 * 16;
        short8 af = *(const short8*)&abuf[cur][rbase + (kb ^ sw)];
        acc = __builtin_amdgcn_mfma_f32_16x16x32_bf16(af, bfr[ks], acc, 0, 0, 0);
      }
      int o = ch * 64 + sub * 16 + l4 * 4;
      f32x4 st = acc * nrm;
      unsigned short* dst = (o < NCH) ? P : Q;
      int oo = (o < NCH) ? o : o - NCH;
      uint2 u;
      u.x = (unsigned)f2bf(st[0]) | ((unsigned)f2bf(st[1]) << 16);
      u.y = (unsigned)f2bf(st[2]) | ((unsigned)f2bf(st[3]) << 16);
      *(uint2*)&dst[orow * NCH + oo] = u;
    }
    if (ci < 5) {
      __syncthreads();
      K2_DSW((ci + 1) & 1);
    }
  }
}

// ---------- K4: m = bf16(gelu(BN2(P - Q + gc_b + max_k Q[idx_k]))), 2 cols/lane ----------
__global__ __launch_bounds__(BDIM) void k4_gathermax(
    const unsigned short* __restrict__ P, const unsigned short* __restrict__ Q,
    const int* __restrict__ idx, const float* __restrict__ gcb,
    const float* __restrict__ g2, const float* __restrict__ b2,
    const float* __restrict__ m2, const float* __restrict__ v2,
    unsigned short* __restrict__ mbh) {
  int t = threadIdx.x;
  int lane = t & 63, wv = t >> 6;
  int row = blockIdx.x * 4 + wv;
  int b = row / NN, n = row % NN;
  const int* ip = idx + (size_t)row * NK;
  int id[NK];
#pragma unroll
  for (int k = 0; k < NK; ++k) id[k] = ip[k];
  const unsigned short* Qb = Q + (size_t)b * NN * NCH;
  const unsigned short* Pr = P + (size_t)row * NCH;
  const unsigned short* Qr = Qb + (size_t)n * NCH;
#pragma unroll
  for (int j = 0; j < 3; ++j) {
    int o = j * 128 + lane * 2;
    float mx0 = -1e30f, mx1 = -1e30f;
#pragma unroll
    for (int k = 0; k < NK; ++k) {
      unsigned g = *(const unsigned*)&Qb[(size_t)id[k] * NCH + o];
      mx0 = fmaxf(mx0, bf2f(g & 0xffffu));
      mx1 = fmaxf(mx1, bf2f(g >> 16));
    }
    unsigned pv = *(const unsigned*)&Pr[o];
    unsigned qv = *(const unsigned*)&Qr[o];
    float2 gc = *(const float2*)&gcb[o];
    float2 gg = *(const float2*)&g2[o];
    float2 bb = *(const float2*)&b2[o];
    float2 mm = *(const float2*)&m2[o];
    float2 vv = *(const float2*)&v2[o];
    float e0 = bf2f(pv & 0xffffu) - bf2f(qv & 0xffffu) + gc.x + mx0;
    float e1 = bf2f(pv >> 16) - bf2f(qv >> 16) + gc.y + mx1;
    float y0 = (e0 - mm.x) * (gg.x * rsqrtf(vv.x + 1e-5f)) + bb.x;
    float y1 = (e1 - mm.y) * (gg.y * rsqrtf(vv.y + 1e-5f)) + bb.y;
    float ge0 = 0.5f * y0 * (1.f + erff(y0 * 0.70710678118654752f));
    float ge1 = 0.5f * y1 * (1.f + erff(y1 * 0.70710678118654752f));
    *(unsigned*)&mbh[(size_t)row * NCH + o] =
        (unsigned)f2bf(ge0) | ((unsigned)f2bf(ge1) << 16);
  }
}

// ---------- K5: out = BN3(m @ fc2_w^T + b) + shortcut (m in bf16) ----------
__global__ __launch_bounds__(BDIM) void k5_fc2out(
    const unsigned short* __restrict__ mbuf, const float* __restrict__ w,
    const float* __restrict__ bias, const float* __restrict__ g3,
    const float* __restrict__ b3, const float* __restrict__ m3,
    const float* __restrict__ v3, const float* __restrict__ x,
    float* __restrict__ out) {
  __shared__ __align__(16) float a[64 * LDP];
  __shared__ __align__(16) float wl[64 * LDP];
  int t = threadIdx.x;
  int b = blockIdx.x / 49, n0 = (blockIdx.x % 49) * 64;
  const unsigned short* mbb = mbuf + (size_t)b * NN * NCH;
  int tx = t & 15, ty = t >> 4;
  float acc[3][4][4];
#pragma unroll
  for (int cp = 0; cp < 3; ++cp)
#pragma unroll
    for (int q = 0; q < 4; ++q)
#pragma unroll
      for (int r = 0; r < 4; ++r) acc[cp][q][r] = 0.f;

  for (int kc = 0; kc < 6; ++kc) {
    __syncthreads();
    for (int i = t; i < 1024; i += BDIM) {
      int n_ = i >> 4, c4 = (i & 15) << 2;
      uint2 ld = *(const uint2*)&mbb[(size_t)(n0 + n_) * NCH + kc * 64 + c4];
      a[(c4 + 0) * LDP + n_] = bf2f(ld.x & 0xffffu);
      a[(c4 + 1) * LDP + n_] = bf2f(ld.x >> 16);
      a[(c4 + 2) * LDP + n_] = bf2f(ld.y & 0xffffu);
      a[(c4 + 3) * LDP + n_] = bf2f(ld.y >> 16);
    }
    for (int cp = 0; cp < 3; ++cp) {
      __syncthreads();
      for (int i = t; i < 1024; i += BDIM) {
        int col_ = i >> 4, k4 = (i & 15) << 2;
        float4 ld = *(const float4*)&w[(size_t)(cp * 64 + col_) * NCH + kc * 64 + k4];
        wl[(k4 + 0) * LDP + col_] = ld.x;
        wl[(k4 + 1) * LDP + col_] = ld.y;
        wl[(k4 + 2) * LDP + col_] = ld.z;
        wl[(k4 + 3) * LDP + col_] = ld.w;
      }
      __syncthreads();
#pragma unroll 4
      for (int c = 0; c < 64; ++c) {
        float4 av = *(const float4*)&a[c * LDP + ty * 4];
        float4 bv = *(const float4*)&wl[c * LDP + tx * 4];
        fma16(acc[cp], av, bv);
      }
    }
  }
  const float* xb = x + (size_t)b * NC * NN;
  float* ob = out + (size_t)b * NC * NN;
  for (int cp = 0; cp < 3; ++cp) {
    __syncthreads();
#pragma unroll
    for (int q = 0; q < 4; ++q)
#pragma unroll
      for (int r = 0; r < 4; ++r) {
        int c = cp * 64 + tx * 4 + r;
        float s = g3[c] * rsqrtf(v3[c] + 1e-5f);
        float val = (acc[cp][q][r] + bias[c] - m3[c]) * s + b3[c];
        wl[(tx * 4 + r) * LDP + ty * 4 + q] = val;
      }
    __syncthreads();
    for (int i = t; i < 4096; i += BDIM) {
      int c_ = i >> 6, n_ = i & 63;
      size_t off = (size_t)(cp * 64 + c_) * NN + n0 + n_;
      ob[off] = wl[c_ * LDP + n_] + xb[off];
    }
  }
}

extern "C" void kernel_launch(void* const* d_in, const int* in_sizes, int n_in,
                              void* d_out, int out_size, void* d_ws, size_t ws_size,
                              hipStream_t stream) {
  const float* x = (const float*)d_in[0];
  const float* fc1_w = (const float*)d_in[1];
  const float* fc1_b = (const float*)d_in[2];
  const float* bn1_g = (const float*)d_in[3];
  const float* bn1_b = (const float*)d_in[4];
  const float* bn1_m = (const float*)d_in[5];
  const float* bn1_v = (const float*)d_in[6];
  const float* gc_w = (const float*)d_in[7];
  const float* gc_b = (const float*)d_in[8];
  const float* bn2_g = (const float*)d_in[9];
  const float* bn2_b = (const float*)d_in[10];
  const float* bn2_m = (const float*)d_in[11];
  const float* bn2_v = (const float*)d_in[12];
  const float* fc2_w = (const float*)d_in[13];
  const float* fc2_b = (const float*)d_in[14];
  const float* bn3_g = (const float*)d_in[15];
  const float* bn3_b = (const float*)d_in[16];
  const float* bn3_m = (const float*)d_in[17];
  const float* bn3_v = (const float*)d_in[18];

  // workspace (~69 MB): Pb | Qb | mbh (bf16) | norm | idx | hnb | gcwb
  size_t nrow = (size_t)NROW;
  size_t npq = (size_t)NB * NN * NCH;
  size_t nhb = (size_t)NB * NN * NC;
  unsigned short* Pb = (unsigned short*)d_ws;
  unsigned short* Qb = Pb + npq;
  unsigned short* mbh = Qb + npq;
  float* norm = (float*)(mbh + npq);
  int* idx = (int*)(norm + nrow);
  unsigned short* hnb = (unsigned short*)(idx + nrow * NK);
  unsigned short* gcwb = hnb + nhb;

  k0_convw<<<144, BDIM, 0, stream>>>(gc_w, gcwb);
  k1_fc1bn<<<NB * 49, BDIM, 0, stream>>>(x, fc1_w, fc1_b, bn1_g, bn1_b, bn1_m,
                                         bn1_v, hnb, norm);
  k2_topk<<<NB * 196, BDIM, 0, stream>>>(hnb, idx);
  k3_pq_mfma<<<NB * 98, BDIM, 0, stream>>>(hnb, gcwb, norm, Pb, Qb);
  k4_gathermax<<<(NB * NN) / 4, BDIM, 0, stream>>>(Pb, Qb, idx, gc_b, bn2_g,
                                                   bn2_b, bn2_m, bn2_v, mbh);
  k5_fc2out<<<NB * 49, BDIM, 0, stream>>>(mbh, fc2_w, fc2_b, bn3_g, bn3_b,
                                          bn3_m, bn3_v, x, (float*)d_out);
}

// Round 7
// 297.269 us; speedup vs baseline: 1.6858x; 1.4675x over previous
//
#include <hip/hip_runtime.h>

#define BDIM 256
#define LDP 68          // padded LDS row stride (floats) for fp32 kernels

#define NB 8
#define NC 192
#define NN 3136         // 56*56 = 49*64
#define NCH 384
#define NK 9
#define NROW (NB * NN)  // 25088

typedef __attribute__((ext_vector_type(8))) short short8;
typedef __attribute__((ext_vector_type(4))) float f32x4;

__device__ __forceinline__ unsigned short f2bf(float f) {
  union { float f; unsigned u; } x{f};
  unsigned r = x.u + 0x7fff + ((x.u >> 16) & 1);  // RNE
  return (unsigned short)(r >> 16);
}

__device__ __forceinline__ float bf2f(unsigned u16) {
  union { unsigned u; float f; } x{u16 << 16};
  return x.f;
}

// sortable-u32 transform of float bits: order-preserving for all finite values
__device__ __forceinline__ unsigned fsort(float f) {
  union { float f; unsigned u; } x{f};
  return x.u ^ ((unsigned)(((int)x.u) >> 31) | 0x80000000u);
}

__device__ __forceinline__ void fma16(float acc[4][4], float4 av, float4 bv) {
  float an[4] = {av.x, av.y, av.z, av.w};
  float bm[4] = {bv.x, bv.y, bv.z, bv.w};
#pragma unroll
  for (int q = 0; q < 4; ++q)
#pragma unroll
    for (int r = 0; r < 4; ++r) acc[q][r] = fmaf(an[q], bm[r], acc[q][r]);
}

// stage one 24KB [64 rows][384B] bf16 tile into LDS via async global_load_lds
// (width 16). LDS dest is linear (wave-uniform base + lane*16, HW-added);
// global source is pre-XOR-swizzled so that LDS[m][kb] = G[m][kb ^ ((m&7)<<4)].
// Readers apply the same XOR -> bit-identical data, bank-conflict-reduced.
__device__ __forceinline__ void stage_tile(const char* gbase, char* lbuf, int w,
                                           int lane) {
#pragma unroll
  for (int i = 0; i < 6; ++i) {
    int L = (i * 4 + w) * 1024 + lane * 16;
    int m = L / 384;
    int kb = L - m * 384;
    const char* g = gbase + m * 384 + (kb ^ ((m & 7) << 4));
    __builtin_amdgcn_global_load_lds(
        (const __attribute__((address_space(1))) unsigned int*)g,
        (__attribute__((address_space(3))) unsigned int*)(lbuf + (i * 4 + w) * 1024),
        16, 0, 0);
  }
}

// ---------- K0: gcwb[768][192] bf16 <- gc_w split (rows 0-383: W1, 384-767: W2) ----------
__global__ __launch_bounds__(BDIM) void k0_convw(const float* __restrict__ gw,
                                                 unsigned short* __restrict__ gcwb) {
  int i = (blockIdx.x * BDIM + threadIdx.x) * 4;  // 147456 total elems
  int o = i / NC;
  int k = i - o * NC;
  const float* src = gw + (size_t)(o < NCH ? o : o - NCH) * (2 * NC) + (o < NCH ? 0 : NC) + k;
  float4 v = *(const float4*)src;
  uint2 u;
  u.x = (unsigned)f2bf(v.x) | ((unsigned)f2bf(v.y) << 16);
  u.y = (unsigned)f2bf(v.z) | ((unsigned)f2bf(v.w) << 16);
  *(uint2*)&gcwb[i] = u;
}

// ---------- K1: fp32 GEMM fc1 + BN1; emits hnb = bf16(normalize(h)) and norm ----------
__global__ __launch_bounds__(BDIM) void k1_fc1bn(
    const float* __restrict__ x, const float* __restrict__ w,
    const float* __restrict__ bias, const float* __restrict__ g1,
    const float* __restrict__ b1, const float* __restrict__ m1,
    const float* __restrict__ v1, unsigned short* __restrict__ hnb,
    float* __restrict__ normo) {
  __shared__ __align__(16) float a[64 * LDP];   // [k][n]
  __shared__ __align__(16) float wl[64 * LDP];  // [k][col]
  __shared__ float ns[64];
  int t = threadIdx.x;
  int b = blockIdx.x / 49, n0 = (blockIdx.x % 49) * 64;
  const float* xb = x + (size_t)b * NC * NN;
  int tx = t & 15, ty = t >> 4;
  if (t < 64) ns[t] = 0.f;
  float acc[3][4][4];
#pragma unroll
  for (int cp = 0; cp < 3; ++cp)
#pragma unroll
    for (int q = 0; q < 4; ++q)
#pragma unroll
      for (int r = 0; r < 4; ++r) acc[cp][q][r] = 0.f;

  for (int kc = 0; kc < 3; ++kc) {
    __syncthreads();
    for (int i = t; i < 1024; i += BDIM) {
      int k_ = i >> 4, n4 = (i & 15) << 2;
      float4 ld = *(const float4*)&xb[(size_t)(kc * 64 + k_) * NN + n0 + n4];
      *(float4*)&a[k_ * LDP + n4] = ld;
    }
    for (int cp = 0; cp < 3; ++cp) {
      __syncthreads();
      for (int i = t; i < 1024; i += BDIM) {
        int col_ = i >> 4, k4 = (i & 15) << 2;
        float4 ld = *(const float4*)&w[(size_t)(cp * 64 + col_) * NC + kc * 64 + k4];
        wl[(k4 + 0) * LDP + col_] = ld.x;
        wl[(k4 + 1) * LDP + col_] = ld.y;
        wl[(k4 + 2) * LDP + col_] = ld.z;
        wl[(k4 + 3) * LDP + col_] = ld.w;
      }
      __syncthreads();
#pragma unroll 4
      for (int c = 0; c < 64; ++c) {
        float4 av = *(const float4*)&a[c * LDP + ty * 4];
        float4 bv = *(const float4*)&wl[c * LDP + tx * 4];
        fma16(acc[cp], av, bv);
      }
    }
  }
  size_t rowb = (size_t)(b * NN + n0);
#pragma unroll
  for (int q = 0; q < 4; ++q) {
    float p = 0.f;
#pragma unroll
    for (int cp = 0; cp < 3; ++cp)
#pragma unroll
      for (int r = 0; r < 4; ++r) {
        int c = cp * 64 + tx * 4 + r;
        float s = g1[c] * rsqrtf(v1[c] + 1e-5f);
        float val = (acc[cp][q][r] + bias[c] - m1[c]) * s + b1[c];
        acc[cp][q][r] = val;
        p += val * val;
      }
    atomicAdd(&ns[ty * 4 + q], p);
  }
  __syncthreads();
  if (t < 64) {
    float s = fmaxf(sqrtf(ns[t]), 1e-12f);
    normo[rowb + t] = s;
    ns[t] = 1.f / s;
  }
  __syncthreads();
#pragma unroll
  for (int q = 0; q < 4; ++q) {
    float iv = ns[ty * 4 + q];
#pragma unroll
    for (int cp = 0; cp < 3; ++cp) {
      uint2 u;
      u.x = (unsigned)f2bf(acc[cp][q][0] * iv) | ((unsigned)f2bf(acc[cp][q][1] * iv) << 16);
      u.y = (unsigned)f2bf(acc[cp][q][2] * iv) | ((unsigned)f2bf(acc[cp][q][3] * iv) << 16);
      *(uint2*)&hnb[(rowb + ty * 4 + q) * (size_t)NC + cp * 64 + tx * 4] = u;
    }
  }
}

// ---------- K2a: sim top-9 via MFMA; async LDS double-buffered A staging ----------
// block: 64 n-rows (wave w owns rows w*16..+15), sweeps half the m-tiles.
// Branchless packed keys: key = sortable_f32_top20 | (4095 - m).
__global__ __launch_bounds__(BDIM) void k2a_topk(
    const unsigned short* __restrict__ hnb, unsigned* __restrict__ candK) {
  __shared__ __align__(16) char abuf[2][24576];
  int t = threadIdx.x;
  int bid = blockIdx.x;
  int b = bid & 7;          // batch -> XCD pin (dispatch round-robins over 8 XCDs)
  int rem = bid >> 3;       // 0..97
  int n0 = (rem >> 1) * 64;
  int seg = rem & 1;
  int mt0 = seg ? 25 : 0, mt1 = seg ? 49 : 25;
  const unsigned short* hb = hnb + (size_t)b * NN * NC;
  const char* hbB = (const char*)hb;
  int lane = t & 63, w = t >> 6;
  int l15 = lane & 15, l4 = lane >> 4;

  // B frag (n-side), VGPR-resident: n = n0 + w*16 + l15, k = ks*32 + l4*8 + j
  short8 bfr[6];
  {
    const short8* brow = (const short8*)(hb + (size_t)(n0 + w * 16 + l15) * NC + l4 * 8);
#pragma unroll
    for (int ks = 0; ks < 6; ++ks) bfr[ks] = brow[ks * 4];
  }
  unsigned tk[NK];
#pragma unroll
  for (int r = 0; r < NK; ++r) tk[r] = 0u;

  stage_tile(hbB + (size_t)mt0 * 24576, abuf[0], w, lane);
  __syncthreads();
  int nt = mt1 - mt0;
  for (int ti = 0; ti < nt; ++ti) {
    int cur = ti & 1;
    if (ti + 1 < nt)
      stage_tile(hbB + (size_t)(mt0 + ti + 1) * 24576, abuf[cur ^ 1], w, lane);
    int mglob = (mt0 + ti) * 64;
#pragma unroll
    for (int sub = 0; sub < 4; ++sub) {
      int r_ = sub * 16 + l15;
      int rbase = r_ * 384, sw = (r_ & 7) << 4;
      short8 af[6];
#pragma unroll
      for (int ks = 0; ks < 6; ++ks)
        af[ks] = *(const short8*)&abuf[cur][rbase + ((ks * 64 + l4 * 16) ^ sw)];
      f32x4 acc = {0.f, 0.f, 0.f, 0.f};
#pragma unroll
      for (int ks = 0; ks < 6; ++ks)
        acc = __builtin_amdgcn_mfma_f32_16x16x32_bf16(af[ks], bfr[ks], acc, 0, 0, 0);
      int mknd = 4095 - (mglob + sub * 16 + l4 * 4);
#pragma unroll
      for (int r = 0; r < 4; ++r) {
        unsigned cur_k = (fsort(acc[r]) & 0xFFFFF000u) | (unsigned)(mknd - r);
#pragma unroll
        for (int j = 0; j < NK; ++j) {
          unsigned hi = tk[j] > cur_k ? tk[j] : cur_k;
          unsigned lo = tk[j] > cur_k ? cur_k : tk[j];
          tk[j] = hi;
          cur_k = lo;
        }
      }
    }
    __syncthreads();  // waits vmcnt(0): next tile staged; all waves done reading cur
  }
  // merge 4 per-lane lists per n-row via LDS (alias staging buffer)
  unsigned* mkeys = (unsigned*)&abuf[0][0];  // [64 rows][4 lists][9]
  int nl = w * 16 + l15;
#pragma unroll
  for (int r = 0; r < NK; ++r) mkeys[(nl * 4 + l4) * NK + r] = tk[r];
  __syncthreads();
  if (t < 64) {
    const unsigned* src = &mkeys[t * 4 * NK];
    unsigned best[NK];
#pragma unroll
    for (int r = 0; r < NK; ++r) best[r] = 0u;
    for (int s = 0; s < 36; ++s) {
      unsigned cur_k = src[s];
#pragma unroll
      for (int q = 0; q < NK; ++q) {
        unsigned hi = best[q] > cur_k ? best[q] : cur_k;
        unsigned lo = best[q] > cur_k ? cur_k : best[q];
        best[q] = hi;
        cur_k = lo;
      }
    }
    size_t row = (size_t)b * NN + n0 + t;
#pragma unroll
    for (int r = 0; r < NK; ++r) candK[(size_t)(seg * NK + r) * NROW + row] = best[r];
  }
}

// ---------- K2b: merge 2x9 keys/row -> final top-9 indices ----------
__global__ __launch_bounds__(BDIM) void k2b_merge(const unsigned* __restrict__ candK,
                                                  int* __restrict__ idxo) {
  int row = blockIdx.x * BDIM + threadIdx.x;
  unsigned tk[NK];
#pragma unroll
  for (int r = 0; r < NK; ++r) tk[r] = 0u;
  for (int s = 0; s < 2 * NK; ++s) {
    unsigned cur = candK[(size_t)s * NROW + row];
#pragma unroll
    for (int j = 0; j < NK; ++j) {
      unsigned hi = tk[j] > cur ? tk[j] : cur;
      unsigned lo = tk[j] > cur ? cur : tk[j];
      tk[j] = hi;
      cur = lo;
    }
  }
#pragma unroll
  for (int r = 0; r < NK; ++r)
    idxo[(size_t)row * NK + r] = 4095 - (int)(tk[r] & 4095u);
}

// ---------- K3: P,Q = bf16((hn @ gcwb^T) * norm); async-staged weights ----------
__global__ __launch_bounds__(BDIM) void k3_pq_mfma(
    const unsigned short* __restrict__ hnb, const unsigned short* __restrict__ gcwb,
    const float* __restrict__ norm, unsigned short* __restrict__ P,
    unsigned short* __restrict__ Q) {
  __shared__ __align__(16) char abuf[2][24576];
  int t = threadIdx.x;
  int b = blockIdx.x / 98;
  int rem = blockIdx.x % 98;
  int n0 = (rem >> 1) * 64;
  int ch0 = (rem & 1) * 6;
  const unsigned short* hb = hnb + (size_t)b * NN * NC;
  int lane = t & 63, w = t >> 6;
  int l15 = lane & 15, l4 = lane >> 4;
  int n = n0 + w * 16 + l15;
  short8 bfr[6];
  {
    const short8* brow = (const short8*)(hb + (size_t)n * NC + l4 * 8);
#pragma unroll
    for (int ks = 0; ks < 6; ++ks) bfr[ks] = brow[ks * 4];
  }
  float nrm = norm[(size_t)b * NN + n];
  size_t orow = (size_t)b * NN + n;
  const char* wB = (const char*)gcwb;

  stage_tile(wB + (size_t)ch0 * 24576, abuf[0], w, lane);
  __syncthreads();
  for (int ci = 0; ci < 6; ++ci) {
    int ch = ch0 + ci;
    int cur = ci & 1;
    if (ci < 5) stage_tile(wB + (size_t)(ch + 1) * 24576, abuf[cur ^ 1], w, lane);
#pragma unroll
    for (int sub = 0; sub < 4; ++sub) {
      int mrow = sub * 16 + l15;
      int rbase = mrow * 384, sw = (mrow & 7) << 4;
      f32x4 acc = {0.f, 0.f, 0.f, 0.f};
#pragma unroll
      for (int ks = 0; ks < 6; ++ks) {
        short8 af = *(const short8*)&abuf[cur][rbase + ((ks * 64 + l4 * 16) ^ sw)];
        acc = __builtin_amdgcn_mfma_f32_16x16x32_bf16(af, bfr[ks], acc, 0, 0, 0);
      }
      int o = ch * 64 + sub * 16 + l4 * 4;
      f32x4 st = acc * nrm;
      unsigned short* dst = (o < NCH) ? P : Q;
      int oo = (o < NCH) ? o : o - NCH;
      uint2 u;
      u.x = (unsigned)f2bf(st[0]) | ((unsigned)f2bf(st[1]) << 16);
      u.y = (unsigned)f2bf(st[2]) | ((unsigned)f2bf(st[3]) << 16);
      *(uint2*)&dst[orow * NCH + oo] = u;
    }
    __syncthreads();
  }
}

// ---------- K4: m = bf16(gelu(BN2(P - Q + gc_b + max_k Q[idx_k]))), 2 cols/lane ----------
__global__ __launch_bounds__(BDIM) void k4_gathermax(
    const unsigned short* __restrict__ P, const unsigned short* __restrict__ Q,
    const int* __restrict__ idx, const float* __restrict__ gcb,
    const float* __restrict__ g2, const float* __restrict__ b2,
    const float* __restrict__ m2, const float* __restrict__ v2,
    unsigned short* __restrict__ mbh) {
  int t = threadIdx.x;
  int lane = t & 63, wv = t >> 6;
  int row = blockIdx.x * 4 + wv;
  int b = row / NN, n = row % NN;
  const int* ip = idx + (size_t)row * NK;
  int id[NK];
#pragma unroll
  for (int k = 0; k < NK; ++k) id[k] = ip[k];
  const unsigned short* Qb = Q + (size_t)b * NN * NCH;
  const unsigned short* Pr = P + (size_t)row * NCH;
  const unsigned short* Qr = Qb + (size_t)n * NCH;
#pragma unroll
  for (int j = 0; j < 3; ++j) {
    int o = j * 128 + lane * 2;
    float mx0 = -1e30f, mx1 = -1e30f;
#pragma unroll
    for (int k = 0; k < NK; ++k) {
      unsigned g = *(const unsigned*)&Qb[(size_t)id[k] * NCH + o];
      mx0 = fmaxf(mx0, bf2f(g & 0xffffu));
      mx1 = fmaxf(mx1, bf2f(g >> 16));
    }
    unsigned pv = *(const unsigned*)&Pr[o];
    unsigned qv = *(const unsigned*)&Qr[o];
    float2 gc = *(const float2*)&gcb[o];
    float2 gg = *(const float2*)&g2[o];
    float2 bb = *(const float2*)&b2[o];
    float2 mm = *(const float2*)&m2[o];
    float2 vv = *(const float2*)&v2[o];
    float e0 = bf2f(pv & 0xffffu) - bf2f(qv & 0xffffu) + gc.x + mx0;
    float e1 = bf2f(pv >> 16) - bf2f(qv >> 16) + gc.y + mx1;
    float y0 = (e0 - mm.x) * (gg.x * rsqrtf(vv.x + 1e-5f)) + bb.x;
    float y1 = (e1 - mm.y) * (gg.y * rsqrtf(vv.y + 1e-5f)) + bb.y;
    float ge0 = 0.5f * y0 * (1.f + erff(y0 * 0.70710678118654752f));
    float ge1 = 0.5f * y1 * (1.f + erff(y1 * 0.70710678118654752f));
    *(unsigned*)&mbh[(size_t)row * NCH + o] =
        (unsigned)f2bf(ge0) | ((unsigned)f2bf(ge1) << 16);
  }
}

// ---------- K5: out = BN3(m @ fc2_w^T + b) + shortcut (m in bf16) ----------
__global__ __launch_bounds__(BDIM) void k5_fc2out(
    const unsigned short* __restrict__ mbuf, const float* __restrict__ w,
    const float* __restrict__ bias, const float* __restrict__ g3,
    const float* __restrict__ b3, const float* __restrict__ m3,
    const float* __restrict__ v3, const float* __restrict__ x,
    float* __restrict__ out) {
  __shared__ __align__(16) float a[64 * LDP];
  __shared__ __align__(16) float wl[64 * LDP];
  int t = threadIdx.x;
  int b = blockIdx.x / 49, n0 = (blockIdx.x % 49) * 64;
  const unsigned short* mbb = mbuf + (size_t)b * NN * NCH;
  int tx = t & 15, ty = t >> 4;
  float acc[3][4][4];
#pragma unroll
  for (int cp = 0; cp < 3; ++cp)
#pragma unroll
    for (int q = 0; q < 4; ++q)
#pragma unroll
      for (int r = 0; r < 4; ++r) acc[cp][q][r] = 0.f;

  for (int kc = 0; kc < 6; ++kc) {
    __syncthreads();
    for (int i = t; i < 1024; i += BDIM) {
      int n_ = i >> 4, c4 = (i & 15) << 2;
      uint2 ld = *(const uint2*)&mbb[(size_t)(n0 + n_) * NCH + kc * 64 + c4];
      a[(c4 + 0) * LDP + n_] = bf2f(ld.x & 0xffffu);
      a[(c4 + 1) * LDP + n_] = bf2f(ld.x >> 16);
      a[(c4 + 2) * LDP + n_] = bf2f(ld.y & 0xffffu);
      a[(c4 + 3) * LDP + n_] = bf2f(ld.y >> 16);
    }
    for (int cp = 0; cp < 3; ++cp) {
      __syncthreads();
      for (int i = t; i < 1024; i += BDIM) {
        int col_ = i >> 4, k4 = (i & 15) << 2;
        float4 ld = *(const float4*)&w[(size_t)(cp * 64 + col_) * NCH + kc * 64 + k4];
        wl[(k4 + 0) * LDP + col_] = ld.x;
        wl[(k4 + 1) * LDP + col_] = ld.y;
        wl[(k4 + 2) * LDP + col_] = ld.z;
        wl[(k4 + 3) * LDP + col_] = ld.w;
      }
      __syncthreads();
#pragma unroll 4
      for (int c = 0; c < 64; ++c) {
        float4 av = *(const float4*)&a[c * LDP + ty * 4];
        float4 bv = *(const float4*)&wl[c * LDP + tx * 4];
        fma16(acc[cp], av, bv);
      }
    }
  }
  const float* xb = x + (size_t)b * NC * NN;
  float* ob = out + (size_t)b * NC * NN;
  for (int cp = 0; cp < 3; ++cp) {
    __syncthreads();
#pragma unroll
    for (int q = 0; q < 4; ++q)
#pragma unroll
      for (int r = 0; r < 4; ++r) {
        int c = cp * 64 + tx * 4 + r;
        float s = g3[c] * rsqrtf(v3[c] + 1e-5f);
        float val = (acc[cp][q][r] + bias[c] - m3[c]) * s + b3[c];
        wl[(tx * 4 + r) * LDP + ty * 4 + q] = val;
      }
    __syncthreads();
    for (int i = t; i < 4096; i += BDIM) {
      int c_ = i >> 6, n_ = i & 63;
      size_t off = (size_t)(cp * 64 + c_) * NN + n0 + n_;
      ob[off] = wl[c_ * LDP + n_] + xb[off];
    }
  }
}

extern "C" void kernel_launch(void* const* d_in, const int* in_sizes, int n_in,
                              void* d_out, int out_size, void* d_ws, size_t ws_size,
                              hipStream_t stream) {
  const float* x = (const float*)d_in[0];
  const float* fc1_w = (const float*)d_in[1];
  const float* fc1_b = (const float*)d_in[2];
  const float* bn1_g = (const float*)d_in[3];
  const float* bn1_b = (const float*)d_in[4];
  const float* bn1_m = (const float*)d_in[5];
  const float* bn1_v = (const float*)d_in[6];
  const float* gc_w = (const float*)d_in[7];
  const float* gc_b = (const float*)d_in[8];
  const float* bn2_g = (const float*)d_in[9];
  const float* bn2_b = (const float*)d_in[10];
  const float* bn2_m = (const float*)d_in[11];
  const float* bn2_v = (const float*)d_in[12];
  const float* fc2_w = (const float*)d_in[13];
  const float* fc2_b = (const float*)d_in[14];
  const float* bn3_g = (const float*)d_in[15];
  const float* bn3_b = (const float*)d_in[16];
  const float* bn3_m = (const float*)d_in[17];
  const float* bn3_v = (const float*)d_in[18];

  // workspace (~72 MB): Pb | Qb | mbh (bf16) | norm | idx | hnb | gcwb | candK
  size_t nrow = (size_t)NROW;
  size_t npq = (size_t)NB * NN * NCH;
  size_t nhb = (size_t)NB * NN * NC;
  unsigned short* Pb = (unsigned short*)d_ws;
  unsigned short* Qb = Pb + npq;
  unsigned short* mbh = Qb + npq;
  float* norm = (float*)(mbh + npq);
  int* idx = (int*)(norm + nrow);
  unsigned short* hnb = (unsigned short*)(idx + nrow * NK);
  unsigned short* gcwb = hnb + nhb;
  unsigned* candK = (unsigned*)(gcwb + 768 * NC);

  k0_convw<<<144, BDIM, 0, stream>>>(gc_w, gcwb);
  k1_fc1bn<<<NB * 49, BDIM, 0, stream>>>(x, fc1_w, fc1_b, bn1_g, bn1_b, bn1_m,
                                         bn1_v, hnb, norm);
  k2a_topk<<<NB * 98, BDIM, 0, stream>>>(hnb, candK);
  k2b_merge<<<NROW / BDIM, BDIM, 0, stream>>>(candK, idx);
  k3_pq_mfma<<<NB * 98, BDIM, 0, stream>>>(hnb, gcwb, norm, Pb, Qb);
  k4_gathermax<<<(NB * NN) / 4, BDIM, 0, stream>>>(Pb, Qb, idx, gc_b, bn2_g,
                                                   bn2_b, bn2_m, bn2_v, mbh);
  k5_fc2out<<<NB * 49, BDIM, 0, stream>>>(mbh, fc2_w, fc2_b, bn3_g, bn3_b,
                                          bn3_m, bn3_v, x, (float*)d_out);
}

// Round 8
// 183.370 us; speedup vs baseline: 2.7329x; 1.6211x over previous
//
#include <hip/hip_runtime.h>

#define BDIM 256
#define NB 8
#define NC 192
#define NN 3136         // 56*56 = 49*64
#define NCH 384
#define NK 9
#define NROW (NB * NN)  // 25088

typedef __attribute__((ext_vector_type(8))) short short8;
typedef __attribute__((ext_vector_type(4))) float f32x4;

__device__ __forceinline__ unsigned short f2bf(float f) {
  union { float f; unsigned u; } x{f};
  unsigned r = x.u + 0x7fff + ((x.u >> 16) & 1);  // RNE
  return (unsigned short)(r >> 16);
}

__device__ __forceinline__ float bf2f(unsigned u16) {
  union { unsigned u; float f; } x{u16 << 16};
  return x.f;
}

// sortable-u32 transform of float bits: order-preserving for all finite values
__device__ __forceinline__ unsigned fsort(float f) {
  union { float f; unsigned u; } x{f};
  return x.u ^ ((unsigned)(((int)x.u) >> 31) | 0x80000000u);
}

// stage one 24KB [64 rows][384B] bf16 tile into LDS via async global_load_lds
// (width 16). LDS dest linear; global source pre-XOR-swizzled so that
// LDS[m][kb] = G[m][kb ^ ((m&7)<<4)]; readers apply the same XOR.
__device__ __forceinline__ void stage_tile(const char* gbase, char* lbuf, int w,
                                           int lane) {
#pragma unroll
  for (int i = 0; i < 6; ++i) {
    int L = (i * 4 + w) * 1024 + lane * 16;
    int m = L / 384;
    int kb = L - m * 384;
    const char* g = gbase + m * 384 + (kb ^ ((m & 7) << 4));
    __builtin_amdgcn_global_load_lds(
        (const __attribute__((address_space(1))) unsigned int*)g,
        (__attribute__((address_space(3))) unsigned int*)(lbuf + (i * 4 + w) * 1024),
        16, 0, 0);
  }
}

// ---------- K0: bf16 weight conversion ----------
// gcwb[768][192] <- gc_w split; fc1b[192][192] <- fc1_w; fc2b retiled
// [(oc*2+kh)][64][192] <- fc2_w[192][384].
__global__ __launch_bounds__(BDIM) void k0_convw(
    const float* __restrict__ gw, const float* __restrict__ f1w,
    const float* __restrict__ f2w, unsigned short* __restrict__ gcwb,
    unsigned short* __restrict__ fc1b, unsigned short* __restrict__ fc2b) {
  int i = (blockIdx.x * BDIM + threadIdx.x) * 4;
  const float* src;
  unsigned short* dst;
  if (i < 147456) {  // gc_w
    int o = i / NC, k = i - o * NC;
    src = gw + (size_t)(o < NCH ? o : o - NCH) * (2 * NC) + (o < NCH ? 0 : NC) + k;
    dst = gcwb + i;
  } else if (i < 184320) {  // fc1
    int j = i - 147456;
    src = f1w + j;
    dst = fc1b + j;
  } else {  // fc2 retile
    int j = i - 184320;
    int o = j / NCH, k = j - o * NCH;
    int oc = o >> 6, om = o & 63;
    int kh = k / 192, km = k - kh * 192;
    src = f2w + j;
    dst = fc2b + ((size_t)((oc * 2 + kh) * 64 + om)) * 192 + km;
  }
  float4 v = *(const float4*)src;
  uint2 u;
  u.x = (unsigned)f2bf(v.x) | ((unsigned)f2bf(v.y) << 16);
  u.y = (unsigned)f2bf(v.z) | ((unsigned)f2bf(v.w) << 16);
  *(uint2*)dst = u;
}

// ---------- K0b: fold BN params: val = gemm*sc + sh ----------
__global__ __launch_bounds__(384) void k0b_params(
    const float* __restrict__ f1b, const float* __restrict__ g1,
    const float* __restrict__ b1, const float* __restrict__ m1,
    const float* __restrict__ v1, const float* __restrict__ gcb,
    const float* __restrict__ g2, const float* __restrict__ b2,
    const float* __restrict__ m2, const float* __restrict__ v2,
    const float* __restrict__ f2b, const float* __restrict__ g3,
    const float* __restrict__ b3, const float* __restrict__ m3,
    const float* __restrict__ v3, float* __restrict__ sc1,
    float* __restrict__ sh1, float* __restrict__ sc2, float* __restrict__ sh2,
    float* __restrict__ sc3, float* __restrict__ sh3) {
  int c = threadIdx.x;
  if (c < NC) {
    float s1 = g1[c] * rsqrtf(v1[c] + 1e-5f);
    sc1[c] = s1;
    sh1[c] = (f1b[c] - m1[c]) * s1 + b1[c];
    float s3 = g3[c] * rsqrtf(v3[c] + 1e-5f);
    sc3[c] = s3;
    sh3[c] = (f2b[c] - m3[c]) * s3 + b3[c];
  }
  float s2 = g2[c] * rsqrtf(v2[c] + 1e-5f);
  sc2[c] = s2;
  sh2[c] = (gcb[c] - m2[c]) * s2 + b2[c];
}

// ---------- KX: xb16[b][n][c] <- bf16(x[b][c][n]) (transpose+convert) ----------
__global__ __launch_bounds__(BDIM) void kx_transpose(const float* __restrict__ x,
                                                     unsigned short* __restrict__ xb) {
  __shared__ float lds[64 * 68];
  int t = threadIdx.x;
  int b = blockIdx.x / 147;
  int rem = blockIdx.x % 147;
  int n0 = (rem / 3) * 64, c0 = (rem % 3) * 64;
  const float* xbp = x + (size_t)b * NC * NN;
  for (int i = t; i < 1024; i += BDIM) {
    int c_ = i >> 4, n4 = (i & 15) << 2;
    float4 v = *(const float4*)&xbp[(size_t)(c0 + c_) * NN + n0 + n4];
    lds[c_ * 68 + n4 + 0] = v.x;
    lds[c_ * 68 + n4 + 1] = v.y;
    lds[c_ * 68 + n4 + 2] = v.z;
    lds[c_ * 68 + n4 + 3] = v.w;
  }
  __syncthreads();
  for (int j = t; j < 1024; j += BDIM) {
    int n_ = j >> 4, c4 = (j & 15) << 2;
    uint2 u;
    u.x = (unsigned)f2bf(lds[(c4 + 0) * 68 + n_]) |
          ((unsigned)f2bf(lds[(c4 + 1) * 68 + n_]) << 16);
    u.y = (unsigned)f2bf(lds[(c4 + 2) * 68 + n_]) |
          ((unsigned)f2bf(lds[(c4 + 3) * 68 + n_]) << 16);
    *(uint2*)&xb[(size_t)(b * NN + n0 + n_) * NC + c0 + c4] = u;
  }
}

// ---------- K1: h = BN1(x @ fc1_w^T) via MFMA; emits hnb, norm ----------
// block: 64 n (4 waves x 16), full 192 o; K=192. A = fc1b tiles (async-staged).
__global__ __launch_bounds__(BDIM) void k1_mfma(
    const unsigned short* __restrict__ xb, const unsigned short* __restrict__ fc1b,
    const float* __restrict__ sc1, const float* __restrict__ sh1,
    unsigned short* __restrict__ hnb, float* __restrict__ normo) {
  __shared__ __align__(16) char abuf[2][24576];
  int t = threadIdx.x;
  int b = blockIdx.x / 49, n0 = (blockIdx.x % 49) * 64;
  int lane = t & 63, w = t >> 6;
  int l15 = lane & 15, l4 = lane >> 4;
  int n = n0 + w * 16 + l15;
  short8 bfr[6];
  {
    const short8* brow = (const short8*)(xb + (size_t)(b * NN + n) * NC + l4 * 8);
#pragma unroll
    for (int ks = 0; ks < 6; ++ks) bfr[ks] = brow[ks * 4];
  }
  f32x4 acc[3][4];
#pragma unroll
  for (int oc = 0; oc < 3; ++oc)
#pragma unroll
    for (int sub = 0; sub < 4; ++sub) acc[oc][sub] = {0.f, 0.f, 0.f, 0.f};

  const char* wB = (const char*)fc1b;
  stage_tile(wB, abuf[0], w, lane);
  __syncthreads();
  for (int oc = 0; oc < 3; ++oc) {
    int cur = oc & 1;
    if (oc < 2) stage_tile(wB + (size_t)(oc + 1) * 24576, abuf[cur ^ 1], w, lane);
#pragma unroll
    for (int sub = 0; sub < 4; ++sub) {
      int r_ = sub * 16 + l15;
      int rbase = r_ * 384, sw = (r_ & 7) << 4;
#pragma unroll
      for (int ks = 0; ks < 6; ++ks) {
        short8 af = *(const short8*)&abuf[cur][rbase + ((ks * 64 + l4 * 16) ^ sw)];
        acc[oc][sub] = __builtin_amdgcn_mfma_f32_16x16x32_bf16(af, bfr[ks],
                                                               acc[oc][sub], 0, 0, 0);
      }
    }
    __syncthreads();
  }
  // epilogue: BN1 fold, row-norm (lanes l4=0..3 hold disjoint o for same n)
  float p = 0.f;
#pragma unroll
  for (int oc = 0; oc < 3; ++oc)
#pragma unroll
    for (int sub = 0; sub < 4; ++sub) {
      int c4 = oc * 64 + sub * 16 + l4 * 4;
      float s_[4], h_[4];
      *(float4*)s_ = *(const float4*)&sc1[c4];
      *(float4*)h_ = *(const float4*)&sh1[c4];
#pragma unroll
      for (int r = 0; r < 4; ++r) {
        float v = acc[oc][sub][r] * s_[r] + h_[r];
        acc[oc][sub][r] = v;
        p += v * v;
      }
    }
  p += __shfl_xor(p, 16);
  p += __shfl_xor(p, 32);
  float nr = fmaxf(sqrtf(p), 1e-12f);
  float iv = 1.f / nr;
  if (l4 == 0) normo[(size_t)b * NN + n] = nr;
#pragma unroll
  for (int oc = 0; oc < 3; ++oc)
#pragma unroll
    for (int sub = 0; sub < 4; ++sub) {
      uint2 u;
      u.x = (unsigned)f2bf(acc[oc][sub][0] * iv) |
            ((unsigned)f2bf(acc[oc][sub][1] * iv) << 16);
      u.y = (unsigned)f2bf(acc[oc][sub][2] * iv) |
            ((unsigned)f2bf(acc[oc][sub][3] * iv) << 16);
      *(uint2*)&hnb[(size_t)(b * NN + n) * NC + oc * 64 + sub * 16 + l4 * 4] = u;
    }
}

// ---------- K2a: sim top-9 via MFMA; async LDS double-buffered A staging ----------
__global__ __launch_bounds__(BDIM) void k2a_topk(
    const unsigned short* __restrict__ hnb, unsigned* __restrict__ candK) {
  __shared__ __align__(16) char abuf[2][24576];
  int t = threadIdx.x;
  int bid = blockIdx.x;
  int b = bid & 7;
  int rem = bid >> 3;
  int n0 = (rem >> 1) * 64;
  int seg = rem & 1;
  int mt0 = seg ? 25 : 0, mt1 = seg ? 49 : 25;
  const unsigned short* hb = hnb + (size_t)b * NN * NC;
  const char* hbB = (const char*)hb;
  int lane = t & 63, w = t >> 6;
  int l15 = lane & 15, l4 = lane >> 4;

  short8 bfr[6];
  {
    const short8* brow = (const short8*)(hb + (size_t)(n0 + w * 16 + l15) * NC + l4 * 8);
#pragma unroll
    for (int ks = 0; ks < 6; ++ks) bfr[ks] = brow[ks * 4];
  }
  unsigned tk[NK];
#pragma unroll
  for (int r = 0; r < NK; ++r) tk[r] = 0u;

  stage_tile(hbB + (size_t)mt0 * 24576, abuf[0], w, lane);
  __syncthreads();
  int nt = mt1 - mt0;
  for (int ti = 0; ti < nt; ++ti) {
    int cur = ti & 1;
    if (ti + 1 < nt)
      stage_tile(hbB + (size_t)(mt0 + ti + 1) * 24576, abuf[cur ^ 1], w, lane);
    int mglob = (mt0 + ti) * 64;
#pragma unroll
    for (int sub = 0; sub < 4; ++sub) {
      int r_ = sub * 16 + l15;
      int rbase = r_ * 384, sw = (r_ & 7) << 4;
      short8 af[6];
#pragma unroll
      for (int ks = 0; ks < 6; ++ks)
        af[ks] = *(const short8*)&abuf[cur][rbase + ((ks * 64 + l4 * 16) ^ sw)];
      f32x4 acc = {0.f, 0.f, 0.f, 0.f};
#pragma unroll
      for (int ks = 0; ks < 6; ++ks)
        acc = __builtin_amdgcn_mfma_f32_16x16x32_bf16(af[ks], bfr[ks], acc, 0, 0, 0);
      int mknd = 4095 - (mglob + sub * 16 + l4 * 4);
#pragma unroll
      for (int r = 0; r < 4; ++r) {
        unsigned cur_k = (fsort(acc[r]) & 0xFFFFF000u) | (unsigned)(mknd - r);
#pragma unroll
        for (int j = 0; j < NK; ++j) {
          unsigned hi = tk[j] > cur_k ? tk[j] : cur_k;
          unsigned lo = tk[j] > cur_k ? cur_k : tk[j];
          tk[j] = hi;
          cur_k = lo;
        }
      }
    }
    __syncthreads();
  }
  unsigned* mkeys = (unsigned*)&abuf[0][0];
  int nl = w * 16 + l15;
#pragma unroll
  for (int r = 0; r < NK; ++r) mkeys[(nl * 4 + l4) * NK + r] = tk[r];
  __syncthreads();
  if (t < 64) {
    const unsigned* src = &mkeys[t * 4 * NK];
    unsigned best[NK];
#pragma unroll
    for (int r = 0; r < NK; ++r) best[r] = 0u;
    for (int s = 0; s < 36; ++s) {
      unsigned cur_k = src[s];
#pragma unroll
      for (int q = 0; q < NK; ++q) {
        unsigned hi = best[q] > cur_k ? best[q] : cur_k;
        unsigned lo = best[q] > cur_k ? cur_k : best[q];
        best[q] = hi;
        cur_k = lo;
      }
    }
    size_t row = (size_t)b * NN + n0 + t;
#pragma unroll
    for (int r = 0; r < NK; ++r) candK[(size_t)(seg * NK + r) * NROW + row] = best[r];
  }
}

// ---------- K2b: merge 2x9 keys/row -> final top-9 indices ----------
__global__ __launch_bounds__(BDIM) void k2b_merge(const unsigned* __restrict__ candK,
                                                  int* __restrict__ idxo) {
  int row = blockIdx.x * BDIM + threadIdx.x;
  unsigned tk[NK];
#pragma unroll
  for (int r = 0; r < NK; ++r) tk[r] = 0u;
  for (int s = 0; s < 2 * NK; ++s) {
    unsigned cur = candK[(size_t)s * NROW + row];
#pragma unroll
    for (int j = 0; j < NK; ++j) {
      unsigned hi = tk[j] > cur ? tk[j] : cur;
      unsigned lo = tk[j] > cur ? cur : tk[j];
      tk[j] = hi;
      cur = lo;
    }
  }
#pragma unroll
  for (int r = 0; r < NK; ++r)
    idxo[(size_t)row * NK + r] = 4095 - (int)(tk[r] & 4095u);
}

// ---------- K3: P,Q = bf16((hn @ gcwb^T) * norm); async-staged weights ----------
__global__ __launch_bounds__(BDIM) void k3_pq_mfma(
    const unsigned short* __restrict__ hnb, const unsigned short* __restrict__ gcwb,
    const float* __restrict__ norm, unsigned short* __restrict__ P,
    unsigned short* __restrict__ Q) {
  __shared__ __align__(16) char abuf[2][24576];
  int t = threadIdx.x;
  int b = blockIdx.x / 98;
  int rem = blockIdx.x % 98;
  int n0 = (rem >> 1) * 64;
  int ch0 = (rem & 1) * 6;
  const unsigned short* hb = hnb + (size_t)b * NN * NC;
  int lane = t & 63, w = t >> 6;
  int l15 = lane & 15, l4 = lane >> 4;
  int n = n0 + w * 16 + l15;
  short8 bfr[6];
  {
    const short8* brow = (const short8*)(hb + (size_t)n * NC + l4 * 8);
#pragma unroll
    for (int ks = 0; ks < 6; ++ks) bfr[ks] = brow[ks * 4];
  }
  float nrm = norm[(size_t)b * NN + n];
  size_t orow = (size_t)b * NN + n;
  const char* wB = (const char*)gcwb;

  stage_tile(wB + (size_t)ch0 * 24576, abuf[0], w, lane);
  __syncthreads();
  for (int ci = 0; ci < 6; ++ci) {
    int ch = ch0 + ci;
    int cur = ci & 1;
    if (ci < 5) stage_tile(wB + (size_t)(ch + 1) * 24576, abuf[cur ^ 1], w, lane);
#pragma unroll
    for (int sub = 0; sub < 4; ++sub) {
      int mrow = sub * 16 + l15;
      int rbase = mrow * 384, sw = (mrow & 7) << 4;
      f32x4 acc = {0.f, 0.f, 0.f, 0.f};
#pragma unroll
      for (int ks = 0; ks < 6; ++ks) {
        short8 af = *(const short8*)&abuf[cur][rbase + ((ks * 64 + l4 * 16) ^ sw)];
        acc = __builtin_amdgcn_mfma_f32_16x16x32_bf16(af, bfr[ks], acc, 0, 0, 0);
      }
      int o = ch * 64 + sub * 16 + l4 * 4;
      f32x4 st = acc * nrm;
      unsigned short* dst = (o < NCH) ? P : Q;
      int oo = (o < NCH) ? o : o - NCH;
      uint2 u;
      u.x = (unsigned)f2bf(st[0]) | ((unsigned)f2bf(st[1]) << 16);
      u.y = (unsigned)f2bf(st[2]) | ((unsigned)f2bf(st[3]) << 16);
      *(uint2*)&dst[orow * NCH + oo] = u;
    }
    __syncthreads();
  }
}

// ---------- K4: m = bf16(gelu(P - Q + max_k Q[idx_k]  -> *sc2+sh2)), 2 cols/lane ----------
__global__ __launch_bounds__(BDIM) void k4_gathermax(
    const unsigned short* __restrict__ P, const unsigned short* __restrict__ Q,
    const int* __restrict__ idx, const float* __restrict__ sc2,
    const float* __restrict__ sh2, unsigned short* __restrict__ mbh) {
  int t = threadIdx.x;
  int lane = t & 63, wv = t >> 6;
  int row = blockIdx.x * 4 + wv;
  int b = row / NN, n = row % NN;
  const int* ip = idx + (size_t)row * NK;
  int id[NK];
#pragma unroll
  for (int k = 0; k < NK; ++k) id[k] = ip[k];
  const unsigned short* Qb = Q + (size_t)b * NN * NCH;
  const unsigned short* Pr = P + (size_t)row * NCH;
  const unsigned short* Qr = Qb + (size_t)n * NCH;
#pragma unroll
  for (int j = 0; j < 3; ++j) {
    int o = j * 128 + lane * 2;
    float mx0 = -1e30f, mx1 = -1e30f;
#pragma unroll
    for (int k = 0; k < NK; ++k) {
      unsigned g = *(const unsigned*)&Qb[(size_t)id[k] * NCH + o];
      mx0 = fmaxf(mx0, bf2f(g & 0xffffu));
      mx1 = fmaxf(mx1, bf2f(g >> 16));
    }
    unsigned pv = *(const unsigned*)&Pr[o];
    unsigned qv = *(const unsigned*)&Qr[o];
    float2 ss = *(const float2*)&sc2[o];
    float2 hh = *(const float2*)&sh2[o];
    float e0 = bf2f(pv & 0xffffu) - bf2f(qv & 0xffffu) + mx0;
    float e1 = bf2f(pv >> 16) - bf2f(qv >> 16) + mx1;
    float y0 = e0 * ss.x + hh.x;
    float y1 = e1 * ss.y + hh.y;
    float ge0 = 0.5f * y0 * (1.f + erff(y0 * 0.70710678118654752f));
    float ge1 = 0.5f * y1 * (1.f + erff(y1 * 0.70710678118654752f));
    *(unsigned*)&mbh[(size_t)row * NCH + o] =
        (unsigned)f2bf(ge0) | ((unsigned)f2bf(ge1) << 16);
  }
}

// ---------- K5: out = BN3(m @ fc2_w^T) + x via MFMA, direct [c][n] store ----------
// block: 64 n x 64 o (oc = 1 of 3), K=384 (2 staged tiles). No LDS transpose.
__global__ __launch_bounds__(BDIM) void k5_mfma(
    const unsigned short* __restrict__ mbh, const unsigned short* __restrict__ fc2b,
    const float* __restrict__ sc3, const float* __restrict__ sh3,
    const float* __restrict__ x, float* __restrict__ out) {
  __shared__ __align__(16) char abuf[2][24576];
  int t = threadIdx.x;
  int bid = blockIdx.x;
  int b = bid / 147;
  int rem = bid % 147;
  int n0 = (rem / 3) * 64;
  int oc = rem % 3;
  int lane = t & 63, w = t >> 6;
  int l15 = lane & 15, l4 = lane >> 4;
  int n = n0 + w * 16 + l15;
  short8 bfr[12];
  {
    const short8* brow = (const short8*)(mbh + (size_t)(b * NN + n) * NCH + l4 * 8);
#pragma unroll
    for (int kh = 0; kh < 2; ++kh)
#pragma unroll
      for (int ks = 0; ks < 6; ++ks) bfr[kh * 6 + ks] = brow[kh * 24 + ks * 4];
  }
  f32x4 acc[4];
#pragma unroll
  for (int sub = 0; sub < 4; ++sub) acc[sub] = {0.f, 0.f, 0.f, 0.f};

  const char* wt = (const char*)fc2b + (size_t)oc * 2 * 24576;
  stage_tile(wt, abuf[0], w, lane);
  __syncthreads();
  for (int kh = 0; kh < 2; ++kh) {
    if (kh == 0) stage_tile(wt + 24576, abuf[1], w, lane);
#pragma unroll
    for (int sub = 0; sub < 4; ++sub) {
      int r_ = sub * 16 + l15;
      int rbase = r_ * 384, sw = (r_ & 7) << 4;
#pragma unroll
      for (int ks = 0; ks < 6; ++ks) {
        short8 af = *(const short8*)&abuf[kh][rbase + ((ks * 64 + l4 * 16) ^ sw)];
        acc[sub] = __builtin_amdgcn_mfma_f32_16x16x32_bf16(af, bfr[kh * 6 + ks],
                                                           acc[sub], 0, 0, 0);
      }
    }
    __syncthreads();
  }
  const float* xb_ = x + (size_t)b * NC * NN;
  float* ob = out + (size_t)b * NC * NN;
#pragma unroll
  for (int sub = 0; sub < 4; ++sub) {
    int c4 = oc * 64 + sub * 16 + l4 * 4;
    float s_[4], h_[4];
    *(float4*)s_ = *(const float4*)&sc3[c4];
    *(float4*)h_ = *(const float4*)&sh3[c4];
#pragma unroll
    for (int r = 0; r < 4; ++r) {
      size_t off = (size_t)(c4 + r) * NN + n;
      ob[off] = acc[sub][r] * s_[r] + h_[r] + xb_[off];
    }
  }
}

extern "C" void kernel_launch(void* const* d_in, const int* in_sizes, int n_in,
                              void* d_out, int out_size, void* d_ws, size_t ws_size,
                              hipStream_t stream) {
  const float* x = (const float*)d_in[0];
  const float* fc1_w = (const float*)d_in[1];
  const float* fc1_b = (const float*)d_in[2];
  const float* bn1_g = (const float*)d_in[3];
  const float* bn1_b = (const float*)d_in[4];
  const float* bn1_m = (const float*)d_in[5];
  const float* bn1_v = (const float*)d_in[6];
  const float* gc_w = (const float*)d_in[7];
  const float* gc_b = (const float*)d_in[8];
  const float* bn2_g = (const float*)d_in[9];
  const float* bn2_b = (const float*)d_in[10];
  const float* bn2_m = (const float*)d_in[11];
  const float* bn2_v = (const float*)d_in[12];
  const float* fc2_w = (const float*)d_in[13];
  const float* fc2_b = (const float*)d_in[14];
  const float* bn3_g = (const float*)d_in[15];
  const float* bn3_b = (const float*)d_in[16];
  const float* bn3_m = (const float*)d_in[17];
  const float* bn3_v = (const float*)d_in[18];

  // workspace (~82 MB): Pb | Qb | mbh | norm | idx | hnb | xb | gcwb | fc1b |
  //                     fc2b | candK | sc/sh params
  size_t nrow = (size_t)NROW;
  size_t npq = (size_t)NB * NN * NCH;
  size_t nhb = (size_t)NB * NN * NC;
  unsigned short* Pb = (unsigned short*)d_ws;
  unsigned short* Qb = Pb + npq;
  unsigned short* mbh = Qb + npq;
  float* norm = (float*)(mbh + npq);
  int* idx = (int*)(norm + nrow);
  unsigned short* hnb = (unsigned short*)(idx + nrow * NK);
  unsigned short* xb = hnb + nhb;
  unsigned short* gcwb = xb + nhb;
  unsigned short* fc1b = gcwb + 768 * NC;
  unsigned short* fc2b = fc1b + NC * NC;
  unsigned* candK = (unsigned*)(fc2b + NC * NCH);
  float* sc1 = (float*)(candK + 2 * NK * nrow);
  float* sh1 = sc1 + NC;
  float* sc2 = sh1 + NC;
  float* sh2 = sc2 + NCH;
  float* sc3 = sh2 + NCH;
  float* sh3 = sc3 + NC;

  k0_convw<<<252, BDIM, 0, stream>>>(gc_w, fc1_w, fc2_w, gcwb, fc1b, fc2b);
  k0b_params<<<1, 384, 0, stream>>>(fc1_b, bn1_g, bn1_b, bn1_m, bn1_v, gc_b,
                                    bn2_g, bn2_b, bn2_m, bn2_v, fc2_b, bn3_g,
                                    bn3_b, bn3_m, bn3_v, sc1, sh1, sc2, sh2,
                                    sc3, sh3);
  kx_transpose<<<NB * 147, BDIM, 0, stream>>>(x, xb);
  k1_mfma<<<NB * 49, BDIM, 0, stream>>>(xb, fc1b, sc1, sh1, hnb, norm);
  k2a_topk<<<NB * 98, BDIM, 0, stream>>>(hnb, candK);
  k2b_merge<<<NROW / BDIM, BDIM, 0, stream>>>(candK, idx);
  k3_pq_mfma<<<NB * 98, BDIM, 0, stream>>>(hnb, gcwb, norm, Pb, Qb);
  k4_gathermax<<<(NB * NN) / 4, BDIM, 0, stream>>>(Pb, Qb, idx, sc2, sh2, mbh);
  k5_mfma<<<NB * 147, BDIM, 0, stream>>>(mbh, fc2b, sc3, sh3, x, (float*)d_out);
}

// Round 9
// 182.548 us; speedup vs baseline: 2.7453x; 1.0045x over previous
//
#include <hip/hip_runtime.h>

#define BDIM 256
#define NB 8
#define NC 192
#define NN 3136         // 56*56 = 49*64
#define NCH 384
#define NK 9
#define NROW (NB * NN)  // 25088

typedef __attribute__((ext_vector_type(8))) short short8;
typedef __attribute__((ext_vector_type(4))) float f32x4;

__device__ __forceinline__ unsigned short f2bf(float f) {
  union { float f; unsigned u; } x{f};
  unsigned r = x.u + 0x7fff + ((x.u >> 16) & 1);  // RNE
  return (unsigned short)(r >> 16);
}

__device__ __forceinline__ float bf2f(unsigned u16) {
  union { unsigned u; float f; } x{u16 << 16};
  return x.f;
}

// sortable-u32 transform of float bits: order-preserving for all finite values
__device__ __forceinline__ unsigned fsort(float f) {
  union { float f; unsigned u; } x{f};
  return x.u ^ ((unsigned)(((int)x.u) >> 31) | 0x80000000u);
}

// stage one 24KB [64 rows][384B] bf16 tile into LDS (async, width 16).
// LDS dest linear; global source pre-XOR-swizzled: LDS[m][kb] = G[m][kb^((m&7)<<4)].
__device__ __forceinline__ void stage_tile(const char* gbase, char* lbuf, int t) {
#pragma unroll
  for (int i = 0; i < 6; ++i) {
    int L = (i * 256 + t) * 16;
    int m = L / 384;
    int kb = L - m * 384;
    const char* g = gbase + m * 384 + (kb ^ ((m & 7) << 4));
    __builtin_amdgcn_global_load_lds(
        (const __attribute__((address_space(1))) unsigned int*)g,
        (__attribute__((address_space(3))) unsigned int*)(lbuf + L), 16, 0, 0);
  }
}

// 12KB variant: [32 rows][384B]
__device__ __forceinline__ void stage_tile32(const char* gbase, char* lbuf, int t) {
#pragma unroll
  for (int i = 0; i < 3; ++i) {
    int L = (i * 256 + t) * 16;
    int m = L / 384;
    int kb = L - m * 384;
    const char* g = gbase + m * 384 + (kb ^ ((m & 7) << 4));
    __builtin_amdgcn_global_load_lds(
        (const __attribute__((address_space(1))) unsigned int*)g,
        (__attribute__((address_space(3))) unsigned int*)(lbuf + L), 16, 0, 0);
  }
}

// ---------- K0: bf16 weight conversion ----------
__global__ __launch_bounds__(BDIM) void k0_convw(
    const float* __restrict__ gw, const float* __restrict__ f1w,
    const float* __restrict__ f2w, unsigned short* __restrict__ gcwb,
    unsigned short* __restrict__ fc1b, unsigned short* __restrict__ fc2b) {
  int i = (blockIdx.x * BDIM + threadIdx.x) * 4;
  const float* src;
  unsigned short* dst;
  if (i < 147456) {  // gc_w split
    int o = i / NC, k = i - o * NC;
    src = gw + (size_t)(o < NCH ? o : o - NCH) * (2 * NC) + (o < NCH ? 0 : NC) + k;
    dst = gcwb + i;
  } else if (i < 184320) {  // fc1
    int j = i - 147456;
    src = f1w + j;
    dst = fc1b + j;
  } else {  // fc2 retile [(oc*2+kh)][64][192]
    int j = i - 184320;
    int o = j / NCH, k = j - o * NCH;
    int oc = o >> 6, om = o & 63;
    int kh = k / 192, km = k - kh * 192;
    src = f2w + j;
    dst = fc2b + ((size_t)((oc * 2 + kh) * 64 + om)) * 192 + km;
  }
  float4 v = *(const float4*)src;
  uint2 u;
  u.x = (unsigned)f2bf(v.x) | ((unsigned)f2bf(v.y) << 16);
  u.y = (unsigned)f2bf(v.z) | ((unsigned)f2bf(v.w) << 16);
  *(uint2*)dst = u;
}

// ---------- K0b: fold BN params: val = gemm*sc + sh ----------
__global__ __launch_bounds__(384) void k0b_params(
    const float* __restrict__ f1b, const float* __restrict__ g1,
    const float* __restrict__ b1, const float* __restrict__ m1,
    const float* __restrict__ v1, const float* __restrict__ gcb,
    const float* __restrict__ g2, const float* __restrict__ b2,
    const float* __restrict__ m2, const float* __restrict__ v2,
    const float* __restrict__ f2b, const float* __restrict__ g3,
    const float* __restrict__ b3, const float* __restrict__ m3,
    const float* __restrict__ v3, float* __restrict__ sc1,
    float* __restrict__ sh1, float* __restrict__ sc2, float* __restrict__ sh2,
    float* __restrict__ sc3, float* __restrict__ sh3) {
  int c = threadIdx.x;
  if (c < NC) {
    float s1 = g1[c] * rsqrtf(v1[c] + 1e-5f);
    sc1[c] = s1;
    sh1[c] = (f1b[c] - m1[c]) * s1 + b1[c];
    float s3 = g3[c] * rsqrtf(v3[c] + 1e-5f);
    sc3[c] = s3;
    sh3[c] = (f2b[c] - m3[c]) * s3 + b3[c];
  }
  float s2 = g2[c] * rsqrtf(v2[c] + 1e-5f);
  sc2[c] = s2;
  sh2[c] = (gcb[c] - m2[c]) * s2 + b2[c];
}

// ---------- K1: h = BN1(x @ fc1_w^T) via MFMA; x read directly (fused transpose) ----------
__global__ __launch_bounds__(BDIM) void k1_mfma(
    const float* __restrict__ x, const unsigned short* __restrict__ fc1b,
    const float* __restrict__ sc1, const float* __restrict__ sh1,
    unsigned short* __restrict__ hnb, float* __restrict__ normo) {
  __shared__ __align__(16) char abuf[2][24576];
  int t = threadIdx.x;
  int b = blockIdx.x / 49, n0 = (blockIdx.x % 49) * 64;
  int lane = t & 63, w = t >> 6;
  int l15 = lane & 15, l4 = lane >> 4;
  int n = n0 + w * 16 + l15;
  // B frag from x[b][c][n] column n, RNE to bf16 (identical to old kx path)
  short8 bfr[6];
  {
    const float* xcol = x + (size_t)b * NC * NN + n;
#pragma unroll
    for (int ks = 0; ks < 6; ++ks) {
      union { short8 s; unsigned u[4]; } pk;
#pragma unroll
      for (int j = 0; j < 4; ++j) {
        float v0 = xcol[(size_t)(ks * 32 + l4 * 8 + 2 * j) * NN];
        float v1 = xcol[(size_t)(ks * 32 + l4 * 8 + 2 * j + 1) * NN];
        pk.u[j] = (unsigned)f2bf(v0) | ((unsigned)f2bf(v1) << 16);
      }
      bfr[ks] = pk.s;
    }
  }
  f32x4 acc[3][4];
#pragma unroll
  for (int oc = 0; oc < 3; ++oc)
#pragma unroll
    for (int sub = 0; sub < 4; ++sub) acc[oc][sub] = {0.f, 0.f, 0.f, 0.f};

  const char* wB = (const char*)fc1b;
  stage_tile(wB, abuf[0], t);
  __syncthreads();
  for (int oc = 0; oc < 3; ++oc) {
    int cur = oc & 1;
    if (oc < 2) stage_tile(wB + (size_t)(oc + 1) * 24576, abuf[cur ^ 1], t);
#pragma unroll
    for (int sub = 0; sub < 4; ++sub) {
      int r_ = sub * 16 + l15;
      int rbase = r_ * 384, sw = (r_ & 7) << 4;
#pragma unroll
      for (int ks = 0; ks < 6; ++ks) {
        short8 af = *(const short8*)&abuf[cur][rbase + ((ks * 64 + l4 * 16) ^ sw)];
        acc[oc][sub] = __builtin_amdgcn_mfma_f32_16x16x32_bf16(af, bfr[ks],
                                                               acc[oc][sub], 0, 0, 0);
      }
    }
    __syncthreads();
  }
  float p = 0.f;
#pragma unroll
  for (int oc = 0; oc < 3; ++oc)
#pragma unroll
    for (int sub = 0; sub < 4; ++sub) {
      int c4 = oc * 64 + sub * 16 + l4 * 4;
      float s_[4], h_[4];
      *(float4*)s_ = *(const float4*)&sc1[c4];
      *(float4*)h_ = *(const float4*)&sh1[c4];
#pragma unroll
      for (int r = 0; r < 4; ++r) {
        float v = acc[oc][sub][r] * s_[r] + h_[r];
        acc[oc][sub][r] = v;
        p += v * v;
      }
    }
  p += __shfl_xor(p, 16);
  p += __shfl_xor(p, 32);
  float nr = fmaxf(sqrtf(p), 1e-12f);
  float iv = 1.f / nr;
  if (l4 == 0) normo[(size_t)b * NN + n] = nr;
#pragma unroll
  for (int oc = 0; oc < 3; ++oc)
#pragma unroll
    for (int sub = 0; sub < 4; ++sub) {
      uint2 u;
      u.x = (unsigned)f2bf(acc[oc][sub][0] * iv) |
            ((unsigned)f2bf(acc[oc][sub][1] * iv) << 16);
      u.y = (unsigned)f2bf(acc[oc][sub][2] * iv) |
            ((unsigned)f2bf(acc[oc][sub][3] * iv) << 16);
      *(uint2*)&hnb[(size_t)(b * NN + n) * NC + oc * 64 + sub * 16 + l4 * 4] = u;
    }
}

// ---------- K2a: sim top-9 via MFMA; 32-row tiles (24KB LDS total, 6 blocks/CU) ----------
__global__ __launch_bounds__(BDIM) void k2a_topk(
    const unsigned short* __restrict__ hnb, unsigned* __restrict__ candK) {
  __shared__ __align__(16) char abuf[2][12288];
  int t = threadIdx.x;
  int bid = blockIdx.x;
  int b = bid & 7;          // batch -> XCD L2 pin
  int rem = bid >> 3;       // 0..97
  int n0 = (rem >> 1) * 64;
  int seg = rem & 1;
  int mt0 = seg * 49;       // 98 tiles of 32 m-rows total
  const unsigned short* hb = hnb + (size_t)b * NN * NC;
  const char* hbB = (const char*)hb;
  int lane = t & 63, w = t >> 6;
  int l15 = lane & 15, l4 = lane >> 4;

  short8 bfr[6];
  {
    const short8* brow = (const short8*)(hb + (size_t)(n0 + w * 16 + l15) * NC + l4 * 8);
#pragma unroll
    for (int ks = 0; ks < 6; ++ks) bfr[ks] = brow[ks * 4];
  }
  unsigned tk[NK];
#pragma unroll
  for (int r = 0; r < NK; ++r) tk[r] = 0u;

  stage_tile32(hbB + (size_t)mt0 * 12288, abuf[0], t);
  __syncthreads();
  for (int ti = 0; ti < 49; ++ti) {
    int cur = ti & 1;
    if (ti < 48)
      stage_tile32(hbB + (size_t)(mt0 + ti + 1) * 12288, abuf[cur ^ 1], t);
    int mglob = (mt0 + ti) * 32;
#pragma unroll
    for (int sub = 0; sub < 2; ++sub) {
      int r_ = sub * 16 + l15;
      int rbase = r_ * 384, sw = (r_ & 7) << 4;
      short8 af[6];
#pragma unroll
      for (int ks = 0; ks < 6; ++ks)
        af[ks] = *(const short8*)&abuf[cur][rbase + ((ks * 64 + l4 * 16) ^ sw)];
      f32x4 acc = {0.f, 0.f, 0.f, 0.f};
#pragma unroll
      for (int ks = 0; ks < 6; ++ks)
        acc = __builtin_amdgcn_mfma_f32_16x16x32_bf16(af[ks], bfr[ks], acc, 0, 0, 0);
      int mknd = 4095 - (mglob + sub * 16 + l4 * 4);
#pragma unroll
      for (int r = 0; r < 4; ++r) {
        unsigned cur_k = (fsort(acc[r]) & 0xFFFFF000u) | (unsigned)(mknd - r);
#pragma unroll
        for (int j = 0; j < NK; ++j) {
          unsigned hi = tk[j] > cur_k ? tk[j] : cur_k;
          unsigned lo = tk[j] > cur_k ? cur_k : tk[j];
          tk[j] = hi;
          cur_k = lo;
        }
      }
    }
    __syncthreads();
  }
  unsigned* mkeys = (unsigned*)&abuf[0][0];  // 64 rows x 4 lists x 9 = 9216B
  int nl = w * 16 + l15;
#pragma unroll
  for (int r = 0; r < NK; ++r) mkeys[(nl * 4 + l4) * NK + r] = tk[r];
  __syncthreads();
  if (t < 64) {
    const unsigned* src = &mkeys[t * 4 * NK];
    unsigned best[NK];
#pragma unroll
    for (int r = 0; r < NK; ++r) best[r] = 0u;
    for (int s = 0; s < 36; ++s) {
      unsigned cur_k = src[s];
#pragma unroll
      for (int q = 0; q < NK; ++q) {
        unsigned hi = best[q] > cur_k ? best[q] : cur_k;
        unsigned lo = best[q] > cur_k ? cur_k : best[q];
        best[q] = hi;
        cur_k = lo;
      }
    }
    size_t row = (size_t)b * NN + n0 + t;
#pragma unroll
    for (int r = 0; r < NK; ++r) candK[(size_t)(seg * NK + r) * NROW + row] = best[r];
  }
}

// ---------- K2b: merge 2x9 keys/row -> final top-9 indices ----------
__global__ __launch_bounds__(BDIM) void k2b_merge(const unsigned* __restrict__ candK,
                                                  int* __restrict__ idxo) {
  int row = blockIdx.x * BDIM + threadIdx.x;
  unsigned tk[NK];
#pragma unroll
  for (int r = 0; r < NK; ++r) tk[r] = 0u;
  for (int s = 0; s < 2 * NK; ++s) {
    unsigned cur = candK[(size_t)s * NROW + row];
#pragma unroll
    for (int j = 0; j < NK; ++j) {
      unsigned hi = tk[j] > cur ? tk[j] : cur;
      unsigned lo = tk[j] > cur ? cur : tk[j];
      tk[j] = hi;
      cur = lo;
    }
  }
#pragma unroll
  for (int r = 0; r < NK; ++r)
    idxo[(size_t)row * NK + r] = 4095 - (int)(tk[r] & 4095u);
}

// ---------- K3: P,Q = bf16((hn @ gcwb^T) * norm); async-staged weights ----------
__global__ __launch_bounds__(BDIM) void k3_pq_mfma(
    const unsigned short* __restrict__ hnb, const unsigned short* __restrict__ gcwb,
    const float* __restrict__ norm, unsigned short* __restrict__ P,
    unsigned short* __restrict__ Q) {
  __shared__ __align__(16) char abuf[2][24576];
  int t = threadIdx.x;
  int b = blockIdx.x / 98;
  int rem = blockIdx.x % 98;
  int n0 = (rem >> 1) * 64;
  int ch0 = (rem & 1) * 6;
  const unsigned short* hb = hnb + (size_t)b * NN * NC;
  int lane = t & 63, w = t >> 6;
  int l15 = lane & 15, l4 = lane >> 4;
  int n = n0 + w * 16 + l15;
  short8 bfr[6];
  {
    const short8* brow = (const short8*)(hb + (size_t)n * NC + l4 * 8);
#pragma unroll
    for (int ks = 0; ks < 6; ++ks) bfr[ks] = brow[ks * 4];
  }
  float nrm = norm[(size_t)b * NN + n];
  size_t orow = (size_t)b * NN + n;
  const char* wB = (const char*)gcwb;

  stage_tile(wB + (size_t)ch0 * 24576, abuf[0], t);
  __syncthreads();
  for (int ci = 0; ci < 6; ++ci) {
    int ch = ch0 + ci;
    int cur = ci & 1;
    if (ci < 5) stage_tile(wB + (size_t)(ch + 1) * 24576, abuf[cur ^ 1], t);
#pragma unroll
    for (int sub = 0; sub < 4; ++sub) {
      int mrow = sub * 16 + l15;
      int rbase = mrow * 384, sw = (mrow & 7) << 4;
      f32x4 acc = {0.f, 0.f, 0.f, 0.f};
#pragma unroll
      for (int ks = 0; ks < 6; ++ks) {
        short8 af = *(const short8*)&abuf[cur][rbase + ((ks * 64 + l4 * 16) ^ sw)];
        acc = __builtin_amdgcn_mfma_f32_16x16x32_bf16(af, bfr[ks], acc, 0, 0, 0);
      }
      int o = ch * 64 + sub * 16 + l4 * 4;
      f32x4 st = acc * nrm;
      unsigned short* dst = (o < NCH) ? P : Q;
      int oo = (o < NCH) ? o : o - NCH;
      uint2 u;
      u.x = (unsigned)f2bf(st[0]) | ((unsigned)f2bf(st[1]) << 16);
      u.y = (unsigned)f2bf(st[2]) | ((unsigned)f2bf(st[3]) << 16);
      *(uint2*)&dst[orow * NCH + oo] = u;
    }
    __syncthreads();
  }
}

// ---------- K4: m = bf16(gelu((P - Q + max_k Q[idx_k])*sc2+sh2)), 2 cols/lane ----------
__global__ __launch_bounds__(BDIM) void k4_gathermax(
    const unsigned short* __restrict__ P, const unsigned short* __restrict__ Q,
    const int* __restrict__ idx, const float* __restrict__ sc2,
    const float* __restrict__ sh2, unsigned short* __restrict__ mbh) {
  int t = threadIdx.x;
  int lane = t & 63, wv = t >> 6;
  int row = blockIdx.x * 4 + wv;
  int b = row / NN, n = row % NN;
  const int* ip = idx + (size_t)row * NK;
  int id[NK];
#pragma unroll
  for (int k = 0; k < NK; ++k) id[k] = ip[k];
  const unsigned short* Qb = Q + (size_t)b * NN * NCH;
  const unsigned short* Pr = P + (size_t)row * NCH;
  const unsigned short* Qr = Qb + (size_t)n * NCH;
#pragma unroll
  for (int j = 0; j < 3; ++j) {
    int o = j * 128 + lane * 2;
    float mx0 = -1e30f, mx1 = -1e30f;
#pragma unroll
    for (int k = 0; k < NK; ++k) {
      unsigned g = *(const unsigned*)&Qb[(size_t)id[k] * NCH + o];
      mx0 = fmaxf(mx0, bf2f(g & 0xffffu));
      mx1 = fmaxf(mx1, bf2f(g >> 16));
    }
    unsigned pv = *(const unsigned*)&Pr[o];
    unsigned qv = *(const unsigned*)&Qr[o];
    float2 ss = *(const float2*)&sc2[o];
    float2 hh = *(const float2*)&sh2[o];
    float e0 = bf2f(pv & 0xffffu) - bf2f(qv & 0xffffu) + mx0;
    float e1 = bf2f(pv >> 16) - bf2f(qv >> 16) + mx1;
    float y0 = e0 * ss.x + hh.x;
    float y1 = e1 * ss.y + hh.y;
    float ge0 = 0.5f * y0 * (1.f + erff(y0 * 0.70710678118654752f));
    float ge1 = 0.5f * y1 * (1.f + erff(y1 * 0.70710678118654752f));
    *(unsigned*)&mbh[(size_t)row * NCH + o] =
        (unsigned)f2bf(ge0) | ((unsigned)f2bf(ge1) << 16);
  }
}

// ---------- K5: out = BN3(m @ fc2_w^T) + x via MFMA, direct [c][n] store ----------
__global__ __launch_bounds__(BDIM) void k5_mfma(
    const unsigned short* __restrict__ mbh, const unsigned short* __restrict__ fc2b,
    const float* __restrict__ sc3, const float* __restrict__ sh3,
    const float* __restrict__ x, float* __restrict__ out) {
  __shared__ __align__(16) char abuf[2][24576];
  int t = threadIdx.x;
  int bid = blockIdx.x;
  int b = bid / 147;
  int rem = bid % 147;
  int n0 = (rem / 3) * 64;
  int oc = rem % 3;
  int lane = t & 63, w = t >> 6;
  int l15 = lane & 15, l4 = lane >> 4;
  int n = n0 + w * 16 + l15;
  short8 bfr[12];
  {
    const short8* brow = (const short8*)(mbh + (size_t)(b * NN + n) * NCH + l4 * 8);
#pragma unroll
    for (int kh = 0; kh < 2; ++kh)
#pragma unroll
      for (int ks = 0; ks < 6; ++ks) bfr[kh * 6 + ks] = brow[kh * 24 + ks * 4];
  }
  f32x4 acc[4];
#pragma unroll
  for (int sub = 0; sub < 4; ++sub) acc[sub] = {0.f, 0.f, 0.f, 0.f};

  const char* wt = (const char*)fc2b + (size_t)oc * 2 * 24576;
  stage_tile(wt, abuf[0], t);
  __syncthreads();
  for (int kh = 0; kh < 2; ++kh) {
    if (kh == 0) stage_tile(wt + 24576, abuf[1], t);
#pragma unroll
    for (int sub = 0; sub < 4; ++sub) {
      int r_ = sub * 16 + l15;
      int rbase = r_ * 384, sw = (r_ & 7) << 4;
#pragma unroll
      for (int ks = 0; ks < 6; ++ks) {
        short8 af = *(const short8*)&abuf[kh][rbase + ((ks * 64 + l4 * 16) ^ sw)];
        acc[sub] = __builtin_amdgcn_mfma_f32_16x16x32_bf16(af, bfr[kh * 6 + ks],
                                                           acc[sub], 0, 0, 0);
      }
    }
    __syncthreads();
  }
  const float* xb_ = x + (size_t)b * NC * NN;
  float* ob = out + (size_t)b * NC * NN;
#pragma unroll
  for (int sub = 0; sub < 4; ++sub) {
    int c4 = oc * 64 + sub * 16 + l4 * 4;
    float s_[4], h_[4];
    *(float4*)s_ = *(const float4*)&sc3[c4];
    *(float4*)h_ = *(const float4*)&sh3[c4];
#pragma unroll
    for (int r = 0; r < 4; ++r) {
      size_t off = (size_t)(c4 + r) * NN + n;
      ob[off] = acc[sub][r] * s_[r] + h_[r] + xb_[off];
    }
  }
}

extern "C" void kernel_launch(void* const* d_in, const int* in_sizes, int n_in,
                              void* d_out, int out_size, void* d_ws, size_t ws_size,
                              hipStream_t stream) {
  const float* x = (const float*)d_in[0];
  const float* fc1_w = (const float*)d_in[1];
  const float* fc1_b = (const float*)d_in[2];
  const float* bn1_g = (const float*)d_in[3];
  const float* bn1_b = (const float*)d_in[4];
  const float* bn1_m = (const float*)d_in[5];
  const float* bn1_v = (const float*)d_in[6];
  const float* gc_w = (const float*)d_in[7];
  const float* gc_b = (const float*)d_in[8];
  const float* bn2_g = (const float*)d_in[9];
  const float* bn2_b = (const float*)d_in[10];
  const float* bn2_m = (const float*)d_in[11];
  const float* bn2_v = (const float*)d_in[12];
  const float* fc2_w = (const float*)d_in[13];
  const float* fc2_b = (const float*)d_in[14];
  const float* bn3_g = (const float*)d_in[15];
  const float* bn3_b = (const float*)d_in[16];
  const float* bn3_m = (const float*)d_in[17];
  const float* bn3_v = (const float*)d_in[18];

  size_t nrow = (size_t)NROW;
  size_t npq = (size_t)NB * NN * NCH;
  size_t nhb = (size_t)NB * NN * NC;
  unsigned short* Pb = (unsigned short*)d_ws;
  unsigned short* Qb = Pb + npq;
  unsigned short* mbh = Qb + npq;
  float* norm = (float*)(mbh + npq);
  int* idx = (int*)(norm + nrow);
  unsigned short* hnb = (unsigned short*)(idx + nrow * NK);
  unsigned short* gcwb = hnb + nhb;
  unsigned short* fc1b = gcwb + 768 * NC;
  unsigned short* fc2b = fc1b + NC * NC;
  unsigned* candK = (unsigned*)(fc2b + NC * NCH);
  float* sc1 = (float*)(candK + 2 * NK * nrow);
  float* sh1 = sc1 + NC;
  float* sc2 = sh1 + NC;
  float* sh2 = sc2 + NCH;
  float* sc3 = sh2 + NCH;
  float* sh3 = sc3 + NC;

  k0_convw<<<252, BDIM, 0, stream>>>(gc_w, fc1_w, fc2_w, gcwb, fc1b, fc2b);
  k0b_params<<<1, 384, 0, stream>>>(fc1_b, bn1_g, bn1_b, bn1_m, bn1_v, gc_b,
                                    bn2_g, bn2_b, bn2_m, bn2_v, fc2_b, bn3_g,
                                    bn3_b, bn3_m, bn3_v, sc1, sh1, sc2, sh2,
                                    sc3, sh3);
  k1_mfma<<<NB * 49, BDIM, 0, stream>>>(x, fc1b, sc1, sh1, hnb, norm);
  k2a_topk<<<NB * 98, BDIM, 0, stream>>>(hnb, candK);
  k2b_merge<<<NROW / BDIM, BDIM, 0, stream>>>(candK, idx);
  k3_pq_mfma<<<NB * 98, BDIM, 0, stream>>>(hnb, gcwb, norm, Pb, Qb);
  k4_gathermax<<<(NB * NN) / 4, BDIM, 0, stream>>>(Pb, Qb, idx, sc2, sh2, mbh);
  k5_mfma<<<NB * 147, BDIM, 0, stream>>>(mbh, fc2b, sc3, sh3, x, (float*)d_out);
}

// Round 10
// 175.977 us; speedup vs baseline: 2.8477x; 1.0373x over previous
//
#include <hip/hip_runtime.h>

#define BDIM 256
#define NB 8
#define NC 192
#define NN 3136         // 56*56 = 49*64
#define NCH 384
#define NK 9
#define NROW (NB * NN)  // 25088

typedef __attribute__((ext_vector_type(8))) short short8;
typedef __attribute__((ext_vector_type(4))) float f32x4;

__device__ __forceinline__ unsigned short f2bf(float f) {
  union { float f; unsigned u; } x{f};
  unsigned r = x.u + 0x7fff + ((x.u >> 16) & 1);  // RNE
  return (unsigned short)(r >> 16);
}

__device__ __forceinline__ float bf2f(unsigned u16) {
  union { unsigned u; float f; } x{u16 << 16};
  return x.f;
}

// sortable-u32 transform of float bits: order-preserving for all finite values
__device__ __forceinline__ unsigned fsort(float f) {
  union { float f; unsigned u; } x{f};
  return x.u ^ ((unsigned)(((int)x.u) >> 31) | 0x80000000u);
}

// stage one 24KB [64 rows][384B] bf16 tile into LDS (async, width 16).
// LDS dest linear; global source pre-XOR-swizzled: LDS[m][kb] = G[m][kb^((m&7)<<4)].
__device__ __forceinline__ void stage_tile(const char* gbase, char* lbuf, int t) {
#pragma unroll
  for (int i = 0; i < 6; ++i) {
    int L = (i * 256 + t) * 16;
    int m = L / 384;
    int kb = L - m * 384;
    const char* g = gbase + m * 384 + (kb ^ ((m & 7) << 4));
    __builtin_amdgcn_global_load_lds(
        (const __attribute__((address_space(1))) unsigned int*)g,
        (__attribute__((address_space(3))) unsigned int*)(lbuf + L), 16, 0, 0);
  }
}

// 12KB variant: [32 rows][384B]
__device__ __forceinline__ void stage_tile32(const char* gbase, char* lbuf, int t) {
#pragma unroll
  for (int i = 0; i < 3; ++i) {
    int L = (i * 256 + t) * 16;
    int m = L / 384;
    int kb = L - m * 384;
    const char* g = gbase + m * 384 + (kb ^ ((m & 7) << 4));
    __builtin_amdgcn_global_load_lds(
        (const __attribute__((address_space(1))) unsigned int*)g,
        (__attribute__((address_space(3))) unsigned int*)(lbuf + L), 16, 0, 0);
  }
}

// ---------- K0: bf16 weight conversion ----------
__global__ __launch_bounds__(BDIM) void k0_convw(
    const float* __restrict__ gw, const float* __restrict__ f1w,
    const float* __restrict__ f2w, unsigned short* __restrict__ gcwb,
    unsigned short* __restrict__ fc1b, unsigned short* __restrict__ fc2b) {
  int i = (blockIdx.x * BDIM + threadIdx.x) * 4;
  const float* src;
  unsigned short* dst;
  if (i < 147456) {  // gc_w split
    int o = i / NC, k = i - o * NC;
    src = gw + (size_t)(o < NCH ? o : o - NCH) * (2 * NC) + (o < NCH ? 0 : NC) + k;
    dst = gcwb + i;
  } else if (i < 184320) {  // fc1
    int j = i - 147456;
    src = f1w + j;
    dst = fc1b + j;
  } else {  // fc2 retile [(oc*2+kh)][64][192]
    int j = i - 184320;
    int o = j / NCH, k = j - o * NCH;
    int oc = o >> 6, om = o & 63;
    int kh = k / 192, km = k - kh * 192;
    src = f2w + j;
    dst = fc2b + ((size_t)((oc * 2 + kh) * 64 + om)) * 192 + km;
  }
  float4 v = *(const float4*)src;
  uint2 u;
  u.x = (unsigned)f2bf(v.x) | ((unsigned)f2bf(v.y) << 16);
  u.y = (unsigned)f2bf(v.z) | ((unsigned)f2bf(v.w) << 16);
  *(uint2*)dst = u;
}

// ---------- K0b: fold BN params: val = gemm*sc + sh ----------
__global__ __launch_bounds__(384) void k0b_params(
    const float* __restrict__ f1b, const float* __restrict__ g1,
    const float* __restrict__ b1, const float* __restrict__ m1,
    const float* __restrict__ v1, const float* __restrict__ gcb,
    const float* __restrict__ g2, const float* __restrict__ b2,
    const float* __restrict__ m2, const float* __restrict__ v2,
    const float* __restrict__ f2b, const float* __restrict__ g3,
    const float* __restrict__ b3, const float* __restrict__ m3,
    const float* __restrict__ v3, float* __restrict__ sc1,
    float* __restrict__ sh1, float* __restrict__ sc2, float* __restrict__ sh2,
    float* __restrict__ sc3, float* __restrict__ sh3) {
  int c = threadIdx.x;
  if (c < NC) {
    float s1 = g1[c] * rsqrtf(v1[c] + 1e-5f);
    sc1[c] = s1;
    sh1[c] = (f1b[c] - m1[c]) * s1 + b1[c];
    float s3 = g3[c] * rsqrtf(v3[c] + 1e-5f);
    sc3[c] = s3;
    sh3[c] = (f2b[c] - m3[c]) * s3 + b3[c];
  }
  float s2 = g2[c] * rsqrtf(v2[c] + 1e-5f);
  sc2[c] = s2;
  sh2[c] = (gcb[c] - m2[c]) * s2 + b2[c];
}

// ---------- K1: h = BN1(x @ fc1_w^T) via MFMA; x read directly (fused transpose) ----------
__global__ __launch_bounds__(BDIM) void k1_mfma(
    const float* __restrict__ x, const unsigned short* __restrict__ fc1b,
    const float* __restrict__ sc1, const float* __restrict__ sh1,
    unsigned short* __restrict__ hnb, float* __restrict__ normo) {
  __shared__ __align__(16) char abuf[2][24576];
  int t = threadIdx.x;
  int b = blockIdx.x / 49, n0 = (blockIdx.x % 49) * 64;
  int lane = t & 63, w = t >> 6;
  int l15 = lane & 15, l4 = lane >> 4;
  int n = n0 + w * 16 + l15;
  short8 bfr[6];
  {
    const float* xcol = x + (size_t)b * NC * NN + n;
#pragma unroll
    for (int ks = 0; ks < 6; ++ks) {
      union { short8 s; unsigned u[4]; } pk;
#pragma unroll
      for (int j = 0; j < 4; ++j) {
        float v0 = xcol[(size_t)(ks * 32 + l4 * 8 + 2 * j) * NN];
        float v1 = xcol[(size_t)(ks * 32 + l4 * 8 + 2 * j + 1) * NN];
        pk.u[j] = (unsigned)f2bf(v0) | ((unsigned)f2bf(v1) << 16);
      }
      bfr[ks] = pk.s;
    }
  }
  f32x4 acc[3][4];
#pragma unroll
  for (int oc = 0; oc < 3; ++oc)
#pragma unroll
    for (int sub = 0; sub < 4; ++sub) acc[oc][sub] = {0.f, 0.f, 0.f, 0.f};

  const char* wB = (const char*)fc1b;
  stage_tile(wB, abuf[0], t);
  __syncthreads();
  for (int oc = 0; oc < 3; ++oc) {
    int cur = oc & 1;
    if (oc < 2) stage_tile(wB + (size_t)(oc + 1) * 24576, abuf[cur ^ 1], t);
#pragma unroll
    for (int sub = 0; sub < 4; ++sub) {
      int r_ = sub * 16 + l15;
      int rbase = r_ * 384, sw = (r_ & 7) << 4;
#pragma unroll
      for (int ks = 0; ks < 6; ++ks) {
        short8 af = *(const short8*)&abuf[cur][rbase + ((ks * 64 + l4 * 16) ^ sw)];
        acc[oc][sub] = __builtin_amdgcn_mfma_f32_16x16x32_bf16(af, bfr[ks],
                                                               acc[oc][sub], 0, 0, 0);
      }
    }
    __syncthreads();
  }
  float p = 0.f;
#pragma unroll
  for (int oc = 0; oc < 3; ++oc)
#pragma unroll
    for (int sub = 0; sub < 4; ++sub) {
      int c4 = oc * 64 + sub * 16 + l4 * 4;
      float s_[4], h_[4];
      *(float4*)s_ = *(const float4*)&sc1[c4];
      *(float4*)h_ = *(const float4*)&sh1[c4];
#pragma unroll
      for (int r = 0; r < 4; ++r) {
        float v = acc[oc][sub][r] * s_[r] + h_[r];
        acc[oc][sub][r] = v;
        p += v * v;
      }
    }
  p += __shfl_xor(p, 16);
  p += __shfl_xor(p, 32);
  float nr = fmaxf(sqrtf(p), 1e-12f);
  float iv = 1.f / nr;
  if (l4 == 0) normo[(size_t)b * NN + n] = nr;
#pragma unroll
  for (int oc = 0; oc < 3; ++oc)
#pragma unroll
    for (int sub = 0; sub < 4; ++sub) {
      uint2 u;
      u.x = (unsigned)f2bf(acc[oc][sub][0] * iv) |
            ((unsigned)f2bf(acc[oc][sub][1] * iv) << 16);
      u.y = (unsigned)f2bf(acc[oc][sub][2] * iv) |
            ((unsigned)f2bf(acc[oc][sub][3] * iv) << 16);
      *(uint2*)&hnb[(size_t)(b * NN + n) * NC + oc * 64 + sub * 16 + l4 * 4] = u;
    }
}

// ---------- K2a: sim top-9 via MFMA; 32-row tiles, m-split 4 (grid 1568) ----------
__global__ __launch_bounds__(BDIM) void k2a_topk(
    const unsigned short* __restrict__ hnb, unsigned* __restrict__ candK) {
  __shared__ __align__(16) char abuf[2][12288];
  int t = threadIdx.x;
  int bid = blockIdx.x;
  int b = bid & 7;          // batch -> XCD L2 pin
  int g = bid >> 3;         // 0..195
  int n0 = (g >> 2) * 64;
  int seg = g & 3;
  int mt0 = (98 * seg) / 4, mt1 = (98 * (seg + 1)) / 4;  // 24/25-tile ranges
  const unsigned short* hb = hnb + (size_t)b * NN * NC;
  const char* hbB = (const char*)hb;
  int lane = t & 63, w = t >> 6;
  int l15 = lane & 15, l4 = lane >> 4;

  short8 bfr[6];
  {
    const short8* brow = (const short8*)(hb + (size_t)(n0 + w * 16 + l15) * NC + l4 * 8);
#pragma unroll
    for (int ks = 0; ks < 6; ++ks) bfr[ks] = brow[ks * 4];
  }
  unsigned tk[NK];
#pragma unroll
  for (int r = 0; r < NK; ++r) tk[r] = 0u;

  stage_tile32(hbB + (size_t)mt0 * 12288, abuf[0], t);
  __syncthreads();
  int nt = mt1 - mt0;
  for (int ti = 0; ti < nt; ++ti) {
    int cur = ti & 1;
    if (ti + 1 < nt)
      stage_tile32(hbB + (size_t)(mt0 + ti + 1) * 12288, abuf[cur ^ 1], t);
    int mglob = (mt0 + ti) * 32;
#pragma unroll
    for (int sub = 0; sub < 2; ++sub) {
      int r_ = sub * 16 + l15;
      int rbase = r_ * 384, sw = (r_ & 7) << 4;
      short8 af[6];
#pragma unroll
      for (int ks = 0; ks < 6; ++ks)
        af[ks] = *(const short8*)&abuf[cur][rbase + ((ks * 64 + l4 * 16) ^ sw)];
      f32x4 acc = {0.f, 0.f, 0.f, 0.f};
#pragma unroll
      for (int ks = 0; ks < 6; ++ks)
        acc = __builtin_amdgcn_mfma_f32_16x16x32_bf16(af[ks], bfr[ks], acc, 0, 0, 0);
      int mknd = 4095 - (mglob + sub * 16 + l4 * 4);
#pragma unroll
      for (int r = 0; r < 4; ++r) {
        unsigned cur_k = (fsort(acc[r]) & 0xFFFFF000u) | (unsigned)(mknd - r);
#pragma unroll
        for (int j = 0; j < NK; ++j) {
          unsigned hi = tk[j] > cur_k ? tk[j] : cur_k;
          unsigned lo = tk[j] > cur_k ? cur_k : tk[j];
          tk[j] = hi;
          cur_k = lo;
        }
      }
    }
    __syncthreads();
  }
  unsigned* mkeys = (unsigned*)&abuf[0][0];  // 64 rows x 4 lists x 9 = 9216B
  int nl = w * 16 + l15;
#pragma unroll
  for (int r = 0; r < NK; ++r) mkeys[(nl * 4 + l4) * NK + r] = tk[r];
  __syncthreads();
  if (t < 64) {
    const unsigned* src = &mkeys[t * 4 * NK];
    unsigned best[NK];
#pragma unroll
    for (int r = 0; r < NK; ++r) best[r] = 0u;
    for (int s = 0; s < 36; ++s) {
      unsigned cur_k = src[s];
#pragma unroll
      for (int q = 0; q < NK; ++q) {
        unsigned hi = best[q] > cur_k ? best[q] : cur_k;
        unsigned lo = best[q] > cur_k ? cur_k : best[q];
        best[q] = hi;
        cur_k = lo;
      }
    }
    size_t row = (size_t)b * NN + n0 + t;
#pragma unroll
    for (int r = 0; r < NK; ++r) candK[(size_t)(seg * NK + r) * NROW + row] = best[r];
  }
}

// ---------- K2b: merge 4x9 keys/row -> final top-9 indices ----------
__global__ __launch_bounds__(BDIM) void k2b_merge(const unsigned* __restrict__ candK,
                                                  int* __restrict__ idxo) {
  int row = blockIdx.x * BDIM + threadIdx.x;
  unsigned tk[NK];
#pragma unroll
  for (int r = 0; r < NK; ++r) tk[r] = 0u;
  for (int s = 0; s < 4 * NK; ++s) {
    unsigned cur = candK[(size_t)s * NROW + row];
#pragma unroll
    for (int j = 0; j < NK; ++j) {
      unsigned hi = tk[j] > cur ? tk[j] : cur;
      unsigned lo = tk[j] > cur ? cur : tk[j];
      tk[j] = hi;
      cur = lo;
    }
  }
#pragma unroll
  for (int r = 0; r < NK; ++r)
    idxo[(size_t)row * NK + r] = 4095 - (int)(tk[r] & 4095u);
}

// ---------- K3: P,Q = bf16((hn @ gcwb^T) * norm); async-staged weights ----------
__global__ __launch_bounds__(BDIM) void k3_pq_mfma(
    const unsigned short* __restrict__ hnb, const unsigned short* __restrict__ gcwb,
    const float* __restrict__ norm, unsigned short* __restrict__ P,
    unsigned short* __restrict__ Q) {
  __shared__ __align__(16) char abuf[2][24576];
  int t = threadIdx.x;
  int b = blockIdx.x / 98;
  int rem = blockIdx.x % 98;
  int n0 = (rem >> 1) * 64;
  int ch0 = (rem & 1) * 6;
  const unsigned short* hb = hnb + (size_t)b * NN * NC;
  int lane = t & 63, w = t >> 6;
  int l15 = lane & 15, l4 = lane >> 4;
  int n = n0 + w * 16 + l15;
  short8 bfr[6];
  {
    const short8* brow = (const short8*)(hb + (size_t)n * NC + l4 * 8);
#pragma unroll
    for (int ks = 0; ks < 6; ++ks) bfr[ks] = brow[ks * 4];
  }
  float nrm = norm[(size_t)b * NN + n];
  size_t orow = (size_t)b * NN + n;
  const char* wB = (const char*)gcwb;

  stage_tile(wB + (size_t)ch0 * 24576, abuf[0], t);
  __syncthreads();
  for (int ci = 0; ci < 6; ++ci) {
    int ch = ch0 + ci;
    int cur = ci & 1;
    if (ci < 5) stage_tile(wB + (size_t)(ch + 1) * 24576, abuf[cur ^ 1], t);
#pragma unroll
    for (int sub = 0; sub < 4; ++sub) {
      int mrow = sub * 16 + l15;
      int rbase = mrow * 384, sw = (mrow & 7) << 4;
      f32x4 acc = {0.f, 0.f, 0.f, 0.f};
#pragma unroll
      for (int ks = 0; ks < 6; ++ks) {
        short8 af = *(const short8*)&abuf[cur][rbase + ((ks * 64 + l4 * 16) ^ sw)];
        acc = __builtin_amdgcn_mfma_f32_16x16x32_bf16(af, bfr[ks], acc, 0, 0, 0);
      }
      int o = ch * 64 + sub * 16 + l4 * 4;
      f32x4 st = acc * nrm;
      unsigned short* dst = (o < NCH) ? P : Q;
      int oo = (o < NCH) ? o : o - NCH;
      uint2 u;
      u.x = (unsigned)f2bf(st[0]) | ((unsigned)f2bf(st[1]) << 16);
      u.y = (unsigned)f2bf(st[2]) | ((unsigned)f2bf(st[3]) << 16);
      *(uint2*)&dst[orow * NCH + oo] = u;
    }
    __syncthreads();
  }
}

// ---------- K4: m = bf16(gelu((P - Q + max_k Q[idx_k])*sc2+sh2)), 2 cols/lane ----------
__global__ __launch_bounds__(BDIM) void k4_gathermax(
    const unsigned short* __restrict__ P, const unsigned short* __restrict__ Q,
    const int* __restrict__ idx, const float* __restrict__ sc2,
    const float* __restrict__ sh2, unsigned short* __restrict__ mbh) {
  int t = threadIdx.x;
  int lane = t & 63, wv = t >> 6;
  int row = blockIdx.x * 4 + wv;
  int b = row / NN, n = row % NN;
  const int* ip = idx + (size_t)row * NK;
  int id[NK];
#pragma unroll
  for (int k = 0; k < NK; ++k) id[k] = ip[k];
  const unsigned short* Qb = Q + (size_t)b * NN * NCH;
  const unsigned short* Pr = P + (size_t)row * NCH;
  const unsigned short* Qr = Qb + (size_t)n * NCH;
#pragma unroll
  for (int j = 0; j < 3; ++j) {
    int o = j * 128 + lane * 2;
    float mx0 = -1e30f, mx1 = -1e30f;
#pragma unroll
    for (int k = 0; k < NK; ++k) {
      unsigned g = *(const unsigned*)&Qb[(size_t)id[k] * NCH + o];
      mx0 = fmaxf(mx0, bf2f(g & 0xffffu));
      mx1 = fmaxf(mx1, bf2f(g >> 16));
    }
    unsigned pv = *(const unsigned*)&Pr[o];
    unsigned qv = *(const unsigned*)&Qr[o];
    float2 ss = *(const float2*)&sc2[o];
    float2 hh = *(const float2*)&sh2[o];
    float e0 = bf2f(pv & 0xffffu) - bf2f(qv & 0xffffu) + mx0;
    float e1 = bf2f(pv >> 16) - bf2f(qv >> 16) + mx1;
    float y0 = e0 * ss.x + hh.x;
    float y1 = e1 * ss.y + hh.y;
    float ge0 = 0.5f * y0 * (1.f + erff(y0 * 0.70710678118654752f));
    float ge1 = 0.5f * y1 * (1.f + erff(y1 * 0.70710678118654752f));
    *(unsigned*)&mbh[(size_t)row * NCH + o] =
        (unsigned)f2bf(ge0) | ((unsigned)f2bf(ge1) << 16);
  }
}

// ---------- K5: out = BN3(m @ fc2_w^T) + x via MFMA, direct [c][n] store ----------
__global__ __launch_bounds__(BDIM) void k5_mfma(
    const unsigned short* __restrict__ mbh, const unsigned short* __restrict__ fc2b,
    const float* __restrict__ sc3, const float* __restrict__ sh3,
    const float* __restrict__ x, float* __restrict__ out) {
  __shared__ __align__(16) char abuf[2][24576];
  int t = threadIdx.x;
  int bid = blockIdx.x;
  int b = bid / 147;
  int rem = bid % 147;
  int n0 = (rem / 3) * 64;
  int oc = rem % 3;
  int lane = t & 63, w = t >> 6;
  int l15 = lane & 15, l4 = lane >> 4;
  int n = n0 + w * 16 + l15;
  short8 bfr[12];
  {
    const short8* brow = (const short8*)(mbh + (size_t)(b * NN + n) * NCH + l4 * 8);
#pragma unroll
    for (int kh = 0; kh < 2; ++kh)
#pragma unroll
      for (int ks = 0; ks < 6; ++ks) bfr[kh * 6 + ks] = brow[kh * 24 + ks * 4];
  }
  f32x4 acc[4];
#pragma unroll
  for (int sub = 0; sub < 4; ++sub) acc[sub] = {0.f, 0.f, 0.f, 0.f};

  const char* wt = (const char*)fc2b + (size_t)oc * 2 * 24576;
  stage_tile(wt, abuf[0], t);
  __syncthreads();
  for (int kh = 0; kh < 2; ++kh) {
    if (kh == 0) stage_tile(wt + 24576, abuf[1], t);
#pragma unroll
    for (int sub = 0; sub < 4; ++sub) {
      int r_ = sub * 16 + l15;
      int rbase = r_ * 384, sw = (r_ & 7) << 4;
#pragma unroll
      for (int ks = 0; ks < 6; ++ks) {
        short8 af = *(const short8*)&abuf[kh][rbase + ((ks * 64 + l4 * 16) ^ sw)];
        acc[sub] = __builtin_amdgcn_mfma_f32_16x16x32_bf16(af, bfr[kh * 6 + ks],
                                                           acc[sub], 0, 0, 0);
      }
    }
    __syncthreads();
  }
  const float* xb_ = x + (size_t)b * NC * NN;
  float* ob = out + (size_t)b * NC * NN;
#pragma unroll
  for (int sub = 0; sub < 4; ++sub) {
    int c4 = oc * 64 + sub * 16 + l4 * 4;
    float s_[4], h_[4];
    *(float4*)s_ = *(const float4*)&sc3[c4];
    *(float4*)h_ = *(const float4*)&sh3[c4];
#pragma unroll
    for (int r = 0; r < 4; ++r) {
      size_t off = (size_t)(c4 + r) * NN + n;
      ob[off] = acc[sub][r] * s_[r] + h_[r] + xb_[off];
    }
  }
}

extern "C" void kernel_launch(void* const* d_in, const int* in_sizes, int n_in,
                              void* d_out, int out_size, void* d_ws, size_t ws_size,
                              hipStream_t stream) {
  const float* x = (const float*)d_in[0];
  const float* fc1_w = (const float*)d_in[1];
  const float* fc1_b = (const float*)d_in[2];
  const float* bn1_g = (const float*)d_in[3];
  const float* bn1_b = (const float*)d_in[4];
  const float* bn1_m = (const float*)d_in[5];
  const float* bn1_v = (const float*)d_in[6];
  const float* gc_w = (const float*)d_in[7];
  const float* gc_b = (const float*)d_in[8];
  const float* bn2_g = (const float*)d_in[9];
  const float* bn2_b = (const float*)d_in[10];
  const float* bn2_m = (const float*)d_in[11];
  const float* bn2_v = (const float*)d_in[12];
  const float* fc2_w = (const float*)d_in[13];
  const float* fc2_b = (const float*)d_in[14];
  const float* bn3_g = (const float*)d_in[15];
  const float* bn3_b = (const float*)d_in[16];
  const float* bn3_m = (const float*)d_in[17];
  const float* bn3_v = (const float*)d_in[18];

  size_t nrow = (size_t)NROW;
  size_t npq = (size_t)NB * NN * NCH;
  size_t nhb = (size_t)NB * NN * NC;
  unsigned short* Pb = (unsigned short*)d_ws;
  unsigned short* Qb = Pb + npq;
  unsigned short* mbh = Qb + npq;
  float* norm = (float*)(mbh + npq);
  int* idx = (int*)(norm + nrow);
  unsigned short* hnb = (unsigned short*)(idx + nrow * NK);
  unsigned short* gcwb = hnb + nhb;
  unsigned short* fc1b = gcwb + 768 * NC;
  unsigned short* fc2b = fc1b + NC * NC;
  unsigned* candK = (unsigned*)(fc2b + NC * NCH);
  float* sc1 = (float*)(candK + 4 * NK * nrow);
  float* sh1 = sc1 + NC;
  float* sc2 = sh1 + NC;
  float* sh2 = sc2 + NCH;
  float* sc3 = sh2 + NCH;
  float* sh3 = sc3 + NC;

  k0_convw<<<252, BDIM, 0, stream>>>(gc_w, fc1_w, fc2_w, gcwb, fc1b, fc2b);
  k0b_params<<<1, 384, 0, stream>>>(fc1_b, bn1_g, bn1_b, bn1_m, bn1_v, gc_b,
                                    bn2_g, bn2_b, bn2_m, bn2_v, fc2_b, bn3_g,
                                    bn3_b, bn3_m, bn3_v, sc1, sh1, sc2, sh2,
                                    sc3, sh3);
  k1_mfma<<<NB * 49, BDIM, 0, stream>>>(x, fc1b, sc1, sh1, hnb, norm);
  k2a_topk<<<NB * 196, BDIM, 0, stream>>>(hnb, candK);
  k2b_merge<<<NROW / BDIM, BDIM, 0, stream>>>(candK, idx);
  k3_pq_mfma<<<NB * 98, BDIM, 0, stream>>>(hnb, gcwb, norm, Pb, Qb);
  k4_gathermax<<<(NB * NN) / 4, BDIM, 0, stream>>>(Pb, Qb, idx, sc2, sh2, mbh);
  k5_mfma<<<NB * 147, BDIM, 0, stream>>>(mbh, fc2b, sc3, sh3, x, (float*)d_out);
}

// Round 11
// 164.208 us; speedup vs baseline: 3.0519x; 1.0717x over previous
//
#include <hip/hip_runtime.h>

#define BDIM 256
#define NB 8
#define NC 192
#define NN 3136         // 56*56 = 49*64
#define NCH 384
#define NK 9
#define NROW (NB * NN)  // 25088

typedef __attribute__((ext_vector_type(8))) short short8;
typedef __attribute__((ext_vector_type(4))) float f32x4;

__device__ __forceinline__ unsigned short f2bf(float f) {
  union { float f; unsigned u; } x{f};
  unsigned r = x.u + 0x7fff + ((x.u >> 16) & 1);  // RNE
  return (unsigned short)(r >> 16);
}

__device__ __forceinline__ float bf2f(unsigned u16) {
  union { unsigned u; float f; } x{u16 << 16};
  return x.f;
}

// sortable-u32 transform of float bits: order-preserving for all finite values
__device__ __forceinline__ unsigned fsort(float f) {
  union { float f; unsigned u; } x{f};
  return x.u ^ ((unsigned)(((int)x.u) >> 31) | 0x80000000u);
}

// stage one 24KB [64 rows][384B] bf16 tile into LDS (async, width 16).
// LDS dest linear; global source pre-XOR-swizzled: LDS[m][kb] = G[m][kb^((m&7)<<4)].
__device__ __forceinline__ void stage_tile(const char* gbase, char* lbuf, int t) {
#pragma unroll
  for (int i = 0; i < 6; ++i) {
    int L = (i * 256 + t) * 16;
    int m = L / 384;
    int kb = L - m * 384;
    const char* g = gbase + m * 384 + (kb ^ ((m & 7) << 4));
    __builtin_amdgcn_global_load_lds(
        (const __attribute__((address_space(1))) unsigned int*)g,
        (__attribute__((address_space(3))) unsigned int*)(lbuf + L), 16, 0, 0);
  }
}

// 12KB variant: [32 rows][384B]
__device__ __forceinline__ void stage_tile32(const char* gbase, char* lbuf, int t) {
#pragma unroll
  for (int i = 0; i < 3; ++i) {
    int L = (i * 256 + t) * 16;
    int m = L / 384;
    int kb = L - m * 384;
    const char* g = gbase + m * 384 + (kb ^ ((m & 7) << 4));
    __builtin_amdgcn_global_load_lds(
        (const __attribute__((address_space(1))) unsigned int*)g,
        (__attribute__((address_space(3))) unsigned int*)(lbuf + L), 16, 0, 0);
  }
}

// ---------- K0: bf16 weight conversion ----------
__global__ __launch_bounds__(BDIM) void k0_convw(
    const float* __restrict__ gw, const float* __restrict__ f1w,
    const float* __restrict__ f2w, unsigned short* __restrict__ gcwb,
    unsigned short* __restrict__ fc1b, unsigned short* __restrict__ fc2b) {
  int i = (blockIdx.x * BDIM + threadIdx.x) * 4;
  const float* src;
  unsigned short* dst;
  if (i < 147456) {  // gc_w split
    int o = i / NC, k = i - o * NC;
    src = gw + (size_t)(o < NCH ? o : o - NCH) * (2 * NC) + (o < NCH ? 0 : NC) + k;
    dst = gcwb + i;
  } else if (i < 184320) {  // fc1
    int j = i - 147456;
    src = f1w + j;
    dst = fc1b + j;
  } else {  // fc2 retile [(oc*2+kh)][64][192]
    int j = i - 184320;
    int o = j / NCH, k = j - o * NCH;
    int oc = o >> 6, om = o & 63;
    int kh = k / 192, km = k - kh * 192;
    src = f2w + j;
    dst = fc2b + ((size_t)((oc * 2 + kh) * 64 + om)) * 192 + km;
  }
  float4 v = *(const float4*)src;
  uint2 u;
  u.x = (unsigned)f2bf(v.x) | ((unsigned)f2bf(v.y) << 16);
  u.y = (unsigned)f2bf(v.z) | ((unsigned)f2bf(v.w) << 16);
  *(uint2*)dst = u;
}

// ---------- K0b: fold BN params: val = gemm*sc + sh ----------
__global__ __launch_bounds__(384) void k0b_params(
    const float* __restrict__ f1b, const float* __restrict__ g1,
    const float* __restrict__ b1, const float* __restrict__ m1,
    const float* __restrict__ v1, const float* __restrict__ gcb,
    const float* __restrict__ g2, const float* __restrict__ b2,
    const float* __restrict__ m2, const float* __restrict__ v2,
    const float* __restrict__ f2b, const float* __restrict__ g3,
    const float* __restrict__ b3, const float* __restrict__ m3,
    const float* __restrict__ v3, float* __restrict__ sc1,
    float* __restrict__ sh1, float* __restrict__ sc2, float* __restrict__ sh2,
    float* __restrict__ sc3, float* __restrict__ sh3) {
  int c = threadIdx.x;
  if (c < NC) {
    float s1 = g1[c] * rsqrtf(v1[c] + 1e-5f);
    sc1[c] = s1;
    sh1[c] = (f1b[c] - m1[c]) * s1 + b1[c];
    float s3 = g3[c] * rsqrtf(v3[c] + 1e-5f);
    sc3[c] = s3;
    sh3[c] = (f2b[c] - m3[c]) * s3 + b3[c];
  }
  float s2 = g2[c] * rsqrtf(v2[c] + 1e-5f);
  sc2[c] = s2;
  sh2[c] = (gcb[c] - m2[c]) * s2 + b2[c];
}

// ---------- K1: h = BN1(x @ fc1_w^T) via MFMA; x read directly (fused transpose) ----------
__global__ __launch_bounds__(BDIM) void k1_mfma(
    const float* __restrict__ x, const unsigned short* __restrict__ fc1b,
    const float* __restrict__ sc1, const float* __restrict__ sh1,
    unsigned short* __restrict__ hnb, float* __restrict__ normo) {
  __shared__ __align__(16) char abuf[2][24576];
  int t = threadIdx.x;
  int b = blockIdx.x / 49, n0 = (blockIdx.x % 49) * 64;
  int lane = t & 63, w = t >> 6;
  int l15 = lane & 15, l4 = lane >> 4;
  int n = n0 + w * 16 + l15;
  short8 bfr[6];
  {
    const float* xcol = x + (size_t)b * NC * NN + n;
#pragma unroll
    for (int ks = 0; ks < 6; ++ks) {
      union { short8 s; unsigned u[4]; } pk;
#pragma unroll
      for (int j = 0; j < 4; ++j) {
        float v0 = xcol[(size_t)(ks * 32 + l4 * 8 + 2 * j) * NN];
        float v1 = xcol[(size_t)(ks * 32 + l4 * 8 + 2 * j + 1) * NN];
        pk.u[j] = (unsigned)f2bf(v0) | ((unsigned)f2bf(v1) << 16);
      }
      bfr[ks] = pk.s;
    }
  }
  f32x4 acc[3][4];
#pragma unroll
  for (int oc = 0; oc < 3; ++oc)
#pragma unroll
    for (int sub = 0; sub < 4; ++sub) acc[oc][sub] = {0.f, 0.f, 0.f, 0.f};

  const char* wB = (const char*)fc1b;
  stage_tile(wB, abuf[0], t);
  __syncthreads();
  for (int oc = 0; oc < 3; ++oc) {
    int cur = oc & 1;
    if (oc < 2) stage_tile(wB + (size_t)(oc + 1) * 24576, abuf[cur ^ 1], t);
#pragma unroll
    for (int sub = 0; sub < 4; ++sub) {
      int r_ = sub * 16 + l15;
      int rbase = r_ * 384, sw = (r_ & 7) << 4;
#pragma unroll
      for (int ks = 0; ks < 6; ++ks) {
        short8 af = *(const short8*)&abuf[cur][rbase + ((ks * 64 + l4 * 16) ^ sw)];
        acc[oc][sub] = __builtin_amdgcn_mfma_f32_16x16x32_bf16(af, bfr[ks],
                                                               acc[oc][sub], 0, 0, 0);
      }
    }
    __syncthreads();
  }
  float p = 0.f;
#pragma unroll
  for (int oc = 0; oc < 3; ++oc)
#pragma unroll
    for (int sub = 0; sub < 4; ++sub) {
      int c4 = oc * 64 + sub * 16 + l4 * 4;
      float s_[4], h_[4];
      *(float4*)s_ = *(const float4*)&sc1[c4];
      *(float4*)h_ = *(const float4*)&sh1[c4];
#pragma unroll
      for (int r = 0; r < 4; ++r) {
        float v = acc[oc][sub][r] * s_[r] + h_[r];
        acc[oc][sub][r] = v;
        p += v * v;
      }
    }
  p += __shfl_xor(p, 16);
  p += __shfl_xor(p, 32);
  float nr = fmaxf(sqrtf(p), 1e-12f);
  float iv = 1.f / nr;
  if (l4 == 0) normo[(size_t)b * NN + n] = nr;
#pragma unroll
  for (int oc = 0; oc < 3; ++oc)
#pragma unroll
    for (int sub = 0; sub < 4; ++sub) {
      uint2 u;
      u.x = (unsigned)f2bf(acc[oc][sub][0] * iv) |
            ((unsigned)f2bf(acc[oc][sub][1] * iv) << 16);
      u.y = (unsigned)f2bf(acc[oc][sub][2] * iv) |
            ((unsigned)f2bf(acc[oc][sub][3] * iv) << 16);
      *(uint2*)&hnb[(size_t)(b * NN + n) * NC + oc * 64 + sub * 16 + l4 * 4] = u;
    }
}

// ---------- K23: fused dispatch — k2a (topk) blocks + k3 (P,Q) blocks ----------
// Per XCD x (= bid&7): j-stream interleaves 2 k2a : 1 k3. Both roles read hnb
// batch x (L2-pinned), both use 2x12KB LDS double-buffer.
__global__ __launch_bounds__(BDIM) void k23_fused(
    const unsigned short* __restrict__ hnb, const float* __restrict__ norm,
    const unsigned short* __restrict__ gcwb, unsigned* __restrict__ candK,
    unsigned short* __restrict__ P, unsigned short* __restrict__ Q) {
  __shared__ __align__(16) char abuf[2][12288];
  int t = threadIdx.x;
  int bid = blockIdx.x;
  int b = bid & 7;          // batch == XCD (dispatch round-robins over 8 XCDs)
  int j = bid >> 3;         // 0..293 per XCD
  int role3 = j % 3;
  int lane = t & 63, w = t >> 6;
  int l15 = lane & 15, l4 = lane >> 4;
  const unsigned short* hb = hnb + (size_t)b * NN * NC;

  if (role3 != 2) {
    // ---- k2a role: 196 blocks/XCD; n0 x m-segment topk candidates ----
    int idx2a = (j / 3) * 2 + role3;  // 0..195
    int n0 = (idx2a >> 2) * 64;
    int seg = idx2a & 3;
    int mt0 = (98 * seg) / 4, mt1 = (98 * (seg + 1)) / 4;
    const char* hbB = (const char*)hb;

    short8 bfr[6];
    {
      const short8* brow =
          (const short8*)(hb + (size_t)(n0 + w * 16 + l15) * NC + l4 * 8);
#pragma unroll
      for (int ks = 0; ks < 6; ++ks) bfr[ks] = brow[ks * 4];
    }
    unsigned tk[NK];
#pragma unroll
    for (int r = 0; r < NK; ++r) tk[r] = 0u;

    stage_tile32(hbB + (size_t)mt0 * 12288, abuf[0], t);
    __syncthreads();
    int nt = mt1 - mt0;
    for (int ti = 0; ti < nt; ++ti) {
      int cur = ti & 1;
      if (ti + 1 < nt)
        stage_tile32(hbB + (size_t)(mt0 + ti + 1) * 12288, abuf[cur ^ 1], t);
      int mglob = (mt0 + ti) * 32;
#pragma unroll
      for (int sub = 0; sub < 2; ++sub) {
        int r_ = sub * 16 + l15;
        int rbase = r_ * 384, sw = (r_ & 7) << 4;
        short8 af[6];
#pragma unroll
        for (int ks = 0; ks < 6; ++ks)
          af[ks] = *(const short8*)&abuf[cur][rbase + ((ks * 64 + l4 * 16) ^ sw)];
        f32x4 acc = {0.f, 0.f, 0.f, 0.f};
#pragma unroll
        for (int ks = 0; ks < 6; ++ks)
          acc = __builtin_amdgcn_mfma_f32_16x16x32_bf16(af[ks], bfr[ks], acc, 0, 0, 0);
        int mknd = 4095 - (mglob + sub * 16 + l4 * 4);
#pragma unroll
        for (int r = 0; r < 4; ++r) {
          unsigned cur_k = (fsort(acc[r]) & 0xFFFFF000u) | (unsigned)(mknd - r);
#pragma unroll
          for (int q = 0; q < NK; ++q) {
            unsigned hi = tk[q] > cur_k ? tk[q] : cur_k;
            unsigned lo = tk[q] > cur_k ? cur_k : tk[q];
            tk[q] = hi;
            cur_k = lo;
          }
        }
      }
      __syncthreads();
    }
    unsigned* mkeys = (unsigned*)&abuf[0][0];  // 64 rows x 4 lists x 9 = 9216B
    int nl = w * 16 + l15;
#pragma unroll
    for (int r = 0; r < NK; ++r) mkeys[(nl * 4 + l4) * NK + r] = tk[r];
    __syncthreads();
    if (t < 64) {
      const unsigned* src = &mkeys[t * 4 * NK];
      unsigned best[NK];
#pragma unroll
      for (int r = 0; r < NK; ++r) best[r] = 0u;
      for (int s = 0; s < 36; ++s) {
        unsigned cur_k = src[s];
#pragma unroll
        for (int q = 0; q < NK; ++q) {
          unsigned hi = best[q] > cur_k ? best[q] : cur_k;
          unsigned lo = best[q] > cur_k ? cur_k : best[q];
          best[q] = hi;
          cur_k = lo;
        }
      }
      size_t row = (size_t)b * NN + n0 + t;
#pragma unroll
      for (int r = 0; r < NK; ++r)
        candK[(size_t)(seg * NK + r) * NROW + row] = best[r];
    }
  } else {
    // ---- k3 role: 98 blocks/XCD; P,Q = bf16((hn @ gcwb^T) * norm) ----
    int jj = j / 3;           // 0..97
    int n0 = (jj >> 1) * 64;
    int half = jj & 1;        // o-chunks [half*12, half*12+12), 32 rows each
    int n = n0 + w * 16 + l15;
    short8 bfr[6];
    {
      const short8* brow = (const short8*)(hb + (size_t)n * NC + l4 * 8);
#pragma unroll
      for (int ks = 0; ks < 6; ++ks) bfr[ks] = brow[ks * 4];
    }
    float nrm = norm[(size_t)b * NN + n];
    size_t orow = (size_t)b * NN + n;
    const char* wB = (const char*)gcwb;

    int ch0 = half * 12;
    stage_tile32(wB + (size_t)ch0 * 12288, abuf[0], t);
    __syncthreads();
    for (int ci = 0; ci < 12; ++ci) {
      int ch = ch0 + ci;
      int cur = ci & 1;
      if (ci < 11) stage_tile32(wB + (size_t)(ch + 1) * 12288, abuf[cur ^ 1], t);
#pragma unroll
      for (int sub = 0; sub < 2; ++sub) {
        int mrow = sub * 16 + l15;
        int rbase = mrow * 384, sw = (mrow & 7) << 4;
        f32x4 acc = {0.f, 0.f, 0.f, 0.f};
#pragma unroll
        for (int ks = 0; ks < 6; ++ks) {
          short8 af = *(const short8*)&abuf[cur][rbase + ((ks * 64 + l4 * 16) ^ sw)];
          acc = __builtin_amdgcn_mfma_f32_16x16x32_bf16(af, bfr[ks], acc, 0, 0, 0);
        }
        int o = ch * 32 + sub * 16 + l4 * 4;
        f32x4 st = acc * nrm;
        unsigned short* dst = (o < NCH) ? P : Q;
        int oo = (o < NCH) ? o : o - NCH;
        uint2 u;
        u.x = (unsigned)f2bf(st[0]) | ((unsigned)f2bf(st[1]) << 16);
        u.y = (unsigned)f2bf(st[2]) | ((unsigned)f2bf(st[3]) << 16);
        *(uint2*)&dst[orow * NCH + oo] = u;
      }
      __syncthreads();
    }
  }
}

// ---------- K2b: merge 4x9 keys/row -> final top-9 indices ----------
__global__ __launch_bounds__(BDIM) void k2b_merge(const unsigned* __restrict__ candK,
                                                  int* __restrict__ idxo) {
  int row = blockIdx.x * BDIM + threadIdx.x;
  unsigned tk[NK];
#pragma unroll
  for (int r = 0; r < NK; ++r) tk[r] = 0u;
  for (int s = 0; s < 4 * NK; ++s) {
    unsigned cur = candK[(size_t)s * NROW + row];
#pragma unroll
    for (int j = 0; j < NK; ++j) {
      unsigned hi = tk[j] > cur ? tk[j] : cur;
      unsigned lo = tk[j] > cur ? cur : tk[j];
      tk[j] = hi;
      cur = lo;
    }
  }
#pragma unroll
  for (int r = 0; r < NK; ++r)
    idxo[(size_t)row * NK + r] = 4095 - (int)(tk[r] & 4095u);
}

// ---------- K4: m = bf16(gelu((P - Q + max_k Q[idx_k])*sc2+sh2)), 2 cols/lane ----------
__global__ __launch_bounds__(BDIM) void k4_gathermax(
    const unsigned short* __restrict__ P, const unsigned short* __restrict__ Q,
    const int* __restrict__ idx, const float* __restrict__ sc2,
    const float* __restrict__ sh2, unsigned short* __restrict__ mbh) {
  int t = threadIdx.x;
  int lane = t & 63, wv = t >> 6;
  int row = blockIdx.x * 4 + wv;
  int b = row / NN, n = row % NN;
  const int* ip = idx + (size_t)row * NK;
  int id[NK];
#pragma unroll
  for (int k = 0; k < NK; ++k) id[k] = ip[k];
  const unsigned short* Qb = Q + (size_t)b * NN * NCH;
  const unsigned short* Pr = P + (size_t)row * NCH;
  const unsigned short* Qr = Qb + (size_t)n * NCH;
#pragma unroll
  for (int j = 0; j < 3; ++j) {
    int o = j * 128 + lane * 2;
    float mx0 = -1e30f, mx1 = -1e30f;
#pragma unroll
    for (int k = 0; k < NK; ++k) {
      unsigned g = *(const unsigned*)&Qb[(size_t)id[k] * NCH + o];
      mx0 = fmaxf(mx0, bf2f(g & 0xffffu));
      mx1 = fmaxf(mx1, bf2f(g >> 16));
    }
    unsigned pv = *(const unsigned*)&Pr[o];
    unsigned qv = *(const unsigned*)&Qr[o];
    float2 ss = *(const float2*)&sc2[o];
    float2 hh = *(const float2*)&sh2[o];
    float e0 = bf2f(pv & 0xffffu) - bf2f(qv & 0xffffu) + mx0;
    float e1 = bf2f(pv >> 16) - bf2f(qv >> 16) + mx1;
    float y0 = e0 * ss.x + hh.x;
    float y1 = e1 * ss.y + hh.y;
    float ge0 = 0.5f * y0 * (1.f + erff(y0 * 0.70710678118654752f));
    float ge1 = 0.5f * y1 * (1.f + erff(y1 * 0.70710678118654752f));
    *(unsigned*)&mbh[(size_t)row * NCH + o] =
        (unsigned)f2bf(ge0) | ((unsigned)f2bf(ge1) << 16);
  }
}

// ---------- K5: out = BN3(m @ fc2_w^T) + x via MFMA, direct [c][n] store ----------
__global__ __launch_bounds__(BDIM) void k5_mfma(
    const unsigned short* __restrict__ mbh, const unsigned short* __restrict__ fc2b,
    const float* __restrict__ sc3, const float* __restrict__ sh3,
    const float* __restrict__ x, float* __restrict__ out) {
  __shared__ __align__(16) char abuf[2][24576];
  int t = threadIdx.x;
  int bid = blockIdx.x;
  int b = bid / 147;
  int rem = bid % 147;
  int n0 = (rem / 3) * 64;
  int oc = rem % 3;
  int lane = t & 63, w = t >> 6;
  int l15 = lane & 15, l4 = lane >> 4;
  int n = n0 + w * 16 + l15;
  short8 bfr[12];
  {
    const short8* brow = (const short8*)(mbh + (size_t)(b * NN + n) * NCH + l4 * 8);
#pragma unroll
    for (int kh = 0; kh < 2; ++kh)
#pragma unroll
      for (int ks = 0; ks < 6; ++ks) bfr[kh * 6 + ks] = brow[kh * 24 + ks * 4];
  }
  f32x4 acc[4];
#pragma unroll
  for (int sub = 0; sub < 4; ++sub) acc[sub] = {0.f, 0.f, 0.f, 0.f};

  const char* wt = (const char*)fc2b + (size_t)oc * 2 * 24576;
  stage_tile(wt, abuf[0], t);
  __syncthreads();
  for (int kh = 0; kh < 2; ++kh) {
    if (kh == 0) stage_tile(wt + 24576, abuf[1], t);
#pragma unroll
    for (int sub = 0; sub < 4; ++sub) {
      int r_ = sub * 16 + l15;
      int rbase = r_ * 384, sw = (r_ & 7) << 4;
#pragma unroll
      for (int ks = 0; ks < 6; ++ks) {
        short8 af = *(const short8*)&abuf[kh][rbase + ((ks * 64 + l4 * 16) ^ sw)];
        acc[sub] = __builtin_amdgcn_mfma_f32_16x16x32_bf16(af, bfr[kh * 6 + ks],
                                                           acc[sub], 0, 0, 0);
      }
    }
    __syncthreads();
  }
  const float* xb_ = x + (size_t)b * NC * NN;
  float* ob = out + (size_t)b * NC * NN;
#pragma unroll
  for (int sub = 0; sub < 4; ++sub) {
    int c4 = oc * 64 + sub * 16 + l4 * 4;
    float s_[4], h_[4];
    *(float4*)s_ = *(const float4*)&sc3[c4];
    *(float4*)h_ = *(const float4*)&sh3[c4];
#pragma unroll
    for (int r = 0; r < 4; ++r) {
      size_t off = (size_t)(c4 + r) * NN + n;
      ob[off] = acc[sub][r] * s_[r] + h_[r] + xb_[off];
    }
  }
}

extern "C" void kernel_launch(void* const* d_in, const int* in_sizes, int n_in,
                              void* d_out, int out_size, void* d_ws, size_t ws_size,
                              hipStream_t stream) {
  const float* x = (const float*)d_in[0];
  const float* fc1_w = (const float*)d_in[1];
  const float* fc1_b = (const float*)d_in[2];
  const float* bn1_g = (const float*)d_in[3];
  const float* bn1_b = (const float*)d_in[4];
  const float* bn1_m = (const float*)d_in[5];
  const float* bn1_v = (const float*)d_in[6];
  const float* gc_w = (const float*)d_in[7];
  const float* gc_b = (const float*)d_in[8];
  const float* bn2_g = (const float*)d_in[9];
  const float* bn2_b = (const float*)d_in[10];
  const float* bn2_m = (const float*)d_in[11];
  const float* bn2_v = (const float*)d_in[12];
  const float* fc2_w = (const float*)d_in[13];
  const float* fc2_b = (const float*)d_in[14];
  const float* bn3_g = (const float*)d_in[15];
  const float* bn3_b = (const float*)d_in[16];
  const float* bn3_m = (const float*)d_in[17];
  const float* bn3_v = (const float*)d_in[18];

  size_t nrow = (size_t)NROW;
  size_t npq = (size_t)NB * NN * NCH;
  size_t nhb = (size_t)NB * NN * NC;
  unsigned short* Pb = (unsigned short*)d_ws;
  unsigned short* Qb = Pb + npq;
  unsigned short* mbh = Qb + npq;
  float* norm = (float*)(mbh + npq);
  int* idx = (int*)(norm + nrow);
  unsigned short* hnb = (unsigned short*)(idx + nrow * NK);
  unsigned short* gcwb = hnb + nhb;
  unsigned short* fc1b = gcwb + 768 * NC;
  unsigned short* fc2b = fc1b + NC * NC;
  unsigned* candK = (unsigned*)(fc2b + NC * NCH);
  float* sc1 = (float*)(candK + 4 * NK * nrow);
  float* sh1 = sc1 + NC;
  float* sc2 = sh1 + NC;
  float* sh2 = sc2 + NCH;
  float* sc3 = sh2 + NCH;
  float* sh3 = sc3 + NC;

  k0_convw<<<252, BDIM, 0, stream>>>(gc_w, fc1_w, fc2_w, gcwb, fc1b, fc2b);
  k0b_params<<<1, 384, 0, stream>>>(fc1_b, bn1_g, bn1_b, bn1_m, bn1_v, gc_b,
                                    bn2_g, bn2_b, bn2_m, bn2_v, fc2_b, bn3_g,
                                    bn3_b, bn3_m, bn3_v, sc1, sh1, sc2, sh2,
                                    sc3, sh3);
  k1_mfma<<<NB * 49, BDIM, 0, stream>>>(x, fc1b, sc1, sh1, hnb, norm);
  k23_fused<<<NB * 294, BDIM, 0, stream>>>(hnb, norm, gcwb, candK, Pb, Qb);
  k2b_merge<<<NROW / BDIM, BDIM, 0, stream>>>(candK, idx);
  k4_gathermax<<<(NB * NN) / 4, BDIM, 0, stream>>>(Pb, Qb, idx, sc2, sh2, mbh);
  k5_mfma<<<NB * 147, BDIM, 0, stream>>>(mbh, fc2b, sc3, sh3, x, (float*)d_out);
}

// Round 12
// 158.295 us; speedup vs baseline: 3.1659x; 1.0374x over previous
//
#include <hip/hip_runtime.h>

#define BDIM 256
#define NB 8
#define NC 192
#define NN 3136         // 56*56 = 49*64
#define NCH 384
#define NK 9
#define NROW (NB * NN)  // 25088

typedef __attribute__((ext_vector_type(8))) short short8;
typedef __attribute__((ext_vector_type(4))) float f32x4;

__device__ __forceinline__ unsigned short f2bf(float f) {
  union { float f; unsigned u; } x{f};
  unsigned r = x.u + 0x7fff + ((x.u >> 16) & 1);  // RNE
  return (unsigned short)(r >> 16);
}

__device__ __forceinline__ float bf2f(unsigned u16) {
  union { unsigned u; float f; } x{u16 << 16};
  return x.f;
}

// sortable-u32 transform of float bits: order-preserving for all finite values
__device__ __forceinline__ unsigned fsort(float f) {
  union { float f; unsigned u; } x{f};
  return x.u ^ ((unsigned)(((int)x.u) >> 31) | 0x80000000u);
}

// stage one 24KB [64 rows][384B] bf16 tile into LDS (async, width 16), 256 thr.
// LDS dest linear; global source pre-XOR-swizzled: LDS[m][kb] = G[m][kb^((m&7)<<4)].
__device__ __forceinline__ void stage_tile(const char* gbase, char* lbuf, int t) {
#pragma unroll
  for (int i = 0; i < 6; ++i) {
    int L = (i * 256 + t) * 16;
    int m = L / 384;
    int kb = L - m * 384;
    const char* g = gbase + m * 384 + (kb ^ ((m & 7) << 4));
    __builtin_amdgcn_global_load_lds(
        (const __attribute__((address_space(1))) unsigned int*)g,
        (__attribute__((address_space(3))) unsigned int*)(lbuf + L), 16, 0, 0);
  }
}

// 12KB [32 rows][384B] tile staged by 512 threads (768 lines: 1 line each +
// second line for t<256).
__device__ __forceinline__ void stage32_512(const char* gbase, char* lbuf, int t) {
  {
    int L = t * 16;
    int m = L / 384;
    int kb = L - m * 384;
    const char* g = gbase + m * 384 + (kb ^ ((m & 7) << 4));
    __builtin_amdgcn_global_load_lds(
        (const __attribute__((address_space(1))) unsigned int*)g,
        (__attribute__((address_space(3))) unsigned int*)(lbuf + L), 16, 0, 0);
  }
  if (t < 256) {
    int L = (512 + t) * 16;
    int m = L / 384;
    int kb = L - m * 384;
    const char* g = gbase + m * 384 + (kb ^ ((m & 7) << 4));
    __builtin_amdgcn_global_load_lds(
        (const __attribute__((address_space(1))) unsigned int*)g,
        (__attribute__((address_space(3))) unsigned int*)(lbuf + L), 16, 0, 0);
  }
}

// ---------- K0: bf16 weight conversion ----------
__global__ __launch_bounds__(BDIM) void k0_convw(
    const float* __restrict__ gw, const float* __restrict__ f1w,
    const float* __restrict__ f2w, unsigned short* __restrict__ gcwb,
    unsigned short* __restrict__ fc1b, unsigned short* __restrict__ fc2b) {
  int i = (blockIdx.x * BDIM + threadIdx.x) * 4;
  const float* src;
  unsigned short* dst;
  if (i < 147456) {  // gc_w split
    int o = i / NC, k = i - o * NC;
    src = gw + (size_t)(o < NCH ? o : o - NCH) * (2 * NC) + (o < NCH ? 0 : NC) + k;
    dst = gcwb + i;
  } else if (i < 184320) {  // fc1
    int j = i - 147456;
    src = f1w + j;
    dst = fc1b + j;
  } else {  // fc2 retile [(oc*2+kh)][64][192]
    int j = i - 184320;
    int o = j / NCH, k = j - o * NCH;
    int oc = o >> 6, om = o & 63;
    int kh = k / 192, km = k - kh * 192;
    src = f2w + j;
    dst = fc2b + ((size_t)((oc * 2 + kh) * 64 + om)) * 192 + km;
  }
  float4 v = *(const float4*)src;
  uint2 u;
  u.x = (unsigned)f2bf(v.x) | ((unsigned)f2bf(v.y) << 16);
  u.y = (unsigned)f2bf(v.z) | ((unsigned)f2bf(v.w) << 16);
  *(uint2*)dst = u;
}

// ---------- K0b: fold BN params: val = gemm*sc + sh ----------
__global__ __launch_bounds__(384) void k0b_params(
    const float* __restrict__ f1b, const float* __restrict__ g1,
    const float* __restrict__ b1, const float* __restrict__ m1,
    const float* __restrict__ v1, const float* __restrict__ gcb,
    const float* __restrict__ g2, const float* __restrict__ b2,
    const float* __restrict__ m2, const float* __restrict__ v2,
    const float* __restrict__ f2b, const float* __restrict__ g3,
    const float* __restrict__ b3, const float* __restrict__ m3,
    const float* __restrict__ v3, float* __restrict__ sc1,
    float* __restrict__ sh1, float* __restrict__ sc2, float* __restrict__ sh2,
    float* __restrict__ sc3, float* __restrict__ sh3) {
  int c = threadIdx.x;
  if (c < NC) {
    float s1 = g1[c] * rsqrtf(v1[c] + 1e-5f);
    sc1[c] = s1;
    sh1[c] = (f1b[c] - m1[c]) * s1 + b1[c];
    float s3 = g3[c] * rsqrtf(v3[c] + 1e-5f);
    sc3[c] = s3;
    sh3[c] = (f2b[c] - m3[c]) * s3 + b3[c];
  }
  float s2 = g2[c] * rsqrtf(v2[c] + 1e-5f);
  sc2[c] = s2;
  sh2[c] = (gcb[c] - m2[c]) * s2 + b2[c];
}

// ---------- K1: h = BN1(x @ fc1_w^T) via MFMA; x read directly (fused transpose) ----------
__global__ __launch_bounds__(BDIM) void k1_mfma(
    const float* __restrict__ x, const unsigned short* __restrict__ fc1b,
    const float* __restrict__ sc1, const float* __restrict__ sh1,
    unsigned short* __restrict__ hnb, float* __restrict__ normo) {
  __shared__ __align__(16) char abuf[2][24576];
  int t = threadIdx.x;
  int b = blockIdx.x / 49, n0 = (blockIdx.x % 49) * 64;
  int lane = t & 63, w = t >> 6;
  int l15 = lane & 15, l4 = lane >> 4;
  int n = n0 + w * 16 + l15;
  short8 bfr[6];
  {
    const float* xcol = x + (size_t)b * NC * NN + n;
#pragma unroll
    for (int ks = 0; ks < 6; ++ks) {
      union { short8 s; unsigned u[4]; } pk;
#pragma unroll
      for (int j = 0; j < 4; ++j) {
        float v0 = xcol[(size_t)(ks * 32 + l4 * 8 + 2 * j) * NN];
        float v1 = xcol[(size_t)(ks * 32 + l4 * 8 + 2 * j + 1) * NN];
        pk.u[j] = (unsigned)f2bf(v0) | ((unsigned)f2bf(v1) << 16);
      }
      bfr[ks] = pk.s;
    }
  }
  f32x4 acc[3][4];
#pragma unroll
  for (int oc = 0; oc < 3; ++oc)
#pragma unroll
    for (int sub = 0; sub < 4; ++sub) acc[oc][sub] = {0.f, 0.f, 0.f, 0.f};

  const char* wB = (const char*)fc1b;
  stage_tile(wB, abuf[0], t);
  __syncthreads();
  for (int oc = 0; oc < 3; ++oc) {
    int cur = oc & 1;
    if (oc < 2) stage_tile(wB + (size_t)(oc + 1) * 24576, abuf[cur ^ 1], t);
#pragma unroll
    for (int sub = 0; sub < 4; ++sub) {
      int r_ = sub * 16 + l15;
      int rbase = r_ * 384, sw = (r_ & 7) << 4;
#pragma unroll
      for (int ks = 0; ks < 6; ++ks) {
        short8 af = *(const short8*)&abuf[cur][rbase + ((ks * 64 + l4 * 16) ^ sw)];
        acc[oc][sub] = __builtin_amdgcn_mfma_f32_16x16x32_bf16(af, bfr[ks],
                                                               acc[oc][sub], 0, 0, 0);
      }
    }
    __syncthreads();
  }
  float p = 0.f;
#pragma unroll
  for (int oc = 0; oc < 3; ++oc)
#pragma unroll
    for (int sub = 0; sub < 4; ++sub) {
      int c4 = oc * 64 + sub * 16 + l4 * 4;
      float s_[4], h_[4];
      *(float4*)s_ = *(const float4*)&sc1[c4];
      *(float4*)h_ = *(const float4*)&sh1[c4];
#pragma unroll
      for (int r = 0; r < 4; ++r) {
        float v = acc[oc][sub][r] * s_[r] + h_[r];
        acc[oc][sub][r] = v;
        p += v * v;
      }
    }
  p += __shfl_xor(p, 16);
  p += __shfl_xor(p, 32);
  float nr = fmaxf(sqrtf(p), 1e-12f);
  float iv = 1.f / nr;
  if (l4 == 0) normo[(size_t)b * NN + n] = nr;
#pragma unroll
  for (int oc = 0; oc < 3; ++oc)
#pragma unroll
    for (int sub = 0; sub < 4; ++sub) {
      uint2 u;
      u.x = (unsigned)f2bf(acc[oc][sub][0] * iv) |
            ((unsigned)f2bf(acc[oc][sub][1] * iv) << 16);
      u.y = (unsigned)f2bf(acc[oc][sub][2] * iv) |
            ((unsigned)f2bf(acc[oc][sub][3] * iv) << 16);
      *(uint2*)&hnb[(size_t)(b * NN + n) * NC + oc * 64 + sub * 16 + l4 * 4] = u;
    }
}

// ---------- K23: fused 512-thread dispatch — k2a (topk) + k3 (P,Q) roles ----------
// 8 waves share one 2x12KB double-buffer (3KB LDS/wave). Wave w: n-group w&3,
// sub w>>2. Per XCD (= bid&7): 4 k2a : 1 k3 interleave; both read batch-pinned hnb.
__global__ __launch_bounds__(512) void k23_fused(
    const unsigned short* __restrict__ hnb, const float* __restrict__ norm,
    const unsigned short* __restrict__ gcwb, unsigned* __restrict__ candK,
    unsigned short* __restrict__ P, unsigned short* __restrict__ Q) {
  __shared__ __align__(16) char abuf[2][12288];
  int t = threadIdx.x;
  int bid = blockIdx.x;
  int b = bid & 7;          // batch == XCD
  int j = bid >> 3;         // 0..244 per XCD
  int lane = t & 63, w = t >> 6;
  int l15 = lane & 15, l4 = lane >> 4;
  int wg = w & 3, sub = w >> 2;
  const unsigned short* hb = hnb + (size_t)b * NN * NC;

  if (j % 5 != 4) {
    // ---- k2a role: 196 blocks/XCD; 64 n x quarter-m top-9 candidates ----
    int idx2a = (j / 5) * 4 + (j % 5);  // 0..195
    int n0 = (idx2a >> 2) * 64;
    int seg = idx2a & 3;
    int mt0 = (98 * seg) / 4, mt1 = (98 * (seg + 1)) / 4;  // 32-row tiles
    const char* hbB = (const char*)hb;

    short8 bfr[6];
    {
      const short8* brow =
          (const short8*)(hb + (size_t)(n0 + wg * 16 + l15) * NC + l4 * 8);
#pragma unroll
      for (int ks = 0; ks < 6; ++ks) bfr[ks] = brow[ks * 4];
    }
    unsigned tk[NK];
#pragma unroll
    for (int r = 0; r < NK; ++r) tk[r] = 0u;

    int r_ = sub * 16 + l15;
    int rbase = r_ * 384, sw = (r_ & 7) << 4;
    stage32_512(hbB + (size_t)mt0 * 12288, abuf[0], t);
    __syncthreads();
    int nt = mt1 - mt0;
    for (int ti = 0; ti < nt; ++ti) {
      int cur = ti & 1;
      if (ti + 1 < nt)
        stage32_512(hbB + (size_t)(mt0 + ti + 1) * 12288, abuf[cur ^ 1], t);
      short8 af[6];
#pragma unroll
      for (int ks = 0; ks < 6; ++ks)
        af[ks] = *(const short8*)&abuf[cur][rbase + ((ks * 64 + l4 * 16) ^ sw)];
      f32x4 acc = {0.f, 0.f, 0.f, 0.f};
#pragma unroll
      for (int ks = 0; ks < 6; ++ks)
        acc = __builtin_amdgcn_mfma_f32_16x16x32_bf16(af[ks], bfr[ks], acc, 0, 0, 0);
      int mknd = 4095 - ((mt0 + ti) * 32 + sub * 16 + l4 * 4);
#pragma unroll
      for (int r = 0; r < 4; ++r) {
        unsigned cur_k = (fsort(acc[r]) & 0xFFFFF000u) | (unsigned)(mknd - r);
#pragma unroll
        for (int q = 0; q < NK; ++q) {
          unsigned hi = tk[q] > cur_k ? tk[q] : cur_k;
          unsigned lo = tk[q] > cur_k ? cur_k : tk[q];
          tk[q] = hi;
          cur_k = lo;
        }
      }
      __syncthreads();
    }
    // merge 8 lists per n-row: [64 rows][8 lists][9] = 18KB (aliases abuf)
    unsigned* mkeys = (unsigned*)&abuf[0][0];
    int rw = wg * 16 + l15;
#pragma unroll
    for (int r = 0; r < NK; ++r) mkeys[(rw * 8 + sub * 4 + l4) * NK + r] = tk[r];
    __syncthreads();
    if (t < 256) {  // stage 2: merge list pairs {g, g+4} -> list g
      int row = t >> 2, g = t & 3;
      unsigned* a = &mkeys[(row * 8 + g) * NK];
      const unsigned* c = &mkeys[(row * 8 + g + 4) * NK];
      unsigned best[NK];
#pragma unroll
      for (int r = 0; r < NK; ++r) best[r] = 0u;
#pragma unroll
      for (int s = 0; s < 2 * NK; ++s) {
        unsigned cur_k = s < NK ? a[s] : c[s - NK];
#pragma unroll
        for (int q = 0; q < NK; ++q) {
          unsigned hi = best[q] > cur_k ? best[q] : cur_k;
          unsigned lo = best[q] > cur_k ? cur_k : best[q];
          best[q] = hi;
          cur_k = lo;
        }
      }
#pragma unroll
      for (int r = 0; r < NK; ++r) a[r] = best[r];
    }
    __syncthreads();
    if (t < 64) {  // stage 3: merge lists 0..3 (36 keys)
      const unsigned* src = &mkeys[(t * 8) * NK];
      unsigned best[NK];
#pragma unroll
      for (int r = 0; r < NK; ++r) best[r] = 0u;
      for (int s = 0; s < 36; ++s) {
        unsigned cur_k = src[s];
#pragma unroll
        for (int q = 0; q < NK; ++q) {
          unsigned hi = best[q] > cur_k ? best[q] : cur_k;
          unsigned lo = best[q] > cur_k ? cur_k : best[q];
          best[q] = hi;
          cur_k = lo;
        }
      }
      size_t row = (size_t)b * NN + n0 + t;
#pragma unroll
      for (int r = 0; r < NK; ++r)
        candK[(size_t)(seg * NK + r) * NROW + row] = best[r];
    }
  } else {
    // ---- k3 role: 49 blocks/XCD; P,Q = bf16((hn @ gcwb^T) * norm), 24 chunks ----
    int jj = j / 5;  // 0..48
    int n0 = jj * 64;
    int n = n0 + wg * 16 + l15;
    short8 bfr[6];
    {
      const short8* brow = (const short8*)(hb + (size_t)n * NC + l4 * 8);
#pragma unroll
      for (int ks = 0; ks < 6; ++ks) bfr[ks] = brow[ks * 4];
    }
    float nrm = norm[(size_t)b * NN + n];
    size_t orow = (size_t)b * NN + n;
    const char* wB = (const char*)gcwb;
    int mrow = sub * 16 + l15;
    int rbase = mrow * 384, sw = (mrow & 7) << 4;

    stage32_512(wB, abuf[0], t);
    __syncthreads();
    for (int ch = 0; ch < 24; ++ch) {
      int cur = ch & 1;
      if (ch < 23) stage32_512(wB + (size_t)(ch + 1) * 12288, abuf[cur ^ 1], t);
      f32x4 acc = {0.f, 0.f, 0.f, 0.f};
#pragma unroll
      for (int ks = 0; ks < 6; ++ks) {
        short8 af = *(const short8*)&abuf[cur][rbase + ((ks * 64 + l4 * 16) ^ sw)];
        acc = __builtin_amdgcn_mfma_f32_16x16x32_bf16(af, bfr[ks], acc, 0, 0, 0);
      }
      int o = ch * 32 + sub * 16 + l4 * 4;
      f32x4 st = acc * nrm;
      unsigned short* dst = (o < NCH) ? P : Q;
      int oo = (o < NCH) ? o : o - NCH;
      uint2 u;
      u.x = (unsigned)f2bf(st[0]) | ((unsigned)f2bf(st[1]) << 16);
      u.y = (unsigned)f2bf(st[2]) | ((unsigned)f2bf(st[3]) << 16);
      *(uint2*)&dst[orow * NCH + oo] = u;
      __syncthreads();
    }
  }
}

// ---------- K2b: merge 4x9 keys/row -> final top-9 indices ----------
__global__ __launch_bounds__(BDIM) void k2b_merge(const unsigned* __restrict__ candK,
                                                  int* __restrict__ idxo) {
  int row = blockIdx.x * BDIM + threadIdx.x;
  unsigned tk[NK];
#pragma unroll
  for (int r = 0; r < NK; ++r) tk[r] = 0u;
  for (int s = 0; s < 4 * NK; ++s) {
    unsigned cur = candK[(size_t)s * NROW + row];
#pragma unroll
    for (int j = 0; j < NK; ++j) {
      unsigned hi = tk[j] > cur ? tk[j] : cur;
      unsigned lo = tk[j] > cur ? cur : tk[j];
      tk[j] = hi;
      cur = lo;
    }
  }
#pragma unroll
  for (int r = 0; r < NK; ++r)
    idxo[(size_t)row * NK + r] = 4095 - (int)(tk[r] & 4095u);
}

// ---------- K4: batch->XCD-pinned gather-max + BN2 + gelu, bf16 out ----------
__global__ __launch_bounds__(BDIM) void k4_gathermax(
    const unsigned short* __restrict__ P, const unsigned short* __restrict__ Q,
    const int* __restrict__ idx, const float* __restrict__ sc2,
    const float* __restrict__ sh2, unsigned short* __restrict__ mbh) {
  int t = threadIdx.x;
  int lane = t & 63, wv = t >> 6;
  int b = blockIdx.x & 7;                      // batch == XCD (L2 pin for Q slab)
  int n = (int)(blockIdx.x >> 3) * 4 + wv;     // 0..3135
  size_t row = (size_t)b * NN + n;
  const int* ip = idx + row * NK;
  int id[NK];
#pragma unroll
  for (int k = 0; k < NK; ++k) id[k] = ip[k];
  const unsigned short* Qb = Q + (size_t)b * NN * NCH;
  const unsigned short* Pr = P + row * NCH;
  const unsigned short* Qr = Qb + (size_t)n * NCH;
#pragma unroll
  for (int j = 0; j < 3; ++j) {
    int o = j * 128 + lane * 2;
    float mx0 = -1e30f, mx1 = -1e30f;
#pragma unroll
    for (int k = 0; k < NK; ++k) {
      unsigned g = *(const unsigned*)&Qb[(size_t)id[k] * NCH + o];
      mx0 = fmaxf(mx0, bf2f(g & 0xffffu));
      mx1 = fmaxf(mx1, bf2f(g >> 16));
    }
    unsigned pv = *(const unsigned*)&Pr[o];
    unsigned qv = *(const unsigned*)&Qr[o];
    float2 ss = *(const float2*)&sc2[o];
    float2 hh = *(const float2*)&sh2[o];
    float e0 = bf2f(pv & 0xffffu) - bf2f(qv & 0xffffu) + mx0;
    float e1 = bf2f(pv >> 16) - bf2f(qv >> 16) + mx1;
    float y0 = e0 * ss.x + hh.x;
    float y1 = e1 * ss.y + hh.y;
    float ge0 = 0.5f * y0 * (1.f + erff(y0 * 0.70710678118654752f));
    float ge1 = 0.5f * y1 * (1.f + erff(y1 * 0.70710678118654752f));
    *(unsigned*)&mbh[row * NCH + o] =
        (unsigned)f2bf(ge0) | ((unsigned)f2bf(ge1) << 16);
  }
}

// ---------- K5: out = BN3(m @ fc2_w^T) + x via MFMA, direct [c][n] store ----------
__global__ __launch_bounds__(BDIM) void k5_mfma(
    const unsigned short* __restrict__ mbh, const unsigned short* __restrict__ fc2b,
    const float* __restrict__ sc3, const float* __restrict__ sh3,
    const float* __restrict__ x, float* __restrict__ out) {
  __shared__ __align__(16) char abuf[2][24576];
  int t = threadIdx.x;
  int bid = blockIdx.x;
  int b = bid / 147;
  int rem = bid % 147;
  int n0 = (rem / 3) * 64;
  int oc = rem % 3;
  int lane = t & 63, w = t >> 6;
  int l15 = lane & 15, l4 = lane >> 4;
  int n = n0 + w * 16 + l15;
  short8 bfr[12];
  {
    const short8* brow = (const short8*)(mbh + (size_t)(b * NN + n) * NCH + l4 * 8);
#pragma unroll
    for (int kh = 0; kh < 2; ++kh)
#pragma unroll
      for (int ks = 0; ks < 6; ++ks) bfr[kh * 6 + ks] = brow[kh * 24 + ks * 4];
  }
  f32x4 acc[4];
#pragma unroll
  for (int sub = 0; sub < 4; ++sub) acc[sub] = {0.f, 0.f, 0.f, 0.f};

  const char* wt = (const char*)fc2b + (size_t)oc * 2 * 24576;
  stage_tile(wt, abuf[0], t);
  __syncthreads();
  for (int kh = 0; kh < 2; ++kh) {
    if (kh == 0) stage_tile(wt + 24576, abuf[1], t);
#pragma unroll
    for (int sub = 0; sub < 4; ++sub) {
      int r_ = sub * 16 + l15;
      int rbase = r_ * 384, sw = (r_ & 7) << 4;
#pragma unroll
      for (int ks = 0; ks < 6; ++ks) {
        short8 af = *(const short8*)&abuf[kh][rbase + ((ks * 64 + l4 * 16) ^ sw)];
        acc[sub] = __builtin_amdgcn_mfma_f32_16x16x32_bf16(af, bfr[kh * 6 + ks],
                                                           acc[sub], 0, 0, 0);
      }
    }
    __syncthreads();
  }
  const float* xb_ = x + (size_t)b * NC * NN;
  float* ob = out + (size_t)b * NC * NN;
#pragma unroll
  for (int sub = 0; sub < 4; ++sub) {
    int c4 = oc * 64 + sub * 16 + l4 * 4;
    float s_[4], h_[4];
    *(float4*)s_ = *(const float4*)&sc3[c4];
    *(float4*)h_ = *(const float4*)&sh3[c4];
#pragma unroll
    for (int r = 0; r < 4; ++r) {
      size_t off = (size_t)(c4 + r) * NN + n;
      ob[off] = acc[sub][r] * s_[r] + h_[r] + xb_[off];
    }
  }
}

extern "C" void kernel_launch(void* const* d_in, const int* in_sizes, int n_in,
                              void* d_out, int out_size, void* d_ws, size_t ws_size,
                              hipStream_t stream) {
  const float* x = (const float*)d_in[0];
  const float* fc1_w = (const float*)d_in[1];
  const float* fc1_b = (const float*)d_in[2];
  const float* bn1_g = (const float*)d_in[3];
  const float* bn1_b = (const float*)d_in[4];
  const float* bn1_m = (const float*)d_in[5];
  const float* bn1_v = (const float*)d_in[6];
  const float* gc_w = (const float*)d_in[7];
  const float* gc_b = (const float*)d_in[8];
  const float* bn2_g = (const float*)d_in[9];
  const float* bn2_b = (const float*)d_in[10];
  const float* bn2_m = (const float*)d_in[11];
  const float* bn2_v = (const float*)d_in[12];
  const float* fc2_w = (const float*)d_in[13];
  const float* fc2_b = (const float*)d_in[14];
  const float* bn3_g = (const float*)d_in[15];
  const float* bn3_b = (const float*)d_in[16];
  const float* bn3_m = (const float*)d_in[17];
  const float* bn3_v = (const float*)d_in[18];

  size_t nrow = (size_t)NROW;
  size_t npq = (size_t)NB * NN * NCH;
  size_t nhb = (size_t)NB * NN * NC;
  unsigned short* Pb = (unsigned short*)d_ws;
  unsigned short* Qb = Pb + npq;
  unsigned short* mbh = Qb + npq;
  float* norm = (float*)(mbh + npq);
  int* idx = (int*)(norm + nrow);
  unsigned short* hnb = (unsigned short*)(idx + nrow * NK);
  unsigned short* gcwb = hnb + nhb;
  unsigned short* fc1b = gcwb + 768 * NC;
  unsigned short* fc2b = fc1b + NC * NC;
  unsigned* candK = (unsigned*)(fc2b + NC * NCH);
  float* sc1 = (float*)(candK + 4 * NK * nrow);
  float* sh1 = sc1 + NC;
  float* sc2 = sh1 + NC;
  float* sh2 = sc2 + NCH;
  float* sc3 = sh2 + NCH;
  float* sh3 = sc3 + NC;

  k0_convw<<<252, BDIM, 0, stream>>>(gc_w, fc1_w, fc2_w, gcwb, fc1b, fc2b);
  k0b_params<<<1, 384, 0, stream>>>(fc1_b, bn1_g, bn1_b, bn1_m, bn1_v, gc_b,
                                    bn2_g, bn2_b, bn2_m, bn2_v, fc2_b, bn3_g,
                                    bn3_b, bn3_m, bn3_v, sc1, sh1, sc2, sh2,
                                    sc3, sh3);
  k1_mfma<<<NB * 49, BDIM, 0, stream>>>(x, fc1b, sc1, sh1, hnb, norm);
  k23_fused<<<NB * 245, 512, 0, stream>>>(hnb, norm, gcwb, candK, Pb, Qb);
  k2b_merge<<<NROW / BDIM, BDIM, 0, stream>>>(candK, idx);
  k4_gathermax<<<(NB * NN) / 4, BDIM, 0, stream>>>(Pb, Qb, idx, sc2, sh2, mbh);
  k5_mfma<<<NB * 147, BDIM, 0, stream>>>(mbh, fc2b, sc3, sh3, x, (float*)d_out);
}

// Round 13
// 158.042 us; speedup vs baseline: 3.1709x; 1.0016x over previous
//
#include <hip/hip_runtime.h>

#define BDIM 256
#define NB 8
#define NC 192
#define NN 3136         // 56*56 = 49*64
#define NCH 384
#define NK 9
#define NROW (NB * NN)  // 25088

typedef __attribute__((ext_vector_type(8))) short short8;
typedef __attribute__((ext_vector_type(4))) float f32x4;

__device__ __forceinline__ unsigned short f2bf(float f) {
  union { float f; unsigned u; } x{f};
  unsigned r = x.u + 0x7fff + ((x.u >> 16) & 1);  // RNE
  return (unsigned short)(r >> 16);
}

__device__ __forceinline__ float bf2f(unsigned u16) {
  union { unsigned u; float f; } x{u16 << 16};
  return x.f;
}

// sortable-u32 transform of float bits: order-preserving for all finite values
__device__ __forceinline__ unsigned fsort(float f) {
  union { float f; unsigned u; } x{f};
  return x.u ^ ((unsigned)(((int)x.u) >> 31) | 0x80000000u);
}

__device__ __forceinline__ void gload16(const char* g, char* l) {
  __builtin_amdgcn_global_load_lds(
      (const __attribute__((address_space(1))) unsigned int*)g,
      (__attribute__((address_space(3))) unsigned int*)l, 16, 0, 0);
}

// stage one 24KB [64 rows][384B] bf16 tile into LDS (async, width 16), 256 thr.
// LDS dest linear; global source pre-XOR-swizzled: LDS[m][kb] = G[m][kb^((m&7)<<4)].
__device__ __forceinline__ void stage_tile(const char* gbase, char* lbuf, int t) {
#pragma unroll
  for (int i = 0; i < 6; ++i) {
    int L = (i * 256 + t) * 16;
    int m = L / 384;
    int kb = L - m * 384;
    gload16(gbase + m * 384 + (kb ^ ((m & 7) << 4)), lbuf + L);
  }
}

// ---------- K0: bf16 weight conversion ----------
__global__ __launch_bounds__(BDIM) void k0_convw(
    const float* __restrict__ gw, const float* __restrict__ f1w,
    const float* __restrict__ f2w, unsigned short* __restrict__ gcwb,
    unsigned short* __restrict__ fc1b, unsigned short* __restrict__ fc2b) {
  int i = (blockIdx.x * BDIM + threadIdx.x) * 4;
  const float* src;
  unsigned short* dst;
  if (i < 147456) {  // gc_w split
    int o = i / NC, k = i - o * NC;
    src = gw + (size_t)(o < NCH ? o : o - NCH) * (2 * NC) + (o < NCH ? 0 : NC) + k;
    dst = gcwb + i;
  } else if (i < 184320) {  // fc1
    int j = i - 147456;
    src = f1w + j;
    dst = fc1b + j;
  } else {  // fc2 retile [(oc*2+kh)][64][192]
    int j = i - 184320;
    int o = j / NCH, k = j - o * NCH;
    int oc = o >> 6, om = o & 63;
    int kh = k / 192, km = k - kh * 192;
    src = f2w + j;
    dst = fc2b + ((size_t)((oc * 2 + kh) * 64 + om)) * 192 + km;
  }
  float4 v = *(const float4*)src;
  uint2 u;
  u.x = (unsigned)f2bf(v.x) | ((unsigned)f2bf(v.y) << 16);
  u.y = (unsigned)f2bf(v.z) | ((unsigned)f2bf(v.w) << 16);
  *(uint2*)dst = u;
}

// ---------- K0b: fold BN params: val = gemm*sc + sh ----------
__global__ __launch_bounds__(384) void k0b_params(
    const float* __restrict__ f1b, const float* __restrict__ g1,
    const float* __restrict__ b1, const float* __restrict__ m1,
    const float* __restrict__ v1, const float* __restrict__ gcb,
    const float* __restrict__ g2, const float* __restrict__ b2,
    const float* __restrict__ m2, const float* __restrict__ v2,
    const float* __restrict__ f2b, const float* __restrict__ g3,
    const float* __restrict__ b3, const float* __restrict__ m3,
    const float* __restrict__ v3, float* __restrict__ sc1,
    float* __restrict__ sh1, float* __restrict__ sc2, float* __restrict__ sh2,
    float* __restrict__ sc3, float* __restrict__ sh3) {
  int c = threadIdx.x;
  if (c < NC) {
    float s1 = g1[c] * rsqrtf(v1[c] + 1e-5f);
    sc1[c] = s1;
    sh1[c] = (f1b[c] - m1[c]) * s1 + b1[c];
    float s3 = g3[c] * rsqrtf(v3[c] + 1e-5f);
    sc3[c] = s3;
    sh3[c] = (f2b[c] - m3[c]) * s3 + b3[c];
  }
  float s2 = g2[c] * rsqrtf(v2[c] + 1e-5f);
  sc2[c] = s2;
  sh2[c] = (gcb[c] - m2[c]) * s2 + b2[c];
}

// ---------- K1: h = BN1(x @ fc1_w^T) via MFMA; x read directly (fused transpose) ----------
__global__ __launch_bounds__(BDIM) void k1_mfma(
    const float* __restrict__ x, const unsigned short* __restrict__ fc1b,
    const float* __restrict__ sc1, const float* __restrict__ sh1,
    unsigned short* __restrict__ hnb, float* __restrict__ normo) {
  __shared__ __align__(16) char abuf[2][24576];
  int t = threadIdx.x;
  int b = blockIdx.x / 49, n0 = (blockIdx.x % 49) * 64;
  int lane = t & 63, w = t >> 6;
  int l15 = lane & 15, l4 = lane >> 4;
  int n = n0 + w * 16 + l15;
  short8 bfr[6];
  {
    const float* xcol = x + (size_t)b * NC * NN + n;
#pragma unroll
    for (int ks = 0; ks < 6; ++ks) {
      union { short8 s; unsigned u[4]; } pk;
#pragma unroll
      for (int j = 0; j < 4; ++j) {
        float v0 = xcol[(size_t)(ks * 32 + l4 * 8 + 2 * j) * NN];
        float v1 = xcol[(size_t)(ks * 32 + l4 * 8 + 2 * j + 1) * NN];
        pk.u[j] = (unsigned)f2bf(v0) | ((unsigned)f2bf(v1) << 16);
      }
      bfr[ks] = pk.s;
    }
  }
  f32x4 acc[3][4];
#pragma unroll
  for (int oc = 0; oc < 3; ++oc)
#pragma unroll
    for (int sub = 0; sub < 4; ++sub) acc[oc][sub] = {0.f, 0.f, 0.f, 0.f};

  const char* wB = (const char*)fc1b;
  stage_tile(wB, abuf[0], t);
  __syncthreads();
  for (int oc = 0; oc < 3; ++oc) {
    int cur = oc & 1;
    if (oc < 2) stage_tile(wB + (size_t)(oc + 1) * 24576, abuf[cur ^ 1], t);
#pragma unroll
    for (int sub = 0; sub < 4; ++sub) {
      int r_ = sub * 16 + l15;
      int rbase = r_ * 384, sw = (r_ & 7) << 4;
#pragma unroll
      for (int ks = 0; ks < 6; ++ks) {
        short8 af = *(const short8*)&abuf[cur][rbase + ((ks * 64 + l4 * 16) ^ sw)];
        acc[oc][sub] = __builtin_amdgcn_mfma_f32_16x16x32_bf16(af, bfr[ks],
                                                               acc[oc][sub], 0, 0, 0);
      }
    }
    __syncthreads();
  }
  float p = 0.f;
#pragma unroll
  for (int oc = 0; oc < 3; ++oc)
#pragma unroll
    for (int sub = 0; sub < 4; ++sub) {
      int c4 = oc * 64 + sub * 16 + l4 * 4;
      float s_[4], h_[4];
      *(float4*)s_ = *(const float4*)&sc1[c4];
      *(float4*)h_ = *(const float4*)&sh1[c4];
#pragma unroll
      for (int r = 0; r < 4; ++r) {
        float v = acc[oc][sub][r] * s_[r] + h_[r];
        acc[oc][sub][r] = v;
        p += v * v;
      }
    }
  p += __shfl_xor(p, 16);
  p += __shfl_xor(p, 32);
  float nr = fmaxf(sqrtf(p), 1e-12f);
  float iv = 1.f / nr;
  if (l4 == 0) normo[(size_t)b * NN + n] = nr;
#pragma unroll
  for (int oc = 0; oc < 3; ++oc)
#pragma unroll
    for (int sub = 0; sub < 4; ++sub) {
      uint2 u;
      u.x = (unsigned)f2bf(acc[oc][sub][0] * iv) |
            ((unsigned)f2bf(acc[oc][sub][1] * iv) << 16);
      u.y = (unsigned)f2bf(acc[oc][sub][2] * iv) |
            ((unsigned)f2bf(acc[oc][sub][3] * iv) << 16);
      *(uint2*)&hnb[(size_t)(b * NN + n) * NC + oc * 64 + sub * 16 + l4 * 4] = u;
    }
}

// ---------- K23: fused 512-thread dispatch — k2a (topk, m-split 2) + k3 (P,Q) ----------
// 8 waves share one 2x12KB double-buffer. Wave w: n-group w&3, sub w>>2.
// Per XCD (= bid&7): 2 k2a : 1 k3 interleave; all loop-invariant addresses hoisted.
__global__ __launch_bounds__(512) void k23_fused(
    const unsigned short* __restrict__ hnb, const float* __restrict__ norm,
    const unsigned short* __restrict__ gcwb, unsigned* __restrict__ candK,
    unsigned short* __restrict__ P, unsigned short* __restrict__ Q) {
  __shared__ __align__(16) char abuf[2][12288];
  int t = threadIdx.x;
  int bid = blockIdx.x;
  int b = bid & 7;          // batch == XCD
  int j = bid >> 3;         // 0..146 per XCD
  int lane = t & 63, w = t >> 6;
  int l15 = lane & 15, l4 = lane >> 4;
  int wg = w & 3, sub = w >> 2;
  const unsigned short* hb = hnb + (size_t)b * NN * NC;

  // hoisted staging offsets (swizzled global offset + linear LDS offset)
  int L0 = t * 16;
  int m0_ = L0 / 384, kb0 = L0 - m0_ * 384;
  int g0 = m0_ * 384 + (kb0 ^ ((m0_ & 7) << 4));
  int L1 = (512 + t) * 16;
  int m1_ = L1 / 384, kb1 = L1 - m1_ * 384;
  int g1 = m1_ * 384 + (kb1 ^ ((m1_ & 7) << 4));
  // hoisted ds_read offsets for this lane's sub-row
  int r_ = sub * 16 + l15;
  int rbase = r_ * 384, sw = (r_ & 7) << 4;
  int dso[6];
#pragma unroll
  for (int ks = 0; ks < 6; ++ks) dso[ks] = rbase + ((ks * 64 + l4 * 16) ^ sw);

  if (j % 3 != 2) {
    // ---- k2a role: 98 blocks/XCD; 64 n x half-m top-9 candidates ----
    int idx2a = (j / 3) * 2 + (j % 3);  // 0..97
    int n0 = (idx2a >> 1) * 64;
    int seg = idx2a & 1;
    int mt0 = seg * 49;                 // 49 32-row tiles per segment
    const char* hbB = (const char*)hb + (size_t)mt0 * 12288;

    short8 bfr[6];
    {
      const short8* brow =
          (const short8*)(hb + (size_t)(n0 + wg * 16 + l15) * NC + l4 * 8);
#pragma unroll
      for (int ks = 0; ks < 6; ++ks) bfr[ks] = brow[ks * 4];
    }
    unsigned tk[NK];
#pragma unroll
    for (int r = 0; r < NK; ++r) tk[r] = 0u;

    gload16(hbB + g0, abuf[0] + L0);
    if (t < 256) gload16(hbB + g1, abuf[0] + L1);
    __syncthreads();
    for (int ti = 0; ti < 49; ++ti) {
      int cur = ti & 1;
      if (ti < 48) {
        const char* src = hbB + (size_t)(ti + 1) * 12288;
        char* dstl = abuf[cur ^ 1];
        gload16(src + g0, dstl + L0);
        if (t < 256) gload16(src + g1, dstl + L1);
      }
      const char* lb = abuf[cur];
      short8 af[6];
#pragma unroll
      for (int ks = 0; ks < 6; ++ks) af[ks] = *(const short8*)&lb[dso[ks]];
      f32x4 acc = {0.f, 0.f, 0.f, 0.f};
#pragma unroll
      for (int ks = 0; ks < 6; ++ks)
        acc = __builtin_amdgcn_mfma_f32_16x16x32_bf16(af[ks], bfr[ks], acc, 0, 0, 0);
      int mknd = 4095 - ((mt0 + ti) * 32 + sub * 16 + l4 * 4);
#pragma unroll
      for (int r = 0; r < 4; ++r) {
        unsigned cur_k = (fsort(acc[r]) & 0xFFFFF000u) | (unsigned)(mknd - r);
#pragma unroll
        for (int q = 0; q < NK; ++q) {
          unsigned hi = tk[q] > cur_k ? tk[q] : cur_k;
          unsigned lo = tk[q] > cur_k ? cur_k : tk[q];
          tk[q] = hi;
          cur_k = lo;
        }
      }
      __syncthreads();
    }
    // merge 8 lists per n-row: [64 rows][8 lists][9] = 18KB (aliases abuf)
    unsigned* mkeys = (unsigned*)&abuf[0][0];
    int rw = wg * 16 + l15;
#pragma unroll
    for (int r = 0; r < NK; ++r) mkeys[(rw * 8 + sub * 4 + l4) * NK + r] = tk[r];
    __syncthreads();
    if (t < 256) {  // stage 2: merge list pairs {g, g+4} -> list g
      int row = t >> 2, g = t & 3;
      unsigned* a = &mkeys[(row * 8 + g) * NK];
      const unsigned* c = &mkeys[(row * 8 + g + 4) * NK];
      unsigned best[NK];
#pragma unroll
      for (int r = 0; r < NK; ++r) best[r] = 0u;
#pragma unroll
      for (int s = 0; s < 2 * NK; ++s) {
        unsigned cur_k = s < NK ? a[s] : c[s - NK];
#pragma unroll
        for (int q = 0; q < NK; ++q) {
          unsigned hi = best[q] > cur_k ? best[q] : cur_k;
          unsigned lo = best[q] > cur_k ? cur_k : best[q];
          best[q] = hi;
          cur_k = lo;
        }
      }
#pragma unroll
      for (int r = 0; r < NK; ++r) a[r] = best[r];
    }
    __syncthreads();
    if (t < 64) {  // stage 3: merge lists 0..3 (36 keys)
      const unsigned* src = &mkeys[(t * 8) * NK];
      unsigned best[NK];
#pragma unroll
      for (int r = 0; r < NK; ++r) best[r] = 0u;
      for (int s = 0; s < 36; ++s) {
        unsigned cur_k = src[s];
#pragma unroll
        for (int q = 0; q < NK; ++q) {
          unsigned hi = best[q] > cur_k ? best[q] : cur_k;
          unsigned lo = best[q] > cur_k ? cur_k : best[q];
          best[q] = hi;
          cur_k = lo;
        }
      }
      size_t row = (size_t)b * NN + n0 + t;
#pragma unroll
      for (int r = 0; r < NK; ++r)
        candK[(size_t)(seg * NK + r) * NROW + row] = best[r];
    }
  } else {
    // ---- k3 role: 49 blocks/XCD; P,Q = bf16((hn @ gcwb^T) * norm), 24 chunks ----
    int jj = j / 3;  // 0..48
    int n0 = jj * 64;
    int n = n0 + wg * 16 + l15;
    short8 bfr[6];
    {
      const short8* brow = (const short8*)(hb + (size_t)n * NC + l4 * 8);
#pragma unroll
      for (int ks = 0; ks < 6; ++ks) bfr[ks] = brow[ks * 4];
    }
    float nrm = norm[(size_t)b * NN + n];
    size_t orow = (size_t)b * NN + n;
    const char* wB = (const char*)gcwb;

    gload16(wB + g0, abuf[0] + L0);
    if (t < 256) gload16(wB + g1, abuf[0] + L1);
    __syncthreads();
    for (int ch = 0; ch < 24; ++ch) {
      int cur = ch & 1;
      if (ch < 23) {
        const char* src = wB + (size_t)(ch + 1) * 12288;
        char* dstl = abuf[cur ^ 1];
        gload16(src + g0, dstl + L0);
        if (t < 256) gload16(src + g1, dstl + L1);
      }
      const char* lb = abuf[cur];
      f32x4 acc = {0.f, 0.f, 0.f, 0.f};
#pragma unroll
      for (int ks = 0; ks < 6; ++ks) {
        short8 af = *(const short8*)&lb[dso[ks]];
        acc = __builtin_amdgcn_mfma_f32_16x16x32_bf16(af, bfr[ks], acc, 0, 0, 0);
      }
      int o = ch * 32 + sub * 16 + l4 * 4;
      f32x4 st = acc * nrm;
      unsigned short* dst = (o < NCH) ? P : Q;
      int oo = (o < NCH) ? o : o - NCH;
      uint2 u;
      u.x = (unsigned)f2bf(st[0]) | ((unsigned)f2bf(st[1]) << 16);
      u.y = (unsigned)f2bf(st[2]) | ((unsigned)f2bf(st[3]) << 16);
      *(uint2*)&dst[orow * NCH + oo] = u;
      __syncthreads();
    }
  }
}

// ---------- K2b: merge 2x9 keys/row -> final top-9 indices ----------
__global__ __launch_bounds__(BDIM) void k2b_merge(const unsigned* __restrict__ candK,
                                                  int* __restrict__ idxo) {
  int row = blockIdx.x * BDIM + threadIdx.x;
  unsigned tk[NK];
#pragma unroll
  for (int r = 0; r < NK; ++r) tk[r] = 0u;
  for (int s = 0; s < 2 * NK; ++s) {
    unsigned cur = candK[(size_t)s * NROW + row];
#pragma unroll
    for (int j = 0; j < NK; ++j) {
      unsigned hi = tk[j] > cur ? tk[j] : cur;
      unsigned lo = tk[j] > cur ? cur : tk[j];
      tk[j] = hi;
      cur = lo;
    }
  }
#pragma unroll
  for (int r = 0; r < NK; ++r)
    idxo[(size_t)row * NK + r] = 4095 - (int)(tk[r] & 4095u);
}

// ---------- K4: batch->XCD-pinned gather-max + BN2 + gelu, bf16 out ----------
__global__ __launch_bounds__(BDIM) void k4_gathermax(
    const unsigned short* __restrict__ P, const unsigned short* __restrict__ Q,
    const int* __restrict__ idx, const float* __restrict__ sc2,
    const float* __restrict__ sh2, unsigned short* __restrict__ mbh) {
  int t = threadIdx.x;
  int lane = t & 63, wv = t >> 6;
  int b = blockIdx.x & 7;                      // batch == XCD (L2 pin for Q slab)
  int n = (int)(blockIdx.x >> 3) * 4 + wv;     // 0..3135
  size_t row = (size_t)b * NN + n;
  const int* ip = idx + row * NK;
  int id[NK];
#pragma unroll
  for (int k = 0; k < NK; ++k) id[k] = ip[k];
  const unsigned short* Qb = Q + (size_t)b * NN * NCH;
  const unsigned short* Pr = P + row * NCH;
  const unsigned short* Qr = Qb + (size_t)n * NCH;
#pragma unroll
  for (int j = 0; j < 3; ++j) {
    int o = j * 128 + lane * 2;
    float mx0 = -1e30f, mx1 = -1e30f;
#pragma unroll
    for (int k = 0; k < NK; ++k) {
      unsigned g = *(const unsigned*)&Qb[(size_t)id[k] * NCH + o];
      mx0 = fmaxf(mx0, bf2f(g & 0xffffu));
      mx1 = fmaxf(mx1, bf2f(g >> 16));
    }
    unsigned pv = *(const unsigned*)&Pr[o];
    unsigned qv = *(const unsigned*)&Qr[o];
    float2 ss = *(const float2*)&sc2[o];
    float2 hh = *(const float2*)&sh2[o];
    float e0 = bf2f(pv & 0xffffu) - bf2f(qv & 0xffffu) + mx0;
    float e1 = bf2f(pv >> 16) - bf2f(qv >> 16) + mx1;
    float y0 = e0 * ss.x + hh.x;
    float y1 = e1 * ss.y + hh.y;
    float ge0 = 0.5f * y0 * (1.f + erff(y0 * 0.70710678118654752f));
    float ge1 = 0.5f * y1 * (1.f + erff(y1 * 0.70710678118654752f));
    *(unsigned*)&mbh[row * NCH + o] =
        (unsigned)f2bf(ge0) | ((unsigned)f2bf(ge1) << 16);
  }
}

// ---------- K5: out = BN3(m @ fc2_w^T) + x via MFMA, direct [c][n] store ----------
__global__ __launch_bounds__(BDIM) void k5_mfma(
    const unsigned short* __restrict__ mbh, const unsigned short* __restrict__ fc2b,
    const float* __restrict__ sc3, const float* __restrict__ sh3,
    const float* __restrict__ x, float* __restrict__ out) {
  __shared__ __align__(16) char abuf[2][24576];
  int t = threadIdx.x;
  int bid = blockIdx.x;
  int b = bid / 147;
  int rem = bid % 147;
  int n0 = (rem / 3) * 64;
  int oc = rem % 3;
  int lane = t & 63, w = t >> 6;
  int l15 = lane & 15, l4 = lane >> 4;
  int n = n0 + w * 16 + l15;
  short8 bfr[12];
  {
    const short8* brow = (const short8*)(mbh + (size_t)(b * NN + n) * NCH + l4 * 8);
#pragma unroll
    for (int kh = 0; kh < 2; ++kh)
#pragma unroll
      for (int ks = 0; ks < 6; ++ks) bfr[kh * 6 + ks] = brow[kh * 24 + ks * 4];
  }
  f32x4 acc[4];
#pragma unroll
  for (int sub = 0; sub < 4; ++sub) acc[sub] = {0.f, 0.f, 0.f, 0.f};

  const char* wt = (const char*)fc2b + (size_t)oc * 2 * 24576;
  stage_tile(wt, abuf[0], t);
  __syncthreads();
  for (int kh = 0; kh < 2; ++kh) {
    if (kh == 0) stage_tile(wt + 24576, abuf[1], t);
#pragma unroll
    for (int sub = 0; sub < 4; ++sub) {
      int r_ = sub * 16 + l15;
      int rbase = r_ * 384, sw = (r_ & 7) << 4;
#pragma unroll
      for (int ks = 0; ks < 6; ++ks) {
        short8 af = *(const short8*)&abuf[kh][rbase + ((ks * 64 + l4 * 16) ^ sw)];
        acc[sub] = __builtin_amdgcn_mfma_f32_16x16x32_bf16(af, bfr[kh * 6 + ks],
                                                           acc[sub], 0, 0, 0);
      }
    }
    __syncthreads();
  }
  const float* xb_ = x + (size_t)b * NC * NN;
  float* ob = out + (size_t)b * NC * NN;
#pragma unroll
  for (int sub = 0; sub < 4; ++sub) {
    int c4 = oc * 64 + sub * 16 + l4 * 4;
    float s_[4], h_[4];
    *(float4*)s_ = *(const float4*)&sc3[c4];
    *(float4*)h_ = *(const float4*)&sh3[c4];
#pragma unroll
    for (int r = 0; r < 4; ++r) {
      size_t off = (size_t)(c4 + r) * NN + n;
      ob[off] = acc[sub][r] * s_[r] + h_[r] + xb_[off];
    }
  }
}

extern "C" void kernel_launch(void* const* d_in, const int* in_sizes, int n_in,
                              void* d_out, int out_size, void* d_ws, size_t ws_size,
                              hipStream_t stream) {
  const float* x = (const float*)d_in[0];
  const float* fc1_w = (const float*)d_in[1];
  const float* fc1_b = (const float*)d_in[2];
  const float* bn1_g = (const float*)d_in[3];
  const float* bn1_b = (const float*)d_in[4];
  const float* bn1_m = (const float*)d_in[5];
  const float* bn1_v = (const float*)d_in[6];
  const float* gc_w = (const float*)d_in[7];
  const float* gc_b = (const float*)d_in[8];
  const float* bn2_g = (const float*)d_in[9];
  const float* bn2_b = (const float*)d_in[10];
  const float* bn2_m = (const float*)d_in[11];
  const float* bn2_v = (const float*)d_in[12];
  const float* fc2_w = (const float*)d_in[13];
  const float* fc2_b = (const float*)d_in[14];
  const float* bn3_g = (const float*)d_in[15];
  const float* bn3_b = (const float*)d_in[16];
  const float* bn3_m = (const float*)d_in[17];
  const float* bn3_v = (const float*)d_in[18];

  size_t nrow = (size_t)NROW;
  size_t npq = (size_t)NB * NN * NCH;
  size_t nhb = (size_t)NB * NN * NC;
  unsigned short* Pb = (unsigned short*)d_ws;
  unsigned short* Qb = Pb + npq;
  unsigned short* mbh = Qb + npq;
  float* norm = (float*)(mbh + npq);
  int* idx = (int*)(norm + nrow);
  unsigned short* hnb = (unsigned short*)(idx + nrow * NK);
  unsigned short* gcwb = hnb + nhb;
  unsigned short* fc1b = gcwb + 768 * NC;
  unsigned short* fc2b = fc1b + NC * NC;
  unsigned* candK = (unsigned*)(fc2b + NC * NCH);
  float* sc1 = (float*)(candK + 2 * NK * nrow);
  float* sh1 = sc1 + NC;
  float* sc2 = sh1 + NC;
  float* sh2 = sc2 + NCH;
  float* sc3 = sh2 + NCH;
  float* sh3 = sc3 + NC;

  k0_convw<<<252, BDIM, 0, stream>>>(gc_w, fc1_w, fc2_w, gcwb, fc1b, fc2b);
  k0b_params<<<1, 384, 0, stream>>>(fc1_b, bn1_g, bn1_b, bn1_m, bn1_v, gc_b,
                                    bn2_g, bn2_b, bn2_m, bn2_v, fc2_b, bn3_g,
                                    bn3_b, bn3_m, bn3_v, sc1, sh1, sc2, sh2,
                                    sc3, sh3);
  k1_mfma<<<NB * 49, BDIM, 0, stream>>>(x, fc1b, sc1, sh1, hnb, norm);
  k23_fused<<<NB * 147, 512, 0, stream>>>(hnb, norm, gcwb, candK, Pb, Qb);
  k2b_merge<<<NROW / BDIM, BDIM, 0, stream>>>(candK, idx);
  k4_gathermax<<<(NB * NN) / 4, BDIM, 0, stream>>>(Pb, Qb, idx, sc2, sh2, mbh);
  k5_mfma<<<NB * 147, BDIM, 0, stream>>>(mbh, fc2b, sc3, sh3, x, (float*)d_out);
}

// Round 14
// 155.565 us; speedup vs baseline: 3.2214x; 1.0159x over previous
//
#include <hip/hip_runtime.h>

#define BDIM 256
#define NB 8
#define NC 192
#define NN 3136         // 56*56 = 49*64
#define NCH 384
#define NK 9
#define NROW (NB * NN)  // 25088

typedef __attribute__((ext_vector_type(8))) short short8;
typedef __attribute__((ext_vector_type(4))) float f32x4;

__device__ __forceinline__ unsigned short f2bf(float f) {
  union { float f; unsigned u; } x{f};
  unsigned r = x.u + 0x7fff + ((x.u >> 16) & 1);  // RNE
  return (unsigned short)(r >> 16);
}

__device__ __forceinline__ float bf2f(unsigned u16) {
  union { unsigned u; float f; } x{u16 << 16};
  return x.f;
}

// sortable-u32 transform of float bits: order-preserving for all finite values
__device__ __forceinline__ unsigned fsort(float f) {
  union { float f; unsigned u; } x{f};
  return x.u ^ ((unsigned)(((int)x.u) >> 31) | 0x80000000u);
}

__device__ __forceinline__ void gload16(const char* g, char* l) {
  __builtin_amdgcn_global_load_lds(
      (const __attribute__((address_space(1))) unsigned int*)g,
      (__attribute__((address_space(3))) unsigned int*)l, 16, 0, 0);
}

// stage one 24KB [64 rows][384B] bf16 tile into LDS (async, width 16), 256 thr.
// LDS dest linear; global source pre-XOR-swizzled: LDS[m][kb] = G[m][kb^((m&7)<<4)].
__device__ __forceinline__ void stage_tile(const char* gbase, char* lbuf, int t) {
#pragma unroll
  for (int i = 0; i < 6; ++i) {
    int L = (i * 256 + t) * 16;
    int m = L / 384;
    int kb = L - m * 384;
    gload16(gbase + m * 384 + (kb ^ ((m & 7) << 4)), lbuf + L);
  }
}

// ---------- K0: bf16 weight conversion ----------
__global__ __launch_bounds__(BDIM) void k0_convw(
    const float* __restrict__ gw, const float* __restrict__ f1w,
    const float* __restrict__ f2w, unsigned short* __restrict__ gcwb,
    unsigned short* __restrict__ fc1b, unsigned short* __restrict__ fc2b) {
  int i = (blockIdx.x * BDIM + threadIdx.x) * 4;
  const float* src;
  unsigned short* dst;
  if (i < 147456) {  // gc_w split
    int o = i / NC, k = i - o * NC;
    src = gw + (size_t)(o < NCH ? o : o - NCH) * (2 * NC) + (o < NCH ? 0 : NC) + k;
    dst = gcwb + i;
  } else if (i < 184320) {  // fc1
    int j = i - 147456;
    src = f1w + j;
    dst = fc1b + j;
  } else {  // fc2 retile [(oc*2+kh)][64][192]
    int j = i - 184320;
    int o = j / NCH, k = j - o * NCH;
    int oc = o >> 6, om = o & 63;
    int kh = k / 192, km = k - kh * 192;
    src = f2w + j;
    dst = fc2b + ((size_t)((oc * 2 + kh) * 64 + om)) * 192 + km;
  }
  float4 v = *(const float4*)src;
  uint2 u;
  u.x = (unsigned)f2bf(v.x) | ((unsigned)f2bf(v.y) << 16);
  u.y = (unsigned)f2bf(v.z) | ((unsigned)f2bf(v.w) << 16);
  *(uint2*)dst = u;
}

// ---------- K0b: fold BN params: val = gemm*sc + sh ----------
__global__ __launch_bounds__(384) void k0b_params(
    const float* __restrict__ f1b, const float* __restrict__ g1,
    const float* __restrict__ b1, const float* __restrict__ m1,
    const float* __restrict__ v1, const float* __restrict__ gcb,
    const float* __restrict__ g2, const float* __restrict__ b2,
    const float* __restrict__ m2, const float* __restrict__ v2,
    const float* __restrict__ f2b, const float* __restrict__ g3,
    const float* __restrict__ b3, const float* __restrict__ m3,
    const float* __restrict__ v3, float* __restrict__ sc1,
    float* __restrict__ sh1, float* __restrict__ sc2, float* __restrict__ sh2,
    float* __restrict__ sc3, float* __restrict__ sh3) {
  int c = threadIdx.x;
  if (c < NC) {
    float s1 = g1[c] * rsqrtf(v1[c] + 1e-5f);
    sc1[c] = s1;
    sh1[c] = (f1b[c] - m1[c]) * s1 + b1[c];
    float s3 = g3[c] * rsqrtf(v3[c] + 1e-5f);
    sc3[c] = s3;
    sh3[c] = (f2b[c] - m3[c]) * s3 + b3[c];
  }
  float s2 = g2[c] * rsqrtf(v2[c] + 1e-5f);
  sc2[c] = s2;
  sh2[c] = (gcb[c] - m2[c]) * s2 + b2[c];
}

// ---------- K1: h = BN1(x @ fc1_w^T) via MFMA; x read directly (fused transpose) ----------
__global__ __launch_bounds__(BDIM) void k1_mfma(
    const float* __restrict__ x, const unsigned short* __restrict__ fc1b,
    const float* __restrict__ sc1, const float* __restrict__ sh1,
    unsigned short* __restrict__ hnb, float* __restrict__ normo) {
  __shared__ __align__(16) char abuf[2][24576];
  int t = threadIdx.x;
  int b = blockIdx.x / 49, n0 = (blockIdx.x % 49) * 64;
  int lane = t & 63, w = t >> 6;
  int l15 = lane & 15, l4 = lane >> 4;
  int n = n0 + w * 16 + l15;
  short8 bfr[6];
  {
    const float* xcol = x + (size_t)b * NC * NN + n;
#pragma unroll
    for (int ks = 0; ks < 6; ++ks) {
      union { short8 s; unsigned u[4]; } pk;
#pragma unroll
      for (int j = 0; j < 4; ++j) {
        float v0 = xcol[(size_t)(ks * 32 + l4 * 8 + 2 * j) * NN];
        float v1 = xcol[(size_t)(ks * 32 + l4 * 8 + 2 * j + 1) * NN];
        pk.u[j] = (unsigned)f2bf(v0) | ((unsigned)f2bf(v1) << 16);
      }
      bfr[ks] = pk.s;
    }
  }
  f32x4 acc[3][4];
#pragma unroll
  for (int oc = 0; oc < 3; ++oc)
#pragma unroll
    for (int sub = 0; sub < 4; ++sub) acc[oc][sub] = {0.f, 0.f, 0.f, 0.f};

  const char* wB = (const char*)fc1b;
  stage_tile(wB, abuf[0], t);
  __syncthreads();
  for (int oc = 0; oc < 3; ++oc) {
    int cur = oc & 1;
    if (oc < 2) stage_tile(wB + (size_t)(oc + 1) * 24576, abuf[cur ^ 1], t);
#pragma unroll
    for (int sub = 0; sub < 4; ++sub) {
      int r_ = sub * 16 + l15;
      int rbase = r_ * 384, sw = (r_ & 7) << 4;
#pragma unroll
      for (int ks = 0; ks < 6; ++ks) {
        short8 af = *(const short8*)&abuf[cur][rbase + ((ks * 64 + l4 * 16) ^ sw)];
        acc[oc][sub] = __builtin_amdgcn_mfma_f32_16x16x32_bf16(af, bfr[ks],
                                                               acc[oc][sub], 0, 0, 0);
      }
    }
    __syncthreads();
  }
  float p = 0.f;
#pragma unroll
  for (int oc = 0; oc < 3; ++oc)
#pragma unroll
    for (int sub = 0; sub < 4; ++sub) {
      int c4 = oc * 64 + sub * 16 + l4 * 4;
      float s_[4], h_[4];
      *(float4*)s_ = *(const float4*)&sc1[c4];
      *(float4*)h_ = *(const float4*)&sh1[c4];
#pragma unroll
      for (int r = 0; r < 4; ++r) {
        float v = acc[oc][sub][r] * s_[r] + h_[r];
        acc[oc][sub][r] = v;
        p += v * v;
      }
    }
  p += __shfl_xor(p, 16);
  p += __shfl_xor(p, 32);
  float nr = fmaxf(sqrtf(p), 1e-12f);
  float iv = 1.f / nr;
  if (l4 == 0) normo[(size_t)b * NN + n] = nr;
#pragma unroll
  for (int oc = 0; oc < 3; ++oc)
#pragma unroll
    for (int sub = 0; sub < 4; ++sub) {
      uint2 u;
      u.x = (unsigned)f2bf(acc[oc][sub][0] * iv) |
            ((unsigned)f2bf(acc[oc][sub][1] * iv) << 16);
      u.y = (unsigned)f2bf(acc[oc][sub][2] * iv) |
            ((unsigned)f2bf(acc[oc][sub][3] * iv) << 16);
      *(uint2*)&hnb[(size_t)(b * NN + n) * NC + oc * 64 + sub * 16 + l4 * 4] = u;
    }
}

// ---------- K23: fused 512-thr dispatch, counted-vmcnt double buffering ----------
// Waves 0-5 stage (2 gload16/thread = 12KB); per tile: issue stage(t+1),
// s_waitcnt vmcnt(2) (tile t's loads done, t+1's stay in flight), s_barrier,
// compute, s_barrier. No vmcnt(0) drain in the loop. 4 k2a : 1 k3 per XCD.
__global__ __launch_bounds__(512) void k23_fused(
    const unsigned short* __restrict__ hnb, const float* __restrict__ norm,
    const unsigned short* __restrict__ gcwb, unsigned* __restrict__ candK,
    unsigned short* __restrict__ P, unsigned short* __restrict__ Q) {
  __shared__ __align__(16) char abuf[2][12288];
  int t = threadIdx.x;
  int bid = blockIdx.x;
  int b = bid & 7;          // batch == XCD
  int j = bid >> 3;         // 0..244 per XCD
  int lane = t & 63, w = t >> 6;
  int l15 = lane & 15, l4 = lane >> 4;
  int wg = w & 3, sub = w >> 2;
  const unsigned short* hb = hnb + (size_t)b * NN * NC;

  // hoisted staging offsets (waves 0-5 only: 2 lines/thread)
  int LA = t * 16;
  int mA = LA / 384, kbA = LA - mA * 384;
  int gA = mA * 384 + (kbA ^ ((mA & 7) << 4));
  int LB = (384 + t) * 16;
  int mB = LB / 384, kbB = LB - mB * 384;
  int gB = mB * 384 + (kbB ^ ((mB & 7) << 4));
  bool stg = (t < 384);
  // hoisted ds_read offsets for this lane's sub-row
  int r_ = sub * 16 + l15;
  int rbase = r_ * 384, sw = (r_ & 7) << 4;
  int dso[6];
#pragma unroll
  for (int ks = 0; ks < 6; ++ks) dso[ks] = rbase + ((ks * 64 + l4 * 16) ^ sw);

  if (j % 5 != 4) {
    // ---- k2a role: 196 blocks/XCD; 64 n x quarter-m top-9 candidates ----
    int idx2a = (j / 5) * 4 + (j % 5);  // 0..195
    int n0 = (idx2a >> 2) * 64;
    int seg = idx2a & 3;
    int mt0 = (98 * seg) / 4, mt1 = (98 * (seg + 1)) / 4;  // 32-row tiles
    const char* hbB = (const char*)hb;

    short8 bfr[6];
    {
      const short8* brow =
          (const short8*)(hb + (size_t)(n0 + wg * 16 + l15) * NC + l4 * 8);
#pragma unroll
      for (int ks = 0; ks < 6; ++ks) bfr[ks] = brow[ks * 4];
    }
    unsigned tk[NK];
#pragma unroll
    for (int r = 0; r < NK; ++r) tk[r] = 0u;

    {
      const char* src = hbB + (size_t)mt0 * 12288;
      if (stg) { gload16(src + gA, abuf[0] + LA); gload16(src + gB, abuf[0] + LB); }
    }
    __syncthreads();  // full drain once (prologue)
    int nt = mt1 - mt0;
    for (int ti = 0; ti < nt; ++ti) {
      int cur = ti & 1;
      if (ti + 1 < nt) {
        const char* src = hbB + (size_t)(mt0 + ti + 1) * 12288;
        char* dl = abuf[cur ^ 1];
        if (stg) { gload16(src + gA, dl + LA); gload16(src + gB, dl + LB); }
        asm volatile("s_waitcnt vmcnt(2)" ::: "memory");
      } else {
        asm volatile("s_waitcnt vmcnt(0)" ::: "memory");
      }
      __builtin_amdgcn_s_barrier();
      __builtin_amdgcn_sched_barrier(0);
      const char* lb = abuf[cur];
      short8 af[6];
#pragma unroll
      for (int ks = 0; ks < 6; ++ks) af[ks] = *(const short8*)&lb[dso[ks]];
      f32x4 acc = {0.f, 0.f, 0.f, 0.f};
#pragma unroll
      for (int ks = 0; ks < 6; ++ks)
        acc = __builtin_amdgcn_mfma_f32_16x16x32_bf16(af[ks], bfr[ks], acc, 0, 0, 0);
      int mknd = 4095 - ((mt0 + ti) * 32 + sub * 16 + l4 * 4);
#pragma unroll
      for (int r = 0; r < 4; ++r) {
        unsigned cur_k = (fsort(acc[r]) & 0xFFFFF000u) | (unsigned)(mknd - r);
#pragma unroll
        for (int q = 0; q < NK; ++q) {
          unsigned hi = tk[q] > cur_k ? tk[q] : cur_k;
          unsigned lo = tk[q] > cur_k ? cur_k : tk[q];
          tk[q] = hi;
          cur_k = lo;
        }
      }
      __builtin_amdgcn_sched_barrier(0);
      __builtin_amdgcn_s_barrier();  // reads of buf[cur] done -> next overwrite safe
    }
    // merge 8 lists per n-row: [64 rows][8 lists][9] = 18KB (aliases abuf)
    unsigned* mkeys = (unsigned*)&abuf[0][0];
    int rw = wg * 16 + l15;
#pragma unroll
    for (int r = 0; r < NK; ++r) mkeys[(rw * 8 + sub * 4 + l4) * NK + r] = tk[r];
    __syncthreads();
    if (t < 256) {  // stage 2: merge list pairs {g, g+4} -> list g
      int row = t >> 2, g = t & 3;
      unsigned* a = &mkeys[(row * 8 + g) * NK];
      const unsigned* c = &mkeys[(row * 8 + g + 4) * NK];
      unsigned best[NK];
#pragma unroll
      for (int r = 0; r < NK; ++r) best[r] = 0u;
#pragma unroll
      for (int s = 0; s < 2 * NK; ++s) {
        unsigned cur_k = s < NK ? a[s] : c[s - NK];
#pragma unroll
        for (int q = 0; q < NK; ++q) {
          unsigned hi = best[q] > cur_k ? best[q] : cur_k;
          unsigned lo = best[q] > cur_k ? cur_k : best[q];
          best[q] = hi;
          cur_k = lo;
        }
      }
#pragma unroll
      for (int r = 0; r < NK; ++r) a[r] = best[r];
    }
    __syncthreads();
    if (t < 64) {  // stage 3: merge lists 0..3 (36 keys)
      const unsigned* src = &mkeys[(t * 8) * NK];
      unsigned best[NK];
#pragma unroll
      for (int r = 0; r < NK; ++r) best[r] = 0u;
      for (int s = 0; s < 36; ++s) {
        unsigned cur_k = src[s];
#pragma unroll
        for (int q = 0; q < NK; ++q) {
          unsigned hi = best[q] > cur_k ? best[q] : cur_k;
          unsigned lo = best[q] > cur_k ? cur_k : best[q];
          best[q] = hi;
          cur_k = lo;
        }
      }
      size_t row = (size_t)b * NN + n0 + t;
#pragma unroll
      for (int r = 0; r < NK; ++r)
        candK[(size_t)(seg * NK + r) * NROW + row] = best[r];
    }
  } else {
    // ---- k3 role: 49 blocks/XCD; P,Q = bf16((hn @ gcwb^T) * norm), 24 chunks ----
    int jj = j / 5;  // 0..48
    int n0 = jj * 64;
    int n = n0 + wg * 16 + l15;
    short8 bfr[6];
    {
      const short8* brow = (const short8*)(hb + (size_t)n * NC + l4 * 8);
#pragma unroll
      for (int ks = 0; ks < 6; ++ks) bfr[ks] = brow[ks * 4];
    }
    float nrm = norm[(size_t)b * NN + n];
    size_t orow = (size_t)b * NN + n;
    const char* wB = (const char*)gcwb;

    if (stg) { gload16(wB + gA, abuf[0] + LA); gload16(wB + gB, abuf[0] + LB); }
    __syncthreads();
    for (int ch = 0; ch < 24; ++ch) {
      int cur = ch & 1;
      if (ch < 23) {
        const char* src = wB + (size_t)(ch + 1) * 12288;
        char* dl = abuf[cur ^ 1];
        if (stg) { gload16(src + gA, dl + LA); gload16(src + gB, dl + LB); }
        asm volatile("s_waitcnt vmcnt(2)" ::: "memory");
      } else {
        asm volatile("s_waitcnt vmcnt(0)" ::: "memory");
      }
      __builtin_amdgcn_s_barrier();
      __builtin_amdgcn_sched_barrier(0);
      const char* lb = abuf[cur];
      f32x4 acc = {0.f, 0.f, 0.f, 0.f};
#pragma unroll
      for (int ks = 0; ks < 6; ++ks) {
        short8 af = *(const short8*)&lb[dso[ks]];
        acc = __builtin_amdgcn_mfma_f32_16x16x32_bf16(af, bfr[ks], acc, 0, 0, 0);
      }
      int o = ch * 32 + sub * 16 + l4 * 4;
      f32x4 st = acc * nrm;
      unsigned short* dst = (o < NCH) ? P : Q;
      int oo = (o < NCH) ? o : o - NCH;
      uint2 u;
      u.x = (unsigned)f2bf(st[0]) | ((unsigned)f2bf(st[1]) << 16);
      u.y = (unsigned)f2bf(st[2]) | ((unsigned)f2bf(st[3]) << 16);
      *(uint2*)&dst[orow * NCH + oo] = u;
      __builtin_amdgcn_sched_barrier(0);
      __builtin_amdgcn_s_barrier();
    }
  }
}

// ---------- K2b: merge 4x9 keys/row -> final top-9 indices ----------
__global__ __launch_bounds__(BDIM) void k2b_merge(const unsigned* __restrict__ candK,
                                                  int* __restrict__ idxo) {
  int row = blockIdx.x * BDIM + threadIdx.x;
  unsigned tk[NK];
#pragma unroll
  for (int r = 0; r < NK; ++r) tk[r] = 0u;
  for (int s = 0; s < 4 * NK; ++s) {
    unsigned cur = candK[(size_t)s * NROW + row];
#pragma unroll
    for (int j = 0; j < NK; ++j) {
      unsigned hi = tk[j] > cur ? tk[j] : cur;
      unsigned lo = tk[j] > cur ? cur : tk[j];
      tk[j] = hi;
      cur = lo;
    }
  }
#pragma unroll
  for (int r = 0; r < NK; ++r)
    idxo[(size_t)row * NK + r] = 4095 - (int)(tk[r] & 4095u);
}

// ---------- K4: batch->XCD-pinned gather-max + BN2 + gelu, bf16 out ----------
__global__ __launch_bounds__(BDIM) void k4_gathermax(
    const unsigned short* __restrict__ P, const unsigned short* __restrict__ Q,
    const int* __restrict__ idx, const float* __restrict__ sc2,
    const float* __restrict__ sh2, unsigned short* __restrict__ mbh) {
  int t = threadIdx.x;
  int lane = t & 63, wv = t >> 6;
  int b = blockIdx.x & 7;                      // batch == XCD (L2 pin for Q slab)
  int n = (int)(blockIdx.x >> 3) * 4 + wv;     // 0..3135
  size_t row = (size_t)b * NN + n;
  const int* ip = idx + row * NK;
  int id[NK];
#pragma unroll
  for (int k = 0; k < NK; ++k) id[k] = ip[k];
  const unsigned short* Qb = Q + (size_t)b * NN * NCH;
  const unsigned short* Pr = P + row * NCH;
  const unsigned short* Qr = Qb + (size_t)n * NCH;
#pragma unroll
  for (int j = 0; j < 3; ++j) {
    int o = j * 128 + lane * 2;
    float mx0 = -1e30f, mx1 = -1e30f;
#pragma unroll
    for (int k = 0; k < NK; ++k) {
      unsigned g = *(const unsigned*)&Qb[(size_t)id[k] * NCH + o];
      mx0 = fmaxf(mx0, bf2f(g & 0xffffu));
      mx1 = fmaxf(mx1, bf2f(g >> 16));
    }
    unsigned pv = *(const unsigned*)&Pr[o];
    unsigned qv = *(const unsigned*)&Qr[o];
    float2 ss = *(const float2*)&sc2[o];
    float2 hh = *(const float2*)&sh2[o];
    float e0 = bf2f(pv & 0xffffu) - bf2f(qv & 0xffffu) + mx0;
    float e1 = bf2f(pv >> 16) - bf2f(qv >> 16) + mx1;
    float y0 = e0 * ss.x + hh.x;
    float y1 = e1 * ss.y + hh.y;
    float ge0 = 0.5f * y0 * (1.f + erff(y0 * 0.70710678118654752f));
    float ge1 = 0.5f * y1 * (1.f + erff(y1 * 0.70710678118654752f));
    *(unsigned*)&mbh[row * NCH + o] =
        (unsigned)f2bf(ge0) | ((unsigned)f2bf(ge1) << 16);
  }
}

// ---------- K5: out = BN3(m @ fc2_w^T) + x via MFMA, direct [c][n] store ----------
__global__ __launch_bounds__(BDIM) void k5_mfma(
    const unsigned short* __restrict__ mbh, const unsigned short* __restrict__ fc2b,
    const float* __restrict__ sc3, const float* __restrict__ sh3,
    const float* __restrict__ x, float* __restrict__ out) {
  __shared__ __align__(16) char abuf[2][24576];
  int t = threadIdx.x;
  int bid = blockIdx.x;
  int b = bid / 147;
  int rem = bid % 147;
  int n0 = (rem / 3) * 64;
  int oc = rem % 3;
  int lane = t & 63, w = t >> 6;
  int l15 = lane & 15, l4 = lane >> 4;
  int n = n0 + w * 16 + l15;
  short8 bfr[12];
  {
    const short8* brow = (const short8*)(mbh + (size_t)(b * NN + n) * NCH + l4 * 8);
#pragma unroll
    for (int kh = 0; kh < 2; ++kh)
#pragma unroll
      for (int ks = 0; ks < 6; ++ks) bfr[kh * 6 + ks] = brow[kh * 24 + ks * 4];
  }
  f32x4 acc[4];
#pragma unroll
  for (int sub = 0; sub < 4; ++sub) acc[sub] = {0.f, 0.f, 0.f, 0.f};

  const char* wt = (const char*)fc2b + (size_t)oc * 2 * 24576;
  stage_tile(wt, abuf[0], t);
  __syncthreads();
  for (int kh = 0; kh < 2; ++kh) {
    if (kh == 0) stage_tile(wt + 24576, abuf[1], t);
#pragma unroll
    for (int sub = 0; sub < 4; ++sub) {
      int r_ = sub * 16 + l15;
      int rbase = r_ * 384, sw = (r_ & 7) << 4;
#pragma unroll
      for (int ks = 0; ks < 6; ++ks) {
        short8 af = *(const short8*)&abuf[kh][rbase + ((ks * 64 + l4 * 16) ^ sw)];
        acc[sub] = __builtin_amdgcn_mfma_f32_16x16x32_bf16(af, bfr[kh * 6 + ks],
                                                           acc[sub], 0, 0, 0);
      }
    }
    __syncthreads();
  }
  const float* xb_ = x + (size_t)b * NC * NN;
  float* ob = out + (size_t)b * NC * NN;
#pragma unroll
  for (int sub = 0; sub < 4; ++sub) {
    int c4 = oc * 64 + sub * 16 + l4 * 4;
    float s_[4], h_[4];
    *(float4*)s_ = *(const float4*)&sc3[c4];
    *(float4*)h_ = *(const float4*)&sh3[c4];
#pragma unroll
    for (int r = 0; r < 4; ++r) {
      size_t off = (size_t)(c4 + r) * NN + n;
      ob[off] = acc[sub][r] * s_[r] + h_[r] + xb_[off];
    }
  }
}

extern "C" void kernel_launch(void* const* d_in, const int* in_sizes, int n_in,
                              void* d_out, int out_size, void* d_ws, size_t ws_size,
                              hipStream_t stream) {
  const float* x = (const float*)d_in[0];
  const float* fc1_w = (const float*)d_in[1];
  const float* fc1_b = (const float*)d_in[2];
  const float* bn1_g = (const float*)d_in[3];
  const float* bn1_b = (const float*)d_in[4];
  const float* bn1_m = (const float*)d_in[5];
  const float* bn1_v = (const float*)d_in[6];
  const float* gc_w = (const float*)d_in[7];
  const float* gc_b = (const float*)d_in[8];
  const float* bn2_g = (const float*)d_in[9];
  const float* bn2_b = (const float*)d_in[10];
  const float* bn2_m = (const float*)d_in[11];
  const float* bn2_v = (const float*)d_in[12];
  const float* fc2_w = (const float*)d_in[13];
  const float* fc2_b = (const float*)d_in[14];
  const float* bn3_g = (const float*)d_in[15];
  const float* bn3_b = (const float*)d_in[16];
  const float* bn3_m = (const float*)d_in[17];
  const float* bn3_v = (const float*)d_in[18];

  size_t nrow = (size_t)NROW;
  size_t npq = (size_t)NB * NN * NCH;
  size_t nhb = (size_t)NB * NN * NC;
  unsigned short* Pb = (unsigned short*)d_ws;
  unsigned short* Qb = Pb + npq;
  unsigned short* mbh = Qb + npq;
  float* norm = (float*)(mbh + npq);
  int* idx = (int*)(norm + nrow);
  unsigned short* hnb = (unsigned short*)(idx + nrow * NK);
  unsigned short* gcwb = hnb + nhb;
  unsigned short* fc1b = gcwb + 768 * NC;
  unsigned short* fc2b = fc1b + NC * NC;
  unsigned* candK = (unsigned*)(fc2b + NC * NCH);
  float* sc1 = (float*)(candK + 4 * NK * nrow);
  float* sh1 = sc1 + NC;
  float* sc2 = sh1 + NC;
  float* sh2 = sc2 + NCH;
  float* sc3 = sh2 + NCH;
  float* sh3 = sc3 + NC;

  k0_convw<<<252, BDIM, 0, stream>>>(gc_w, fc1_w, fc2_w, gcwb, fc1b, fc2b);
  k0b_params<<<1, 384, 0, stream>>>(fc1_b, bn1_g, bn1_b, bn1_m, bn1_v, gc_b,
                                    bn2_g, bn2_b, bn2_m, bn2_v, fc2_b, bn3_g,
                                    bn3_b, bn3_m, bn3_v, sc1, sh1, sc2, sh2,
                                    sc3, sh3);
  k1_mfma<<<NB * 49, BDIM, 0, stream>>>(x, fc1b, sc1, sh1, hnb, norm);
  k23_fused<<<NB * 245, 512, 0, stream>>>(hnb, norm, gcwb, candK, Pb, Qb);
  k2b_merge<<<NROW / BDIM, BDIM, 0, stream>>>(candK, idx);
  k4_gathermax<<<(NB * NN) / 4, BDIM, 0, stream>>>(Pb, Qb, idx, sc2, sh2, mbh);
  k5_mfma<<<NB * 147, BDIM, 0, stream>>>(mbh, fc2b, sc3, sh3, x, (float*)d_out);
}

// Round 15
// 146.926 us; speedup vs baseline: 3.4108x; 1.0588x over previous
//
#include <hip/hip_runtime.h>

#define BDIM 256
#define NB 8
#define NC 192
#define NN 3136         // 56*56 = 49*64
#define NCH 384
#define NK 9
#define NROW (NB * NN)  // 25088

typedef __attribute__((ext_vector_type(8))) short short8;
typedef __attribute__((ext_vector_type(4))) float f32x4;

__device__ __forceinline__ unsigned short f2bf(float f) {
  union { float f; unsigned u; } x{f};
  unsigned r = x.u + 0x7fff + ((x.u >> 16) & 1);  // RNE
  return (unsigned short)(r >> 16);
}

__device__ __forceinline__ float bf2f(unsigned u16) {
  union { unsigned u; float f; } x{u16 << 16};
  return x.f;
}

__device__ __forceinline__ unsigned umax_(unsigned a, unsigned b) { return a > b ? a : b; }
__device__ __forceinline__ unsigned umin_(unsigned a, unsigned b) { return a < b ? a : b; }
#define UMAX3(a, b, c) umax_(umax_((a), (b)), (c))
#define CXD(x, y)                      \
  {                                    \
    unsigned h_ = umax_(x, y);         \
    unsigned l_ = umin_(x, y);         \
    x = h_;                            \
    y = l_;                            \
  }

// key for sim value f (in [-1,1]) and index term it: bits(f+2.0) is positive and
// bitwise-monotone in f; top 20 bits | (4095-m) gives value-then-lowest-index order.
__device__ __forceinline__ unsigned simkey(float f, unsigned it) {
  union { float f; unsigned u; } x{f + 2.0f};
  return (x.u & 0xFFFFF000u) | it;
}

__device__ __forceinline__ void gload16(const char* g, char* l) {
  __builtin_amdgcn_global_load_lds(
      (const __attribute__((address_space(1))) unsigned int*)g,
      (__attribute__((address_space(3))) unsigned int*)l, 16, 0, 0);
}

// stage one 24KB [64 rows][384B] bf16 tile into LDS (async, width 16), 256 thr.
// LDS dest linear; global source pre-XOR-swizzled: LDS[m][kb] = G[m][kb^((m&7)<<4)].
__device__ __forceinline__ void stage_tile(const char* gbase, char* lbuf, int t) {
#pragma unroll
  for (int i = 0; i < 6; ++i) {
    int L = (i * 256 + t) * 16;
    int m = L / 384;
    int kb = L - m * 384;
    gload16(gbase + m * 384 + (kb ^ ((m & 7) << 4)), lbuf + L);
  }
}

// ---------- K0: bf16 weight conversion ----------
__global__ __launch_bounds__(BDIM) void k0_convw(
    const float* __restrict__ gw, const float* __restrict__ f1w,
    const float* __restrict__ f2w, unsigned short* __restrict__ gcwb,
    unsigned short* __restrict__ fc1b, unsigned short* __restrict__ fc2b) {
  int i = (blockIdx.x * BDIM + threadIdx.x) * 4;
  const float* src;
  unsigned short* dst;
  if (i < 147456) {  // gc_w split
    int o = i / NC, k = i - o * NC;
    src = gw + (size_t)(o < NCH ? o : o - NCH) * (2 * NC) + (o < NCH ? 0 : NC) + k;
    dst = gcwb + i;
  } else if (i < 184320) {  // fc1
    int j = i - 147456;
    src = f1w + j;
    dst = fc1b + j;
  } else {  // fc2 retile [(oc*2+kh)][64][192]
    int j = i - 184320;
    int o = j / NCH, k = j - o * NCH;
    int oc = o >> 6, om = o & 63;
    int kh = k / 192, km = k - kh * 192;
    src = f2w + j;
    dst = fc2b + ((size_t)((oc * 2 + kh) * 64 + om)) * 192 + km;
  }
  float4 v = *(const float4*)src;
  uint2 u;
  u.x = (unsigned)f2bf(v.x) | ((unsigned)f2bf(v.y) << 16);
  u.y = (unsigned)f2bf(v.z) | ((unsigned)f2bf(v.w) << 16);
  *(uint2*)dst = u;
}

// ---------- K0b: fold BN params: val = gemm*sc + sh ----------
__global__ __launch_bounds__(384) void k0b_params(
    const float* __restrict__ f1b, const float* __restrict__ g1,
    const float* __restrict__ b1, const float* __restrict__ m1,
    const float* __restrict__ v1, const float* __restrict__ gcb,
    const float* __restrict__ g2, const float* __restrict__ b2,
    const float* __restrict__ m2, const float* __restrict__ v2,
    const float* __restrict__ f2b, const float* __restrict__ g3,
    const float* __restrict__ b3, const float* __restrict__ m3,
    const float* __restrict__ v3, float* __restrict__ sc1,
    float* __restrict__ sh1, float* __restrict__ sc2, float* __restrict__ sh2,
    float* __restrict__ sc3, float* __restrict__ sh3) {
  int c = threadIdx.x;
  if (c < NC) {
    float s1 = g1[c] * rsqrtf(v1[c] + 1e-5f);
    sc1[c] = s1;
    sh1[c] = (f1b[c] - m1[c]) * s1 + b1[c];
    float s3 = g3[c] * rsqrtf(v3[c] + 1e-5f);
    sc3[c] = s3;
    sh3[c] = (f2b[c] - m3[c]) * s3 + b3[c];
  }
  float s2 = g2[c] * rsqrtf(v2[c] + 1e-5f);
  sc2[c] = s2;
  sh2[c] = (gcb[c] - m2[c]) * s2 + b2[c];
}

// ---------- K1: h = BN1(x @ fc1_w^T) via MFMA; x read directly (fused transpose) ----------
__global__ __launch_bounds__(BDIM) void k1_mfma(
    const float* __restrict__ x, const unsigned short* __restrict__ fc1b,
    const float* __restrict__ sc1, const float* __restrict__ sh1,
    unsigned short* __restrict__ hnb, float* __restrict__ normo) {
  __shared__ __align__(16) char abuf[2][24576];
  int t = threadIdx.x;
  int b = blockIdx.x / 49, n0 = (blockIdx.x % 49) * 64;
  int lane = t & 63, w = t >> 6;
  int l15 = lane & 15, l4 = lane >> 4;
  int n = n0 + w * 16 + l15;
  short8 bfr[6];
  {
    const float* xcol = x + (size_t)b * NC * NN + n;
#pragma unroll
    for (int ks = 0; ks < 6; ++ks) {
      union { short8 s; unsigned u[4]; } pk;
#pragma unroll
      for (int j = 0; j < 4; ++j) {
        float v0 = xcol[(size_t)(ks * 32 + l4 * 8 + 2 * j) * NN];
        float v1 = xcol[(size_t)(ks * 32 + l4 * 8 + 2 * j + 1) * NN];
        pk.u[j] = (unsigned)f2bf(v0) | ((unsigned)f2bf(v1) << 16);
      }
      bfr[ks] = pk.s;
    }
  }
  f32x4 acc[3][4];
#pragma unroll
  for (int oc = 0; oc < 3; ++oc)
#pragma unroll
    for (int sub = 0; sub < 4; ++sub) acc[oc][sub] = {0.f, 0.f, 0.f, 0.f};

  const char* wB = (const char*)fc1b;
  stage_tile(wB, abuf[0], t);
  __syncthreads();
  for (int oc = 0; oc < 3; ++oc) {
    int cur = oc & 1;
    if (oc < 2) stage_tile(wB + (size_t)(oc + 1) * 24576, abuf[cur ^ 1], t);
#pragma unroll
    for (int sub = 0; sub < 4; ++sub) {
      int r_ = sub * 16 + l15;
      int rbase = r_ * 384, sw = (r_ & 7) << 4;
#pragma unroll
      for (int ks = 0; ks < 6; ++ks) {
        short8 af = *(const short8*)&abuf[cur][rbase + ((ks * 64 + l4 * 16) ^ sw)];
        acc[oc][sub] = __builtin_amdgcn_mfma_f32_16x16x32_bf16(af, bfr[ks],
                                                               acc[oc][sub], 0, 0, 0);
      }
    }
    __syncthreads();
  }
  float p = 0.f;
#pragma unroll
  for (int oc = 0; oc < 3; ++oc)
#pragma unroll
    for (int sub = 0; sub < 4; ++sub) {
      int c4 = oc * 64 + sub * 16 + l4 * 4;
      float s_[4], h_[4];
      *(float4*)s_ = *(const float4*)&sc1[c4];
      *(float4*)h_ = *(const float4*)&sh1[c4];
#pragma unroll
      for (int r = 0; r < 4; ++r) {
        float v = acc[oc][sub][r] * s_[r] + h_[r];
        acc[oc][sub][r] = v;
        p += v * v;
      }
    }
  p += __shfl_xor(p, 16);
  p += __shfl_xor(p, 32);
  float nr = fmaxf(sqrtf(p), 1e-12f);
  float iv = 1.f / nr;
  if (l4 == 0) normo[(size_t)b * NN + n] = nr;
#pragma unroll
  for (int oc = 0; oc < 3; ++oc)
#pragma unroll
    for (int sub = 0; sub < 4; ++sub) {
      uint2 u;
      u.x = (unsigned)f2bf(acc[oc][sub][0] * iv) |
            ((unsigned)f2bf(acc[oc][sub][1] * iv) << 16);
      u.y = (unsigned)f2bf(acc[oc][sub][2] * iv) |
            ((unsigned)f2bf(acc[oc][sub][3] * iv) << 16);
      *(uint2*)&hnb[(size_t)(b * NN + n) * NC + oc * 64 + sub * 16 + l4 * 4] = u;
    }
}

// ---------- K23: fused 512-thr dispatch, counted-vmcnt double buffering ----------
// k2a select: sort4 + exact (9,4) selection-merge (max3/min network), cheap keys.
__global__ __launch_bounds__(512) void k23_fused(
    const unsigned short* __restrict__ hnb, const float* __restrict__ norm,
    const unsigned short* __restrict__ gcwb, unsigned* __restrict__ candK,
    unsigned short* __restrict__ P, unsigned short* __restrict__ Q) {
  __shared__ __align__(16) char abuf[2][12288];
  int t = threadIdx.x;
  int bid = blockIdx.x;
  int b = bid & 7;          // batch == XCD
  int j = bid >> 3;         // 0..244 per XCD
  int lane = t & 63, w = t >> 6;
  int l15 = lane & 15, l4 = lane >> 4;
  int wg = w & 3, sub = w >> 2;
  const unsigned short* hb = hnb + (size_t)b * NN * NC;

  // hoisted staging offsets (waves 0-5 only: 2 lines/thread)
  int LA = t * 16;
  int mA = LA / 384, kbA = LA - mA * 384;
  int gA = mA * 384 + (kbA ^ ((mA & 7) << 4));
  int LB = (384 + t) * 16;
  int mB = LB / 384, kbB = LB - mB * 384;
  int gB = mB * 384 + (kbB ^ ((mB & 7) << 4));
  bool stg = (t < 384);
  // hoisted ds_read offsets for this lane's sub-row
  int r_ = sub * 16 + l15;
  int rbase = r_ * 384, sw = (r_ & 7) << 4;
  int dso[6];
#pragma unroll
  for (int ks = 0; ks < 6; ++ks) dso[ks] = rbase + ((ks * 64 + l4 * 16) ^ sw);

  if (j % 5 != 4) {
    // ---- k2a role: 196 blocks/XCD; 64 n x quarter-m top-9 candidates ----
    int idx2a = (j / 5) * 4 + (j % 5);  // 0..195
    int n0 = (idx2a >> 2) * 64;
    int seg = idx2a & 3;
    int mt0 = (98 * seg) / 4, mt1 = (98 * (seg + 1)) / 4;  // 32-row tiles
    const char* hbB = (const char*)hb;

    short8 bfr[6];
    {
      const short8* brow =
          (const short8*)(hb + (size_t)(n0 + wg * 16 + l15) * NC + l4 * 8);
#pragma unroll
      for (int ks = 0; ks < 6; ++ks) bfr[ks] = brow[ks * 4];
    }
    unsigned tk[NK];
#pragma unroll
    for (int r = 0; r < NK; ++r) tk[r] = 0u;

    {
      const char* src = hbB + (size_t)mt0 * 12288;
      if (stg) { gload16(src + gA, abuf[0] + LA); gload16(src + gB, abuf[0] + LB); }
    }
    __syncthreads();  // full drain once (prologue)
    int nt = mt1 - mt0;
    for (int ti = 0; ti < nt; ++ti) {
      int cur = ti & 1;
      if (ti + 1 < nt) {
        const char* src = hbB + (size_t)(mt0 + ti + 1) * 12288;
        char* dl = abuf[cur ^ 1];
        if (stg) { gload16(src + gA, dl + LA); gload16(src + gB, dl + LB); }
        asm volatile("s_waitcnt vmcnt(2)" ::: "memory");
      } else {
        asm volatile("s_waitcnt vmcnt(0)" ::: "memory");
      }
      __builtin_amdgcn_s_barrier();
      __builtin_amdgcn_sched_barrier(0);
      const char* lb = abuf[cur];
      short8 af[6];
#pragma unroll
      for (int ks = 0; ks < 6; ++ks) af[ks] = *(const short8*)&lb[dso[ks]];
      f32x4 acc = {0.f, 0.f, 0.f, 0.f};
#pragma unroll
      for (int ks = 0; ks < 6; ++ks)
        acc = __builtin_amdgcn_mfma_f32_16x16x32_bf16(af[ks], bfr[ks], acc, 0, 0, 0);
      unsigned mknd = (unsigned)(4095 - ((mt0 + ti) * 32 + sub * 16 + l4 * 4));
      // 4 keys (lower m -> larger index term; strictly unique keys)
      unsigned c0 = simkey(acc[0], mknd);
      unsigned c1 = simkey(acc[1], mknd - 1);
      unsigned c2 = simkey(acc[2], mknd - 2);
      unsigned c3 = simkey(acc[3], mknd - 3);
      // sort4 descending (5 comparators)
      CXD(c0, c1); CXD(c2, c3); CXD(c0, c2); CXD(c1, c3); CXD(c1, c2);
      // exact (9,4) selection-merge, computed descending (no temps needed:
      // step j reads tk[j-4..j], writes tk[j]; later steps read only lower idx)
      tk[8] = UMAX3(UMAX3(tk[8], umin_(tk[7], c0), umin_(tk[6], c1)),
                    umin_(tk[5], c2), umin_(tk[4], c3));
      tk[7] = UMAX3(UMAX3(tk[7], umin_(tk[6], c0), umin_(tk[5], c1)),
                    umin_(tk[4], c2), umin_(tk[3], c3));
      tk[6] = UMAX3(UMAX3(tk[6], umin_(tk[5], c0), umin_(tk[4], c1)),
                    umin_(tk[3], c2), umin_(tk[2], c3));
      tk[5] = UMAX3(UMAX3(tk[5], umin_(tk[4], c0), umin_(tk[3], c1)),
                    umin_(tk[2], c2), umin_(tk[1], c3));
      tk[4] = UMAX3(UMAX3(tk[4], umin_(tk[3], c0), umin_(tk[2], c1)),
                    umin_(tk[1], c2), umin_(tk[0], c3));
      tk[3] = UMAX3(UMAX3(tk[3], c3, umin_(tk[2], c0)),
                    umin_(tk[1], c1), umin_(tk[0], c2));
      tk[2] = umax_(UMAX3(tk[2], c2, umin_(tk[1], c0)), umin_(tk[0], c1));
      tk[1] = UMAX3(tk[1], c1, umin_(tk[0], c0));
      tk[0] = umax_(tk[0], c0);
      __builtin_amdgcn_sched_barrier(0);
      __builtin_amdgcn_s_barrier();  // reads of buf[cur] done -> next overwrite safe
    }
    // merge 8 lists per n-row: [64 rows][8 lists][9] = 18KB (aliases abuf)
    unsigned* mkeys = (unsigned*)&abuf[0][0];
    int rw = wg * 16 + l15;
#pragma unroll
    for (int r = 0; r < NK; ++r) mkeys[(rw * 8 + sub * 4 + l4) * NK + r] = tk[r];
    __syncthreads();
    if (t < 256) {  // stage 2: merge list pairs {g, g+4} -> list g
      int row = t >> 2, g = t & 3;
      unsigned* a = &mkeys[(row * 8 + g) * NK];
      const unsigned* c = &mkeys[(row * 8 + g + 4) * NK];
      unsigned best[NK];
#pragma unroll
      for (int r = 0; r < NK; ++r) best[r] = 0u;
#pragma unroll
      for (int s = 0; s < 2 * NK; ++s) {
        unsigned cur_k = s < NK ? a[s] : c[s - NK];
#pragma unroll
        for (int q = 0; q < NK; ++q) {
          unsigned hi = best[q] > cur_k ? best[q] : cur_k;
          unsigned lo = best[q] > cur_k ? cur_k : best[q];
          best[q] = hi;
          cur_k = lo;
        }
      }
#pragma unroll
      for (int r = 0; r < NK; ++r) a[r] = best[r];
    }
    __syncthreads();
    if (t < 64) {  // stage 3: merge lists 0..3 (36 keys)
      const unsigned* src = &mkeys[(t * 8) * NK];
      unsigned best[NK];
#pragma unroll
      for (int r = 0; r < NK; ++r) best[r] = 0u;
      for (int s = 0; s < 36; ++s) {
        unsigned cur_k = src[s];
#pragma unroll
        for (int q = 0; q < NK; ++q) {
          unsigned hi = best[q] > cur_k ? best[q] : cur_k;
          unsigned lo = best[q] > cur_k ? cur_k : best[q];
          best[q] = hi;
          cur_k = lo;
        }
      }
      size_t row = (size_t)b * NN + n0 + t;
#pragma unroll
      for (int r = 0; r < NK; ++r)
        candK[(size_t)(seg * NK + r) * NROW + row] = best[r];
    }
  } else {
    // ---- k3 role: 49 blocks/XCD; P,Q = bf16((hn @ gcwb^T) * norm), 24 chunks ----
    int jj = j / 5;  // 0..48
    int n0 = jj * 64;
    int n = n0 + wg * 16 + l15;
    short8 bfr[6];
    {
      const short8* brow = (const short8*)(hb + (size_t)n * NC + l4 * 8);
#pragma unroll
      for (int ks = 0; ks < 6; ++ks) bfr[ks] = brow[ks * 4];
    }
    float nrm = norm[(size_t)b * NN + n];
    size_t orow = (size_t)b * NN + n;
    const char* wB = (const char*)gcwb;

    if (stg) { gload16(wB + gA, abuf[0] + LA); gload16(wB + gB, abuf[0] + LB); }
    __syncthreads();
    for (int ch = 0; ch < 24; ++ch) {
      int cur = ch & 1;
      if (ch < 23) {
        const char* src = wB + (size_t)(ch + 1) * 12288;
        char* dl = abuf[cur ^ 1];
        if (stg) { gload16(src + gA, dl + LA); gload16(src + gB, dl + LB); }
        asm volatile("s_waitcnt vmcnt(2)" ::: "memory");
      } else {
        asm volatile("s_waitcnt vmcnt(0)" ::: "memory");
      }
      __builtin_amdgcn_s_barrier();
      __builtin_amdgcn_sched_barrier(0);
      const char* lb = abuf[cur];
      f32x4 acc = {0.f, 0.f, 0.f, 0.f};
#pragma unroll
      for (int ks = 0; ks < 6; ++ks) {
        short8 af = *(const short8*)&lb[dso[ks]];
        acc = __builtin_amdgcn_mfma_f32_16x16x32_bf16(af, bfr[ks], acc, 0, 0, 0);
      }
      int o = ch * 32 + sub * 16 + l4 * 4;
      f32x4 st = acc * nrm;
      unsigned short* dst = (o < NCH) ? P : Q;
      int oo = (o < NCH) ? o : o - NCH;
      uint2 u;
      u.x = (unsigned)f2bf(st[0]) | ((unsigned)f2bf(st[1]) << 16);
      u.y = (unsigned)f2bf(st[2]) | ((unsigned)f2bf(st[3]) << 16);
      *(uint2*)&dst[orow * NCH + oo] = u;
      __builtin_amdgcn_sched_barrier(0);
      __builtin_amdgcn_s_barrier();
    }
  }
}

// ---------- K2b: merge 4x9 keys/row -> final top-9 indices ----------
__global__ __launch_bounds__(BDIM) void k2b_merge(const unsigned* __restrict__ candK,
                                                  int* __restrict__ idxo) {
  int row = blockIdx.x * BDIM + threadIdx.x;
  unsigned tk[NK];
#pragma unroll
  for (int r = 0; r < NK; ++r) tk[r] = 0u;
  for (int s = 0; s < 4 * NK; ++s) {
    unsigned cur = candK[(size_t)s * NROW + row];
#pragma unroll
    for (int j = 0; j < NK; ++j) {
      unsigned hi = tk[j] > cur ? tk[j] : cur;
      unsigned lo = tk[j] > cur ? cur : tk[j];
      tk[j] = hi;
      cur = lo;
    }
  }
#pragma unroll
  for (int r = 0; r < NK; ++r)
    idxo[(size_t)row * NK + r] = 4095 - (int)(tk[r] & 4095u);
}

// ---------- K4: batch->XCD-pinned gather-max + BN2 + gelu, bf16 out ----------
__global__ __launch_bounds__(BDIM) void k4_gathermax(
    const unsigned short* __restrict__ P, const unsigned short* __restrict__ Q,
    const int* __restrict__ idx, const float* __restrict__ sc2,
    const float* __restrict__ sh2, unsigned short* __restrict__ mbh) {
  int t = threadIdx.x;
  int lane = t & 63, wv = t >> 6;
  int b = blockIdx.x & 7;                      // batch == XCD (L2 pin for Q slab)
  int n = (int)(blockIdx.x >> 3) * 4 + wv;     // 0..3135
  size_t row = (size_t)b * NN + n;
  const int* ip = idx + row * NK;
  int id[NK];
#pragma unroll
  for (int k = 0; k < NK; ++k) id[k] = ip[k];
  const unsigned short* Qb = Q + (size_t)b * NN * NCH;
  const unsigned short* Pr = P + row * NCH;
  const unsigned short* Qr = Qb + (size_t)n * NCH;
#pragma unroll
  for (int j = 0; j < 3; ++j) {
    int o = j * 128 + lane * 2;
    float mx0 = -1e30f, mx1 = -1e30f;
#pragma unroll
    for (int k = 0; k < NK; ++k) {
      unsigned g = *(const unsigned*)&Qb[(size_t)id[k] * NCH + o];
      mx0 = fmaxf(mx0, bf2f(g & 0xffffu));
      mx1 = fmaxf(mx1, bf2f(g >> 16));
    }
    unsigned pv = *(const unsigned*)&Pr[o];
    unsigned qv = *(const unsigned*)&Qr[o];
    float2 ss = *(const float2*)&sc2[o];
    float2 hh = *(const float2*)&sh2[o];
    float e0 = bf2f(pv & 0xffffu) - bf2f(qv & 0xffffu) + mx0;
    float e1 = bf2f(pv >> 16) - bf2f(qv >> 16) + mx1;
    float y0 = e0 * ss.x + hh.x;
    float y1 = e1 * ss.y + hh.y;
    float ge0 = 0.5f * y0 * (1.f + erff(y0 * 0.70710678118654752f));
    float ge1 = 0.5f * y1 * (1.f + erff(y1 * 0.70710678118654752f));
    *(unsigned*)&mbh[row * NCH + o] =
        (unsigned)f2bf(ge0) | ((unsigned)f2bf(ge1) << 16);
  }
}

// ---------- K5: out = BN3(m @ fc2_w^T) + x via MFMA, direct [c][n] store ----------
__global__ __launch_bounds__(BDIM) void k5_mfma(
    const unsigned short* __restrict__ mbh, const unsigned short* __restrict__ fc2b,
    const float* __restrict__ sc3, const float* __restrict__ sh3,
    const float* __restrict__ x, float* __restrict__ out) {
  __shared__ __align__(16) char abuf[2][24576];
  int t = threadIdx.x;
  int bid = blockIdx.x;
  int b = bid / 147;
  int rem = bid % 147;
  int n0 = (rem / 3) * 64;
  int oc = rem % 3;
  int lane = t & 63, w = t >> 6;
  int l15 = lane & 15, l4 = lane >> 4;
  int n = n0 + w * 16 + l15;
  short8 bfr[12];
  {
    const short8* brow = (const short8*)(mbh + (size_t)(b * NN + n) * NCH + l4 * 8);
#pragma unroll
    for (int kh = 0; kh < 2; ++kh)
#pragma unroll
      for (int ks = 0; ks < 6; ++ks) bfr[kh * 6 + ks] = brow[kh * 24 + ks * 4];
  }
  f32x4 acc[4];
#pragma unroll
  for (int sub = 0; sub < 4; ++sub) acc[sub] = {0.f, 0.f, 0.f, 0.f};

  const char* wt = (const char*)fc2b + (size_t)oc * 2 * 24576;
  stage_tile(wt, abuf[0], t);
  __syncthreads();
  for (int kh = 0; kh < 2; ++kh) {
    if (kh == 0) stage_tile(wt + 24576, abuf[1], t);
#pragma unroll
    for (int sub = 0; sub < 4; ++sub) {
      int r_ = sub * 16 + l15;
      int rbase = r_ * 384, sw = (r_ & 7) << 4;
#pragma unroll
      for (int ks = 0; ks < 6; ++ks) {
        short8 af = *(const short8*)&abuf[kh][rbase + ((ks * 64 + l4 * 16) ^ sw)];
        acc[sub] = __builtin_amdgcn_mfma_f32_16x16x32_bf16(af, bfr[kh * 6 + ks],
                                                           acc[sub], 0, 0, 0);
      }
    }
    __syncthreads();
  }
  const float* xb_ = x + (size_t)b * NC * NN;
  float* ob = out + (size_t)b * NC * NN;
#pragma unroll
  for (int sub = 0; sub < 4; ++sub) {
    int c4 = oc * 64 + sub * 16 + l4 * 4;
    float s_[4], h_[4];
    *(float4*)s_ = *(const float4*)&sc3[c4];
    *(float4*)h_ = *(const float4*)&sh3[c4];
#pragma unroll
    for (int r = 0; r < 4; ++r) {
      size_t off = (size_t)(c4 + r) * NN + n;
      ob[off] = acc[sub][r] * s_[r] + h_[r] + xb_[off];
    }
  }
}

extern "C" void kernel_launch(void* const* d_in, const int* in_sizes, int n_in,
                              void* d_out, int out_size, void* d_ws, size_t ws_size,
                              hipStream_t stream) {
  const float* x = (const float*)d_in[0];
  const float* fc1_w = (const float*)d_in[1];
  const float* fc1_b = (const float*)d_in[2];
  const float* bn1_g = (const float*)d_in[3];
  const float* bn1_b = (const float*)d_in[4];
  const float* bn1_m = (const float*)d_in[5];
  const float* bn1_v = (const float*)d_in[6];
  const float* gc_w = (const float*)d_in[7];
  const float* gc_b = (const float*)d_in[8];
  const float* bn2_g = (const float*)d_in[9];
  const float* bn2_b = (const float*)d_in[10];
  const float* bn2_m = (const float*)d_in[11];
  const float* bn2_v = (const float*)d_in[12];
  const float* fc2_w = (const float*)d_in[13];
  const float* fc2_b = (const float*)d_in[14];
  const float* bn3_g = (const float*)d_in[15];
  const float* bn3_b = (const float*)d_in[16];
  const float* bn3_m = (const float*)d_in[17];
  const float* bn3_v = (const float*)d_in[18];

  size_t nrow = (size_t)NROW;
  size_t npq = (size_t)NB * NN * NCH;
  size_t nhb = (size_t)NB * NN * NC;
  unsigned short* Pb = (unsigned short*)d_ws;
  unsigned short* Qb = Pb + npq;
  unsigned short* mbh = Qb + npq;
  float* norm = (float*)(mbh + npq);
  int* idx = (int*)(norm + nrow);
  unsigned short* hnb = (unsigned short*)(idx + nrow * NK);
  unsigned short* gcwb = hnb + nhb;
  unsigned short* fc1b = gcwb + 768 * NC;
  unsigned short* fc2b = fc1b + NC * NC;
  unsigned* candK = (unsigned*)(fc2b + NC * NCH);
  float* sc1 = (float*)(candK + 4 * NK * nrow);
  float* sh1 = sc1 + NC;
  float* sc2 = sh1 + NC;
  float* sh2 = sc2 + NCH;
  float* sc3 = sh2 + NCH;
  float* sh3 = sc3 + NC;

  k0_convw<<<252, BDIM, 0, stream>>>(gc_w, fc1_w, fc2_w, gcwb, fc1b, fc2b);
  k0b_params<<<1, 384, 0, stream>>>(fc1_b, bn1_g, bn1_b, bn1_m, bn1_v, gc_b,
                                    bn2_g, bn2_b, bn2_m, bn2_v, fc2_b, bn3_g,
                                    bn3_b, bn3_m, bn3_v, sc1, sh1, sc2, sh2,
                                    sc3, sh3);
  k1_mfma<<<NB * 49, BDIM, 0, stream>>>(x, fc1b, sc1, sh1, hnb, norm);
  k23_fused<<<NB * 245, 512, 0, stream>>>(hnb, norm, gcwb, candK, Pb, Qb);
  k2b_merge<<<NROW / BDIM, BDIM, 0, stream>>>(candK, idx);
  k4_gathermax<<<(NB * NN) / 4, BDIM, 0, stream>>>(Pb, Qb, idx, sc2, sh2, mbh);
  k5_mfma<<<NB * 147, BDIM, 0, stream>>>(mbh, fc2b, sc3, sh3, x, (float*)d_out);
}

// Round 16
// 144.645 us; speedup vs baseline: 3.4646x; 1.0158x over previous
//
#include <hip/hip_runtime.h>

#define BDIM 256
#define NB 8
#define NC 192
#define NN 3136         // 56*56 = 49*64
#define NCH 384
#define NK 9
#define NROW (NB * NN)  // 25088

typedef __attribute__((ext_vector_type(8))) short short8;
typedef __attribute__((ext_vector_type(4))) float f32x4;

__device__ __forceinline__ unsigned short f2bf(float f) {
  union { float f; unsigned u; } x{f};
  unsigned r = x.u + 0x7fff + ((x.u >> 16) & 1);  // RNE
  return (unsigned short)(r >> 16);
}

__device__ __forceinline__ float bf2f(unsigned u16) {
  union { unsigned u; float f; } x{u16 << 16};
  return x.f;
}

__device__ __forceinline__ unsigned umax_(unsigned a, unsigned b) { return a > b ? a : b; }
__device__ __forceinline__ unsigned umin_(unsigned a, unsigned b) { return a < b ? a : b; }
#define UMAX3(a, b, c) umax_(umax_((a), (b)), (c))
#define CXD(x, y)                      \
  {                                    \
    unsigned h_ = umax_(x, y);         \
    unsigned l_ = umin_(x, y);         \
    x = h_;                            \
    y = l_;                            \
  }

// key for sim value f (in [-1,1]) and index term it: bits(f+2.0) is positive and
// bitwise-monotone in f; top 20 bits | (4095-m) gives value-then-lowest-index order.
__device__ __forceinline__ unsigned simkey(float f, unsigned it) {
  union { float f; unsigned u; } x{f + 2.0f};
  return (x.u & 0xFFFFF000u) | it;
}

__device__ __forceinline__ void gload16(const char* g, char* l) {
  __builtin_amdgcn_global_load_lds(
      (const __attribute__((address_space(1))) unsigned int*)g,
      (__attribute__((address_space(3))) unsigned int*)l, 16, 0, 0);
}

// stage one 24KB [64 rows][384B] bf16 tile into LDS (async, width 16), 256 thr.
// LDS dest linear; global source pre-XOR-swizzled: LDS[m][kb] = G[m][kb^((m&7)<<4)].
__device__ __forceinline__ void stage_tile(const char* gbase, char* lbuf, int t) {
#pragma unroll
  for (int i = 0; i < 6; ++i) {
    int L = (i * 256 + t) * 16;
    int m = L / 384;
    int kb = L - m * 384;
    gload16(gbase + m * 384 + (kb ^ ((m & 7) << 4)), lbuf + L);
  }
}

// ---------- K0: bf16 weight conversion ----------
__global__ __launch_bounds__(BDIM) void k0_convw(
    const float* __restrict__ gw, const float* __restrict__ f1w,
    const float* __restrict__ f2w, unsigned short* __restrict__ gcwb,
    unsigned short* __restrict__ fc1b, unsigned short* __restrict__ fc2b) {
  int i = (blockIdx.x * BDIM + threadIdx.x) * 4;
  const float* src;
  unsigned short* dst;
  if (i < 147456) {  // gc_w split
    int o = i / NC, k = i - o * NC;
    src = gw + (size_t)(o < NCH ? o : o - NCH) * (2 * NC) + (o < NCH ? 0 : NC) + k;
    dst = gcwb + i;
  } else if (i < 184320) {  // fc1
    int j = i - 147456;
    src = f1w + j;
    dst = fc1b + j;
  } else {  // fc2 retile [(oc*2+kh)][64][192]
    int j = i - 184320;
    int o = j / NCH, k = j - o * NCH;
    int oc = o >> 6, om = o & 63;
    int kh = k / 192, km = k - kh * 192;
    src = f2w + j;
    dst = fc2b + ((size_t)((oc * 2 + kh) * 64 + om)) * 192 + km;
  }
  float4 v = *(const float4*)src;
  uint2 u;
  u.x = (unsigned)f2bf(v.x) | ((unsigned)f2bf(v.y) << 16);
  u.y = (unsigned)f2bf(v.z) | ((unsigned)f2bf(v.w) << 16);
  *(uint2*)dst = u;
}

// ---------- K0b: fold BN params: val = gemm*sc + sh ----------
__global__ __launch_bounds__(384) void k0b_params(
    const float* __restrict__ f1b, const float* __restrict__ g1,
    const float* __restrict__ b1, const float* __restrict__ m1,
    const float* __restrict__ v1, const float* __restrict__ gcb,
    const float* __restrict__ g2, const float* __restrict__ b2,
    const float* __restrict__ m2, const float* __restrict__ v2,
    const float* __restrict__ f2b, const float* __restrict__ g3,
    const float* __restrict__ b3, const float* __restrict__ m3,
    const float* __restrict__ v3, float* __restrict__ sc1,
    float* __restrict__ sh1, float* __restrict__ sc2, float* __restrict__ sh2,
    float* __restrict__ sc3, float* __restrict__ sh3) {
  int c = threadIdx.x;
  if (c < NC) {
    float s1 = g1[c] * rsqrtf(v1[c] + 1e-5f);
    sc1[c] = s1;
    sh1[c] = (f1b[c] - m1[c]) * s1 + b1[c];
    float s3 = g3[c] * rsqrtf(v3[c] + 1e-5f);
    sc3[c] = s3;
    sh3[c] = (f2b[c] - m3[c]) * s3 + b3[c];
  }
  float s2 = g2[c] * rsqrtf(v2[c] + 1e-5f);
  sc2[c] = s2;
  sh2[c] = (gcb[c] - m2[c]) * s2 + b2[c];
}

// ---------- K1: h = BN1(x @ fc1_w^T) via MFMA; x read directly (fused transpose) ----------
__global__ __launch_bounds__(BDIM) void k1_mfma(
    const float* __restrict__ x, const unsigned short* __restrict__ fc1b,
    const float* __restrict__ sc1, const float* __restrict__ sh1,
    unsigned short* __restrict__ hnb, float* __restrict__ normo) {
  __shared__ __align__(16) char abuf[2][24576];
  int t = threadIdx.x;
  int b = blockIdx.x / 49, n0 = (blockIdx.x % 49) * 64;
  int lane = t & 63, w = t >> 6;
  int l15 = lane & 15, l4 = lane >> 4;
  int n = n0 + w * 16 + l15;
  short8 bfr[6];
  {
    const float* xcol = x + (size_t)b * NC * NN + n;
#pragma unroll
    for (int ks = 0; ks < 6; ++ks) {
      union { short8 s; unsigned u[4]; } pk;
#pragma unroll
      for (int j = 0; j < 4; ++j) {
        float v0 = xcol[(size_t)(ks * 32 + l4 * 8 + 2 * j) * NN];
        float v1 = xcol[(size_t)(ks * 32 + l4 * 8 + 2 * j + 1) * NN];
        pk.u[j] = (unsigned)f2bf(v0) | ((unsigned)f2bf(v1) << 16);
      }
      bfr[ks] = pk.s;
    }
  }
  f32x4 acc[3][4];
#pragma unroll
  for (int oc = 0; oc < 3; ++oc)
#pragma unroll
    for (int sub = 0; sub < 4; ++sub) acc[oc][sub] = {0.f, 0.f, 0.f, 0.f};

  const char* wB = (const char*)fc1b;
  stage_tile(wB, abuf[0], t);
  __syncthreads();
  for (int oc = 0; oc < 3; ++oc) {
    int cur = oc & 1;
    if (oc < 2) stage_tile(wB + (size_t)(oc + 1) * 24576, abuf[cur ^ 1], t);
#pragma unroll
    for (int sub = 0; sub < 4; ++sub) {
      int r_ = sub * 16 + l15;
      int rbase = r_ * 384, sw = (r_ & 7) << 4;
#pragma unroll
      for (int ks = 0; ks < 6; ++ks) {
        short8 af = *(const short8*)&abuf[cur][rbase + ((ks * 64 + l4 * 16) ^ sw)];
        acc[oc][sub] = __builtin_amdgcn_mfma_f32_16x16x32_bf16(af, bfr[ks],
                                                               acc[oc][sub], 0, 0, 0);
      }
    }
    __syncthreads();
  }
  float p = 0.f;
#pragma unroll
  for (int oc = 0; oc < 3; ++oc)
#pragma unroll
    for (int sub = 0; sub < 4; ++sub) {
      int c4 = oc * 64 + sub * 16 + l4 * 4;
      float s_[4], h_[4];
      *(float4*)s_ = *(const float4*)&sc1[c4];
      *(float4*)h_ = *(const float4*)&sh1[c4];
#pragma unroll
      for (int r = 0; r < 4; ++r) {
        float v = acc[oc][sub][r] * s_[r] + h_[r];
        acc[oc][sub][r] = v;
        p += v * v;
      }
    }
  p += __shfl_xor(p, 16);
  p += __shfl_xor(p, 32);
  float nr = fmaxf(sqrtf(p), 1e-12f);
  float iv = 1.f / nr;
  if (l4 == 0) normo[(size_t)b * NN + n] = nr;
#pragma unroll
  for (int oc = 0; oc < 3; ++oc)
#pragma unroll
    for (int sub = 0; sub < 4; ++sub) {
      uint2 u;
      u.x = (unsigned)f2bf(acc[oc][sub][0] * iv) |
            ((unsigned)f2bf(acc[oc][sub][1] * iv) << 16);
      u.y = (unsigned)f2bf(acc[oc][sub][2] * iv) |
            ((unsigned)f2bf(acc[oc][sub][3] * iv) << 16);
      *(uint2*)&hnb[(size_t)(b * NN + n) * NC + oc * 64 + sub * 16 + l4 * 4] = u;
    }
}

// ---------- K23: fused 512-thr dispatch; TRIPLE buffer, ONE barrier per tile ----------
// stage(t+1)->buf[(t+1)%3] writes the buffer read at iter t-2; barrier chain makes
// the trailing barrier redundant. vmcnt(2) k2a / vmcnt(3) k3 (1 store in flight).
__global__ __launch_bounds__(512) void k23_fused(
    const unsigned short* __restrict__ hnb, const float* __restrict__ norm,
    const unsigned short* __restrict__ gcwb, unsigned* __restrict__ candK,
    unsigned short* __restrict__ P, unsigned short* __restrict__ Q) {
  __shared__ __align__(16) char abuf[3][12288];
  int t = threadIdx.x;
  int bid = blockIdx.x;
  int b = bid & 7;          // batch == XCD
  int j = bid >> 3;         // 0..244 per XCD
  int lane = t & 63, w = t >> 6;
  int l15 = lane & 15, l4 = lane >> 4;
  int wg = w & 3, sub = w >> 2;
  const unsigned short* hb = hnb + (size_t)b * NN * NC;

  // hoisted staging offsets (waves 0-5 only: 2 lines/thread)
  int LA = t * 16;
  int mA = LA / 384, kbA = LA - mA * 384;
  int gA = mA * 384 + (kbA ^ ((mA & 7) << 4));
  int LB = (384 + t) * 16;
  int mB = LB / 384, kbB = LB - mB * 384;
  int gB = mB * 384 + (kbB ^ ((mB & 7) << 4));
  bool stg = (t < 384);
  // hoisted ds_read offsets for this lane's sub-row
  int r_ = sub * 16 + l15;
  int rbase = r_ * 384, sw = (r_ & 7) << 4;
  int dso[6];
#pragma unroll
  for (int ks = 0; ks < 6; ++ks) dso[ks] = rbase + ((ks * 64 + l4 * 16) ^ sw);

  if (j % 5 != 4) {
    // ---- k2a role: 196 blocks/XCD; 64 n x quarter-m top-9 candidates ----
    int idx2a = (j / 5) * 4 + (j % 5);  // 0..195
    int n0 = (idx2a >> 2) * 64;
    int seg = idx2a & 3;
    int mt0 = (98 * seg) / 4, mt1 = (98 * (seg + 1)) / 4;  // 32-row tiles
    const char* hbB = (const char*)hb;

    short8 bfr[6];
    {
      const short8* brow =
          (const short8*)(hb + (size_t)(n0 + wg * 16 + l15) * NC + l4 * 8);
#pragma unroll
      for (int ks = 0; ks < 6; ++ks) bfr[ks] = brow[ks * 4];
    }
    unsigned tk[NK];
#pragma unroll
    for (int r = 0; r < NK; ++r) tk[r] = 0u;

    {
      const char* src = hbB + (size_t)mt0 * 12288;
      if (stg) { gload16(src + gA, abuf[0] + LA); gload16(src + gB, abuf[0] + LB); }
    }
    int nt = mt1 - mt0;
    int cur = 0;
    for (int ti = 0; ti < nt; ++ti) {
      int nxt = cur + 1 == 3 ? 0 : cur + 1;
      if (ti + 1 < nt) {
        const char* src = hbB + (size_t)(mt0 + ti + 1) * 12288;
        char* dl = &abuf[nxt][0];
        if (stg) { gload16(src + gA, dl + LA); gload16(src + gB, dl + LB); }
        asm volatile("s_waitcnt vmcnt(2)" ::: "memory");
      } else {
        asm volatile("s_waitcnt vmcnt(0)" ::: "memory");
      }
      __builtin_amdgcn_s_barrier();
      __builtin_amdgcn_sched_barrier(0);
      const char* lb = &abuf[cur][0];
      short8 af[6];
#pragma unroll
      for (int ks = 0; ks < 6; ++ks) af[ks] = *(const short8*)&lb[dso[ks]];
      f32x4 acc = {0.f, 0.f, 0.f, 0.f};
#pragma unroll
      for (int ks = 0; ks < 6; ++ks)
        acc = __builtin_amdgcn_mfma_f32_16x16x32_bf16(af[ks], bfr[ks], acc, 0, 0, 0);
      unsigned mknd = (unsigned)(4095 - ((mt0 + ti) * 32 + sub * 16 + l4 * 4));
      unsigned c0 = simkey(acc[0], mknd);
      unsigned c1 = simkey(acc[1], mknd - 1);
      unsigned c2 = simkey(acc[2], mknd - 2);
      unsigned c3 = simkey(acc[3], mknd - 3);
      // sort4 descending (5 comparators)
      CXD(c0, c1); CXD(c2, c3); CXD(c0, c2); CXD(c1, c3); CXD(c1, c2);
      // exact (9,4) selection-merge, descending (step j reads only lower indices)
      tk[8] = UMAX3(UMAX3(tk[8], umin_(tk[7], c0), umin_(tk[6], c1)),
                    umin_(tk[5], c2), umin_(tk[4], c3));
      tk[7] = UMAX3(UMAX3(tk[7], umin_(tk[6], c0), umin_(tk[5], c1)),
                    umin_(tk[4], c2), umin_(tk[3], c3));
      tk[6] = UMAX3(UMAX3(tk[6], umin_(tk[5], c0), umin_(tk[4], c1)),
                    umin_(tk[3], c2), umin_(tk[2], c3));
      tk[5] = UMAX3(UMAX3(tk[5], umin_(tk[4], c0), umin_(tk[3], c1)),
                    umin_(tk[2], c2), umin_(tk[1], c3));
      tk[4] = UMAX3(UMAX3(tk[4], umin_(tk[3], c0), umin_(tk[2], c1)),
                    umin_(tk[1], c2), umin_(tk[0], c3));
      tk[3] = UMAX3(UMAX3(tk[3], c3, umin_(tk[2], c0)),
                    umin_(tk[1], c1), umin_(tk[0], c2));
      tk[2] = umax_(UMAX3(tk[2], c2, umin_(tk[1], c0)), umin_(tk[0], c1));
      tk[1] = UMAX3(tk[1], c1, umin_(tk[0], c0));
      tk[0] = umax_(tk[0], c0);
      cur = nxt;
    }
    __syncthreads();  // loop exit is unsynced; abuf reused as merge scratch below
    // merge 8 lists per n-row: [64 rows][8 lists][9] = 18KB (aliases abuf)
    unsigned* mkeys = (unsigned*)&abuf[0][0];
    int rw = wg * 16 + l15;
#pragma unroll
    for (int r = 0; r < NK; ++r) mkeys[(rw * 8 + sub * 4 + l4) * NK + r] = tk[r];
    __syncthreads();
    if (t < 256) {  // stage 2: merge list pairs {g, g+4} -> list g
      int row = t >> 2, g = t & 3;
      unsigned* a = &mkeys[(row * 8 + g) * NK];
      const unsigned* c = &mkeys[(row * 8 + g + 4) * NK];
      unsigned best[NK];
#pragma unroll
      for (int r = 0; r < NK; ++r) best[r] = 0u;
#pragma unroll
      for (int s = 0; s < 2 * NK; ++s) {
        unsigned cur_k = s < NK ? a[s] : c[s - NK];
#pragma unroll
        for (int q = 0; q < NK; ++q) {
          unsigned hi = best[q] > cur_k ? best[q] : cur_k;
          unsigned lo = best[q] > cur_k ? cur_k : best[q];
          best[q] = hi;
          cur_k = lo;
        }
      }
#pragma unroll
      for (int r = 0; r < NK; ++r) a[r] = best[r];
    }
    __syncthreads();
    if (t < 64) {  // stage 3: merge lists 0..3 (36 keys)
      const unsigned* src = &mkeys[(t * 8) * NK];
      unsigned best[NK];
#pragma unroll
      for (int r = 0; r < NK; ++r) best[r] = 0u;
      for (int s = 0; s < 36; ++s) {
        unsigned cur_k = src[s];
#pragma unroll
        for (int q = 0; q < NK; ++q) {
          unsigned hi = best[q] > cur_k ? best[q] : cur_k;
          unsigned lo = best[q] > cur_k ? cur_k : best[q];
          best[q] = hi;
          cur_k = lo;
        }
      }
      size_t row = (size_t)b * NN + n0 + t;
#pragma unroll
      for (int r = 0; r < NK; ++r)
        candK[(size_t)(seg * NK + r) * NROW + row] = best[r];
    }
  } else {
    // ---- k3 role: 49 blocks/XCD; P,Q = bf16((hn @ gcwb^T) * norm), 24 chunks ----
    int jj = j / 5;  // 0..48
    int n0 = jj * 64;
    int n = n0 + wg * 16 + l15;
    short8 bfr[6];
    {
      const short8* brow = (const short8*)(hb + (size_t)n * NC + l4 * 8);
#pragma unroll
      for (int ks = 0; ks < 6; ++ks) bfr[ks] = brow[ks * 4];
    }
    float nrm = norm[(size_t)b * NN + n];
    size_t orow = (size_t)b * NN + n;
    const char* wB = (const char*)gcwb;

    if (stg) { gload16(wB + gA, abuf[0] + LA); gload16(wB + gB, abuf[0] + LB); }
    int cur = 0;
    for (int ch = 0; ch < 24; ++ch) {
      int nxt = cur + 1 == 3 ? 0 : cur + 1;
      if (ch < 23) {
        const char* src = wB + (size_t)(ch + 1) * 12288;
        char* dl = &abuf[nxt][0];
        if (stg) { gload16(src + gA, dl + LA); gload16(src + gB, dl + LB); }
        asm volatile("s_waitcnt vmcnt(3)" ::: "memory");  // tolerate 1 store in flight
      } else {
        asm volatile("s_waitcnt vmcnt(0)" ::: "memory");
      }
      __builtin_amdgcn_s_barrier();
      __builtin_amdgcn_sched_barrier(0);
      const char* lb = &abuf[cur][0];
      f32x4 acc = {0.f, 0.f, 0.f, 0.f};
#pragma unroll
      for (int ks = 0; ks < 6; ++ks) {
        short8 af = *(const short8*)&lb[dso[ks]];
        acc = __builtin_amdgcn_mfma_f32_16x16x32_bf16(af, bfr[ks], acc, 0, 0, 0);
      }
      int o = ch * 32 + sub * 16 + l4 * 4;
      f32x4 st = acc * nrm;
      unsigned short* dst = (o < NCH) ? P : Q;
      int oo = (o < NCH) ? o : o - NCH;
      uint2 u;
      u.x = (unsigned)f2bf(st[0]) | ((unsigned)f2bf(st[1]) << 16);
      u.y = (unsigned)f2bf(st[2]) | ((unsigned)f2bf(st[3]) << 16);
      *(uint2*)&dst[orow * NCH + oo] = u;
      cur = nxt;
    }
  }
}

// ---------- K2b: merge 4x9 keys/row -> final top-9 indices ----------
__global__ __launch_bounds__(BDIM) void k2b_merge(const unsigned* __restrict__ candK,
                                                  int* __restrict__ idxo) {
  int row = blockIdx.x * BDIM + threadIdx.x;
  unsigned tk[NK];
#pragma unroll
  for (int r = 0; r < NK; ++r) tk[r] = 0u;
  for (int s = 0; s < 4 * NK; ++s) {
    unsigned cur = candK[(size_t)s * NROW + row];
#pragma unroll
    for (int j = 0; j < NK; ++j) {
      unsigned hi = tk[j] > cur ? tk[j] : cur;
      unsigned lo = tk[j] > cur ? cur : tk[j];
      tk[j] = hi;
      cur = lo;
    }
  }
#pragma unroll
  for (int r = 0; r < NK; ++r)
    idxo[(size_t)row * NK + r] = 4095 - (int)(tk[r] & 4095u);
}

// ---------- K4: batch->XCD-pinned gather-max + BN2 + gelu, bf16 out ----------
__global__ __launch_bounds__(BDIM) void k4_gathermax(
    const unsigned short* __restrict__ P, const unsigned short* __restrict__ Q,
    const int* __restrict__ idx, const float* __restrict__ sc2,
    const float* __restrict__ sh2, unsigned short* __restrict__ mbh) {
  int t = threadIdx.x;
  int lane = t & 63, wv = t >> 6;
  int b = blockIdx.x & 7;                      // batch == XCD (L2 pin for Q slab)
  int n = (int)(blockIdx.x >> 3) * 4 + wv;     // 0..3135
  size_t row = (size_t)b * NN + n;
  const int* ip = idx + row * NK;
  int id[NK];
#pragma unroll
  for (int k = 0; k < NK; ++k) id[k] = ip[k];
  const unsigned short* Qb = Q + (size_t)b * NN * NCH;
  const unsigned short* Pr = P + row * NCH;
  const unsigned short* Qr = Qb + (size_t)n * NCH;
#pragma unroll
  for (int j = 0; j < 3; ++j) {
    int o = j * 128 + lane * 2;
    float mx0 = -1e30f, mx1 = -1e30f;
#pragma unroll
    for (int k = 0; k < NK; ++k) {
      unsigned g = *(const unsigned*)&Qb[(size_t)id[k] * NCH + o];
      mx0 = fmaxf(mx0, bf2f(g & 0xffffu));
      mx1 = fmaxf(mx1, bf2f(g >> 16));
    }
    unsigned pv = *(const unsigned*)&Pr[o];
    unsigned qv = *(const unsigned*)&Qr[o];
    float2 ss = *(const float2*)&sc2[o];
    float2 hh = *(const float2*)&sh2[o];
    float e0 = bf2f(pv & 0xffffu) - bf2f(qv & 0xffffu) + mx0;
    float e1 = bf2f(pv >> 16) - bf2f(qv >> 16) + mx1;
    float y0 = e0 * ss.x + hh.x;
    float y1 = e1 * ss.y + hh.y;
    float ge0 = 0.5f * y0 * (1.f + erff(y0 * 0.70710678118654752f));
    float ge1 = 0.5f * y1 * (1.f + erff(y1 * 0.70710678118654752f));
    *(unsigned*)&mbh[row * NCH + o] =
        (unsigned)f2bf(ge0) | ((unsigned)f2bf(ge1) << 16);
  }
}

// ---------- K5: out = BN3(m @ fc2_w^T) + x via MFMA, direct [c][n] store ----------
__global__ __launch_bounds__(BDIM) void k5_mfma(
    const unsigned short* __restrict__ mbh, const unsigned short* __restrict__ fc2b,
    const float* __restrict__ sc3, const float* __restrict__ sh3,
    const float* __restrict__ x, float* __restrict__ out) {
  __shared__ __align__(16) char abuf[2][24576];
  int t = threadIdx.x;
  int bid = blockIdx.x;
  int b = bid / 147;
  int rem = bid % 147;
  int n0 = (rem / 3) * 64;
  int oc = rem % 3;
  int lane = t & 63, w = t >> 6;
  int l15 = lane & 15, l4 = lane >> 4;
  int n = n0 + w * 16 + l15;
  short8 bfr[12];
  {
    const short8* brow = (const short8*)(mbh + (size_t)(b * NN + n) * NCH + l4 * 8);
#pragma unroll
    for (int kh = 0; kh < 2; ++kh)
#pragma unroll
      for (int ks = 0; ks < 6; ++ks) bfr[kh * 6 + ks] = brow[kh * 24 + ks * 4];
  }
  f32x4 acc[4];
#pragma unroll
  for (int sub = 0; sub < 4; ++sub) acc[sub] = {0.f, 0.f, 0.f, 0.f};

  const char* wt = (const char*)fc2b + (size_t)oc * 2 * 24576;
  stage_tile(wt, abuf[0], t);
  __syncthreads();
  for (int kh = 0; kh < 2; ++kh) {
    if (kh == 0) stage_tile(wt + 24576, abuf[1], t);
#pragma unroll
    for (int sub = 0; sub < 4; ++sub) {
      int r_ = sub * 16 + l15;
      int rbase = r_ * 384, sw = (r_ & 7) << 4;
#pragma unroll
      for (int ks = 0; ks < 6; ++ks) {
        short8 af = *(const short8*)&abuf[kh][rbase + ((ks * 64 + l4 * 16) ^ sw)];
        acc[sub] = __builtin_amdgcn_mfma_f32_16x16x32_bf16(af, bfr[kh * 6 + ks],
                                                           acc[sub], 0, 0, 0);
      }
    }
    __syncthreads();
  }
  const float* xb_ = x + (size_t)b * NC * NN;
  float* ob = out + (size_t)b * NC * NN;
#pragma unroll
  for (int sub = 0; sub < 4; ++sub) {
    int c4 = oc * 64 + sub * 16 + l4 * 4;
    float s_[4], h_[4];
    *(float4*)s_ = *(const float4*)&sc3[c4];
    *(float4*)h_ = *(const float4*)&sh3[c4];
#pragma unroll
    for (int r = 0; r < 4; ++r) {
      size_t off = (size_t)(c4 + r) * NN + n;
      ob[off] = acc[sub][r] * s_[r] + h_[r] + xb_[off];
    }
  }
}

extern "C" void kernel_launch(void* const* d_in, const int* in_sizes, int n_in,
                              void* d_out, int out_size, void* d_ws, size_t ws_size,
                              hipStream_t stream) {
  const float* x = (const float*)d_in[0];
  const float* fc1_w = (const float*)d_in[1];
  const float* fc1_b = (const float*)d_in[2];
  const float* bn1_g = (const float*)d_in[3];
  const float* bn1_b = (const float*)d_in[4];
  const float* bn1_m = (const float*)d_in[5];
  const float* bn1_v = (const float*)d_in[6];
  const float* gc_w = (const float*)d_in[7];
  const float* gc_b = (const float*)d_in[8];
  const float* bn2_g = (const float*)d_in[9];
  const float* bn2_b = (const float*)d_in[10];
  const float* bn2_m = (const float*)d_in[11];
  const float* bn2_v = (const float*)d_in[12];
  const float* fc2_w = (const float*)d_in[13];
  const float* fc2_b = (const float*)d_in[14];
  const float* bn3_g = (const float*)d_in[15];
  const float* bn3_b = (const float*)d_in[16];
  const float* bn3_m = (const float*)d_in[17];
  const float* bn3_v = (const float*)d_in[18];

  size_t nrow = (size_t)NROW;
  size_t npq = (size_t)NB * NN * NCH;
  size_t nhb = (size_t)NB * NN * NC;
  unsigned short* Pb = (unsigned short*)d_ws;
  unsigned short* Qb = Pb + npq;
  unsigned short* mbh = Qb + npq;
  float* norm = (float*)(mbh + npq);
  int* idx = (int*)(norm + nrow);
  unsigned short* hnb = (unsigned short*)(idx + nrow * NK);
  unsigned short* gcwb = hnb + nhb;
  unsigned short* fc1b = gcwb + 768 * NC;
  unsigned short* fc2b = fc1b + NC * NC;
  unsigned* candK = (unsigned*)(fc2b + NC * NCH);
  float* sc1 = (float*)(candK + 4 * NK * nrow);
  float* sh1 = sc1 + NC;
  float* sc2 = sh1 + NC;
  float* sh2 = sc2 + NCH;
  float* sc3 = sh2 + NCH;
  float* sh3 = sc3 + NC;

  k0_convw<<<252, BDIM, 0, stream>>>(gc_w, fc1_w, fc2_w, gcwb, fc1b, fc2b);
  k0b_params<<<1, 384, 0, stream>>>(fc1_b, bn1_g, bn1_b, bn1_m, bn1_v, gc_b,
                                    bn2_g, bn2_b, bn2_m, bn2_v, fc2_b, bn3_g,
                                    bn3_b, bn3_m, bn3_v, sc1, sh1, sc2, sh2,
                                    sc3, sh3);
  k1_mfma<<<NB * 49, BDIM, 0, stream>>>(x, fc1b, sc1, sh1, hnb, norm);
  k23_fused<<<NB * 245, 512, 0, stream>>>(hnb, norm, gcwb, candK, Pb, Qb);
  k2b_merge<<<NROW / BDIM, BDIM, 0, stream>>>(candK, idx);
  k4_gathermax<<<(NB * NN) / 4, BDIM, 0, stream>>>(Pb, Qb, idx, sc2, sh2, mbh);
  k5_mfma<<<NB * 147, BDIM, 0, stream>>>(mbh, fc2b, sc3, sh3, x, (float*)d_out);
}